// Round 1
// baseline (2631.692 us; speedup 1.0000x reference)
//
#include <hip/hip_runtime.h>
#include <cstdio>

#define D_ 256
#define LT 1024
#define LA 2048
#define NB 16
#define RR_ 64
#define NRT (NB*LT)   // 16384 text rows
#define NRA (NB*LA)   // 32768 audio rows

__device__ __forceinline__ float gelu_f(float x) {
    return 0.5f * x * (1.0f + erff(x * 0.70710678118654752f));
}

// ---------------- K1: LayerNorm + shared projection + inv-norm ----------------
// 8 rows per block, 256 threads. Phase1: LN (32 lanes/row). Phase2: out = xh @ W^T + b.
__global__ __launch_bounds__(256) void k_lnproj(
    const float* __restrict__ X, const float* __restrict__ g, const float* __restrict__ bln,
    const float* __restrict__ W, const float* __restrict__ bsh,
    float* __restrict__ P, float* __restrict__ rinv)
{
    __shared__ float xh[8][256];
    int tid = threadIdx.x;
    long blk = blockIdx.x;
    int r = tid >> 5, lane = tid & 31;
    long row = blk * 8 + r;
    const float* xp = X + row * D_;
    float v[8];
    float s = 0.f;
#pragma unroll
    for (int j = 0; j < 8; j++) { v[j] = xp[lane + 32 * j]; s += v[j]; }
#pragma unroll
    for (int off = 16; off >= 1; off >>= 1) s += __shfl_xor(s, off, 32);
    float mean = s * (1.0f / 256.0f);
    float q = 0.f;
#pragma unroll
    for (int j = 0; j < 8; j++) { float d = v[j] - mean; q += d * d; }
#pragma unroll
    for (int off = 16; off >= 1; off >>= 1) q += __shfl_xor(q, off, 32);
    float ivar = rsqrtf(q * (1.0f / 256.0f) + 1e-5f);
#pragma unroll
    for (int j = 0; j < 8; j++) {
        int c = lane + 32 * j;
        xh[r][c] = (v[j] - mean) * ivar * g[c] + bln[c];
    }
    __syncthreads();
    // phase 2: each thread owns output column c for all 8 rows
    int c = tid;
    float acc[8];
    float bv = bsh[c];
#pragma unroll
    for (int rr = 0; rr < 8; rr++) acc[rr] = bv;
    const float4* W4 = (const float4*)(W + (long)c * D_);
    for (int k4 = 0; k4 < 64; k4++) {
        float4 w = W4[k4];
#pragma unroll
        for (int rr = 0; rr < 8; rr++) {
            float4 xv = *(const float4*)&xh[rr][k4 * 4];
            acc[rr] += xv.x * w.x + xv.y * w.y + xv.z * w.z + xv.w * w.w;
        }
    }
#pragma unroll
    for (int rr = 0; rr < 8; rr++) P[(blk * 8 + rr) * D_ + c] = acc[rr];
    __syncthreads();   // all xh reads done
#pragma unroll
    for (int rr = 0; rr < 8; rr++) xh[rr][c] = acc[rr] * acc[rr];
    __syncthreads();
    for (int sr = 128; sr >= 1; sr >>= 1) {
        if (c < sr) {
#pragma unroll
            for (int rr = 0; rr < 8; rr++) xh[rr][c] += xh[rr][c + sr];
        }
        __syncthreads();
    }
    if (c < 8) {
        float nrm = sqrtf(xh[c][0]);
        rinv[blk * 8 + c] = 1.0f / fmaxf(nrm, 1e-12f);
    }
}

// ---------------- K2: cost GEMM -> logK ----------------
// 64x64 tile, BK=32, LDS k-major tiles, 4x4 micro-tile per thread.
__global__ __launch_bounds__(256) void k_cost(
    const float* __restrict__ Tp, const float* __restrict__ Ap,
    const float* __restrict__ rnt, const float* __restrict__ rna,
    float* __restrict__ logK, float inv_eps)
{
    __shared__ float As[32][68];
    __shared__ float Bs[32][68];
    int b = blockIdx.z;
    int m0 = blockIdx.y * 64, n0 = blockIdx.x * 64;
    const float* Aptr = Tp + ((long)b * LT + m0) * D_;
    const float* Bptr = Ap + ((long)b * LA + n0) * D_;
    int tid = threadIdx.x;
    int tx = tid & 15, ty = tid >> 4;
    float acc[4][4] = {};
    for (int kt = 0; kt < 8; kt++) {
        int k0 = kt * 32;
#pragma unroll
        for (int h = 0; h < 2; h++) {
            int chunk = tid + 256 * h;
            int rowi = chunk >> 3, kc = chunk & 7;
            float4 a = *(const float4*)(Aptr + (long)rowi * D_ + k0 + kc * 4);
            float4 bb = *(const float4*)(Bptr + (long)rowi * D_ + k0 + kc * 4);
            As[kc * 4 + 0][rowi] = a.x; As[kc * 4 + 1][rowi] = a.y;
            As[kc * 4 + 2][rowi] = a.z; As[kc * 4 + 3][rowi] = a.w;
            Bs[kc * 4 + 0][rowi] = bb.x; Bs[kc * 4 + 1][rowi] = bb.y;
            Bs[kc * 4 + 2][rowi] = bb.z; Bs[kc * 4 + 3][rowi] = bb.w;
        }
        __syncthreads();
#pragma unroll
        for (int kk = 0; kk < 32; kk++) {
            float4 av = *(const float4*)&As[kk][ty * 4];
            float4 bv = *(const float4*)&Bs[kk][tx * 4];
            float aa[4] = { av.x, av.y, av.z, av.w };
            float bb4[4] = { bv.x, bv.y, bv.z, bv.w };
#pragma unroll
            for (int i = 0; i < 4; i++)
#pragma unroll
                for (int j = 0; j < 4; j++) acc[i][j] += aa[i] * bb4[j];
        }
        __syncthreads();
    }
    int n = n0 + tx * 4;
    float ra0 = rna[b * LA + n + 0], ra1 = rna[b * LA + n + 1];
    float ra2 = rna[b * LA + n + 2], ra3 = rna[b * LA + n + 3];
#pragma unroll
    for (int i = 0; i < 4; i++) {
        int m = m0 + ty * 4 + i;
        float rt = rnt[b * LT + m];
        float4 o;
        o.x = (acc[i][0] * rt * ra0 - 1.0f) * inv_eps;
        o.y = (acc[i][1] * rt * ra1 - 1.0f) * inv_eps;
        o.z = (acc[i][2] * rt * ra2 - 1.0f) * inv_eps;
        o.w = (acc[i][3] * rt * ra3 - 1.0f) * inv_eps;
        *(float4*)(logK + ((long)(b * LT + m)) * LA + n) = o;
    }
}

// ---------------- K3: row logsumexp -> lu ----------------
__global__ __launch_bounds__(256) void k_rowlse(
    const float* __restrict__ logK, const float* __restrict__ lv, float* __restrict__ lu)
{
    __shared__ float red[4];
    long blk = blockIdx.x;             // b*LT + m
    int b = (int)(blk >> 10);
    const float* p = logK + blk * LA;
    const float* lvp = lv + (long)b * LA;
    int tid = threadIdx.x;
    float v[8];
    float mx = -INFINITY;
#pragma unroll
    for (int j = 0; j < 8; j++) {
        v[j] = p[tid + 256 * j] + lvp[tid + 256 * j];
        mx = fmaxf(mx, v[j]);
    }
#pragma unroll
    for (int off = 32; off >= 1; off >>= 1) mx = fmaxf(mx, __shfl_xor(mx, off));
    if ((tid & 63) == 0) red[tid >> 6] = mx;
    __syncthreads();
    mx = fmaxf(fmaxf(red[0], red[1]), fmaxf(red[2], red[3]));
    __syncthreads();
    float s = 0.f;
#pragma unroll
    for (int j = 0; j < 8; j++) s += __expf(v[j] - mx);
#pragma unroll
    for (int off = 32; off >= 1; off >>= 1) s += __shfl_xor(s, off);
    if ((tid & 63) == 0) red[tid >> 6] = s;
    __syncthreads();
    s = red[0] + red[1] + red[2] + red[3];
    if (tid == 0) lu[blk] = -6.9314718055994531f - (mx + __logf(s));
}

// ---------------- K4: col logsumexp -> lv ----------------
__global__ __launch_bounds__(256) void k_collse(
    const float* __restrict__ logK, const float* __restrict__ lu, float* __restrict__ lv)
{
    __shared__ float lus[1024];
    __shared__ float redM[4][64];
    __shared__ float redS[4][64];
    int b = blockIdx.y;
    int n0 = blockIdx.x * 64;
    int tid = threadIdx.x;
    for (int i = tid; i < 1024; i += 256) lus[i] = lu[(long)b * LT + i];
    __syncthreads();
    int n = n0 + (tid & 63);
    int g = tid >> 6;
    const float* base = logK + (long)b * LT * LA + n;
    float M = -INFINITY, S = 0.f;
#pragma unroll 4
    for (int m = g; m < 1024; m += 4) {
        float vv = base[(long)m * LA] + lus[m];
        float Mn = fmaxf(M, vv);
        S = S * __expf(M - Mn) + __expf(vv - Mn);
        M = Mn;
    }
    redM[g][tid & 63] = M; redS[g][tid & 63] = S;
    __syncthreads();
    if (tid < 64) {
        float Mx = fmaxf(fmaxf(redM[0][tid], redM[1][tid]), fmaxf(redM[2][tid], redM[3][tid]));
        float Ss = 0.f;
#pragma unroll
        for (int gg = 0; gg < 4; gg++) Ss += redS[gg][tid] * __expf(redM[gg][tid] - Mx);
        lv[(long)b * LA + n0 + tid] = -7.6246189861593985f - (Mx + __logf(Ss));
    }
}

// ---------------- K5: A_al = pi @ Ap (exp fused into A staging) ----------------
// 64(m) x 128(d) tile, BK=32 over n. 8x4 micro-tile per thread.
__global__ __launch_bounds__(256) void k_pigemm(
    const float* __restrict__ logK, const float* __restrict__ Ap,
    const float* __restrict__ lu, const float* __restrict__ lv,
    float* __restrict__ Aal)
{
    __shared__ float As[32][68];
    __shared__ float Bs[32][132];
    int b = blockIdx.z;
    int m0 = blockIdx.y * 64;
    int d0 = blockIdx.x * 128;
    int tid = threadIdx.x;
    int tx = tid & 31;       // d: tx*4
    int ty = tid >> 5;       // m: ty*8 .. +7
    float acc[8][4] = {};
    const float* Kb = logK + ((long)b * LT + m0) * LA;
    const float* Bb = Ap + (long)b * LA * D_ + d0;
    const float* lup = lu + (long)b * LT + m0;
    const float* lvp = lv + (long)b * LA;
    for (int kt = 0; kt < 64; kt++) {
        int k0 = kt * 32;
#pragma unroll
        for (int h = 0; h < 2; h++) {
            int chunk = tid + 256 * h;
            int rowi = chunk >> 3, kc = chunk & 7;
            float4 a = *(const float4*)(Kb + (long)rowi * LA + k0 + kc * 4);
            float lum = lup[rowi];
            As[kc * 4 + 0][rowi] = __expf(lum + a.x + lvp[k0 + kc * 4 + 0]);
            As[kc * 4 + 1][rowi] = __expf(lum + a.y + lvp[k0 + kc * 4 + 1]);
            As[kc * 4 + 2][rowi] = __expf(lum + a.z + lvp[k0 + kc * 4 + 2]);
            As[kc * 4 + 3][rowi] = __expf(lum + a.w + lvp[k0 + kc * 4 + 3]);
        }
#pragma unroll
        for (int h = 0; h < 4; h++) {
            int chunk = tid + 256 * h;   // 0..1023
            int krow = chunk >> 5, dc = chunk & 31;
            float4 vv = *(const float4*)(Bb + (long)(k0 + krow) * D_ + dc * 4);
            *(float4*)&Bs[krow][dc * 4] = vv;
        }
        __syncthreads();
#pragma unroll
        for (int kk = 0; kk < 32; kk++) {
            float4 a0 = *(const float4*)&As[kk][ty * 8];
            float4 a1 = *(const float4*)&As[kk][ty * 8 + 4];
            float4 bv = *(const float4*)&Bs[kk][tx * 4];
            float aa[8] = { a0.x, a0.y, a0.z, a0.w, a1.x, a1.y, a1.z, a1.w };
            float bb4[4] = { bv.x, bv.y, bv.z, bv.w };
#pragma unroll
            for (int mi = 0; mi < 8; mi++)
#pragma unroll
                for (int j = 0; j < 4; j++) acc[mi][j] += aa[mi] * bb4[j];
        }
        __syncthreads();
    }
#pragma unroll
    for (int mi = 0; mi < 8; mi++) {
        long m = m0 + ty * 8 + mi;
        float4 o = { acc[mi][0], acc[mi][1], acc[mi][2], acc[mi][3] };
        *(float4*)(Aal + ((long)b * LT + m) * D_ + d0 + tx * 4) = o;
    }
}

// ---------------- K6: S = <Tp, A_al>, resid = |Tp - A_al| ----------------
__global__ __launch_bounds__(256) void k_sresid(
    const float* __restrict__ Tp, const float* __restrict__ Aal,
    float* __restrict__ resid, float* __restrict__ S)
{
    __shared__ float red[4];
    long row = blockIdx.x;
    int tid = threadIdx.x;
    float t = Tp[row * D_ + tid], a = Aal[row * D_ + tid];
    resid[row * D_ + tid] = fabsf(t - a);
    float p = t * a;
#pragma unroll
    for (int off = 32; off >= 1; off >>= 1) p += __shfl_xor(p, off);
    if ((tid & 63) == 0) red[tid >> 6] = p;
    __syncthreads();
    if (tid == 0) S[row] = red[0] + red[1] + red[2] + red[3];
}

// ---------------- K7a: H = gelu([S,resid] @ Wr1^T + br1) as GEMM + rank-1 ----------------
__global__ __launch_bounds__(256) void k_router1(
    const float* __restrict__ resid, const float* __restrict__ Wr1,
    const float* __restrict__ br1, const float* __restrict__ S,
    float* __restrict__ H)
{
    __shared__ float As[32][68];
    __shared__ float Bs[32][68];
    int m0 = blockIdx.y * 64;
    int n0 = blockIdx.x * 64;
    const float* Aptr = resid + (long)m0 * D_;
    int tid = threadIdx.x;
    int tx = tid & 15, ty = tid >> 4;
    float acc[4][4] = {};
    for (int kt = 0; kt < 8; kt++) {
        int k0 = kt * 32;
#pragma unroll
        for (int h = 0; h < 2; h++) {
            int chunk = tid + 256 * h;
            int rowi = chunk >> 3, kc = chunk & 7;
            float4 a = *(const float4*)(Aptr + (long)rowi * D_ + k0 + kc * 4);
            As[kc * 4 + 0][rowi] = a.x; As[kc * 4 + 1][rowi] = a.y;
            As[kc * 4 + 2][rowi] = a.z; As[kc * 4 + 3][rowi] = a.w;
            const float* wrow = Wr1 + (long)(n0 + rowi) * 257 + 1 + k0 + kc * 4;
            Bs[kc * 4 + 0][rowi] = wrow[0]; Bs[kc * 4 + 1][rowi] = wrow[1];
            Bs[kc * 4 + 2][rowi] = wrow[2]; Bs[kc * 4 + 3][rowi] = wrow[3];
        }
        __syncthreads();
#pragma unroll
        for (int kk = 0; kk < 32; kk++) {
            float4 av = *(const float4*)&As[kk][ty * 4];
            float4 bv = *(const float4*)&Bs[kk][tx * 4];
            float aa[4] = { av.x, av.y, av.z, av.w };
            float bb4[4] = { bv.x, bv.y, bv.z, bv.w };
#pragma unroll
            for (int i = 0; i < 4; i++)
#pragma unroll
                for (int j = 0; j < 4; j++) acc[i][j] += aa[i] * bb4[j];
        }
        __syncthreads();
    }
#pragma unroll
    for (int i = 0; i < 4; i++) {
        int m = m0 + ty * 4 + i;
        float sm = S[m];
#pragma unroll
        for (int j = 0; j < 4; j++) {
            int n = n0 + tx * 4 + j;
            float val = acc[i][j] + sm * Wr1[(long)n * 257] + br1[n];
            H[(long)m * D_ + n] = gelu_f(val);
        }
    }
}

// ---------------- K7b: logits + softmax -> G planes [3][16384] ----------------
__global__ __launch_bounds__(256) void k_router2(
    const float* __restrict__ H, const float* __restrict__ Wr2,
    const float* __restrict__ br2, float* __restrict__ G)
{
    __shared__ float rd[3][4];
    long row = blockIdx.x;
    int tid = threadIdx.x;
    float h = H[row * D_ + tid];
    float l0 = h * Wr2[tid], l1 = h * Wr2[256 + tid], l2 = h * Wr2[512 + tid];
#pragma unroll
    for (int off = 32; off >= 1; off >>= 1) {
        l0 += __shfl_xor(l0, off); l1 += __shfl_xor(l1, off); l2 += __shfl_xor(l2, off);
    }
    if ((tid & 63) == 0) { int w = tid >> 6; rd[0][w] = l0; rd[1][w] = l1; rd[2][w] = l2; }
    __syncthreads();
    if (tid == 0) {
        float L0 = rd[0][0] + rd[0][1] + rd[0][2] + rd[0][3] + br2[0];
        float L1 = rd[1][0] + rd[1][1] + rd[1][2] + rd[1][3] + br2[1];
        float L2 = rd[2][0] + rd[2][1] + rd[2][2] + rd[2][3] + br2[2];
        float mx = fmaxf(L0, fmaxf(L1, L2));
        float e0 = __expf(L0 - mx), e1 = __expf(L1 - mx), e2 = __expf(L2 - mx);
        float inv = 1.0f / (e0 + e1 + e2);
        G[row] = e0 * inv; G[NRT + row] = e1 * inv; G[2 * NRT + row] = e2 * inv;
    }
}

// ---------------- K8a: h = gelu(resid @ down_W^T + down_b) ----------------
__global__ __launch_bounds__(256) void k_down(
    const float* __restrict__ resid, const float* __restrict__ dW,
    const float* __restrict__ db, float* __restrict__ h)
{
    __shared__ float rs[8][256];
    long row0 = (long)blockIdx.x * 8;
    int tid = threadIdx.x;
    for (int idx = tid; idx < 8 * 256; idx += 256) rs[idx >> 8][idx & 255] = resid[row0 * D_ + idx];
    __syncthreads();
    int j = tid & 63, rg = tid >> 6;
    const float4* w4 = (const float4*)(dW + (long)j * D_);
    float a0 = db[j], a1 = a0;
    for (int k4 = 0; k4 < 64; k4++) {
        float4 w = w4[k4];
        float4 x0 = *(const float4*)&rs[rg * 2][k4 * 4];
        float4 x1 = *(const float4*)&rs[rg * 2 + 1][k4 * 4];
        a0 += x0.x * w.x + x0.y * w.y + x0.z * w.z + x0.w * w.w;
        a1 += x1.x * w.x + x1.y * w.y + x1.z * w.z + x1.w * w.w;
    }
    h[(row0 + rg * 2) * RR_ + j] = gelu_f(a0);
    h[(row0 + rg * 2 + 1) * RR_ + j] = gelu_f(a1);
}

// ---------------- K8b: depth-conv over sequence dim + bias + gelu ----------------
__global__ __launch_bounds__(256) void k_conv(
    const float* __restrict__ h, const float* __restrict__ w,
    const float* __restrict__ cb, float* __restrict__ hc, int ksz)
{
    __shared__ float hs[12][64];
    int blk = blockIdx.x;
    int b = blk >> 7, m0 = (blk & 127) * 8;
    int tid = threadIdx.x;
    int pad = (ksz - 1) >> 1;
    for (int idx = tid; idx < 12 * 64; idx += 256) {
        int mr = idx >> 6, i = idx & 63;
        int mm = m0 - 2 + mr;
        float vv = 0.f;
        if (mm >= 0 && mm < LT) vv = h[((long)b * LT + mm) * RR_ + i];
        hs[mr][i] = vv;
    }
    __syncthreads();
    int j = tid & 63, rg = tid >> 6;
    for (int rr = rg; rr < 8; rr += 4) {
        float acc = cb[j];
        for (int t = 0; t < ksz; t++) {
            const float* hrow = hs[rr + 2 + t - pad];
            const float* wp = w + (long)j * 64 * ksz + t;
#pragma unroll 16
            for (int i = 0; i < 64; i++) acc += wp[i * ksz] * hrow[i];
        }
        hc[((long)b * LT + m0 + rr) * RR_ + j] = gelu_f(acc);
    }
}

// ---------------- K8c: up-proj + residual + LN + gated accumulate ----------------
__global__ __launch_bounds__(256) void k_up(
    const float* __restrict__ hc, const float* __restrict__ uW, const float* __restrict__ ub,
    const float* __restrict__ resid, const float* __restrict__ eg, const float* __restrict__ eb,
    const float* __restrict__ G, float* __restrict__ out, int isFirst)
{
    __shared__ float hs[8][64];
    __shared__ float red[8][256];
    long row0 = (long)blockIdx.x * 8;
    int tid = threadIdx.x;
    for (int idx = tid; idx < 512; idx += 256) hs[idx >> 6][idx & 63] = hc[row0 * RR_ + idx];
    __syncthreads();
    int c = tid;
    const float4* w4 = (const float4*)(uW + (long)c * RR_);
    float v[8];
    float ubc = ub[c];
#pragma unroll
    for (int r = 0; r < 8; r++) v[r] = ubc;
    for (int k4 = 0; k4 < 16; k4++) {
        float4 w = w4[k4];
#pragma unroll
        for (int r = 0; r < 8; r++) {
            float4 x = *(const float4*)&hs[r][k4 * 4];
            v[r] += x.x * w.x + x.y * w.y + x.z * w.z + x.w * w.w;
        }
    }
#pragma unroll
    for (int r = 0; r < 8; r++) v[r] += resid[(row0 + r) * D_ + c];
#pragma unroll
    for (int r = 0; r < 8; r++) red[r][c] = v[r];
    __syncthreads();
    for (int sr = 128; sr >= 1; sr >>= 1) {
        if (c < sr) {
#pragma unroll
            for (int r = 0; r < 8; r++) red[r][c] += red[r][c + sr];
        }
        __syncthreads();
    }
    float mn[8];
#pragma unroll
    for (int r = 0; r < 8; r++) mn[r] = red[r][0] * (1.0f / 256.0f);
    __syncthreads();
#pragma unroll
    for (int r = 0; r < 8; r++) { float d = v[r] - mn[r]; red[r][c] = d * d; }
    __syncthreads();
    for (int sr = 128; sr >= 1; sr >>= 1) {
        if (c < sr) {
#pragma unroll
            for (int r = 0; r < 8; r++) red[r][c] += red[r][c + sr];
        }
        __syncthreads();
    }
#pragma unroll
    for (int r = 0; r < 8; r++) {
        float var = red[r][0] * (1.0f / 256.0f);
        float iv = rsqrtf(var + 1e-5f);
        float eo = (v[r] - mn[r]) * iv * eg[c] + eb[c];
        float gc = G[row0 + r];
        long o = (row0 + r) * D_ + c;
        if (isFirst) out[o] = gc * eo;
        else out[o] += gc * eo;
    }
}

__global__ void k_zero(float* p, int n) {
    int i = blockIdx.x * 256 + threadIdx.x;
    if (i < n) p[i] = 0.f;
}

extern "C" void kernel_launch(void* const* d_in, const int* in_sizes, int n_in,
                              void* d_out, int out_size, void* d_ws, size_t ws_size,
                              hipStream_t stream)
{
    const float* text   = (const float*)d_in[0];
    const float* audio  = (const float*)d_in[1];
    const float* ln_g   = (const float*)d_in[2];
    const float* ln_b   = (const float*)d_in[3];
    const float* W_sh   = (const float*)d_in[4];
    const float* b_sh   = (const float*)d_in[5];
    const float* Wr1    = (const float*)d_in[6];
    const float* br1    = (const float*)d_in[7];
    const float* Wr2    = (const float*)d_in[8];
    const float* br2    = (const float*)d_in[9];
    const float* down_W = (const float*)d_in[10];
    const float* down_b = (const float*)d_in[11];
    const float* cw1    = (const float*)d_in[12];
    const float* cw3    = (const float*)d_in[13];
    const float* cw5    = (const float*)d_in[14];
    const float* conv_b = (const float*)d_in[15];
    const float* up_W   = (const float*)d_in[16];
    const float* up_b   = (const float*)d_in[17];
    const float* en_g   = (const float*)d_in[18];
    const float* en_b   = (const float*)d_in[19];

    float* ws = (float*)d_ws;
    float* Tp    = ws;                       // 16*1024*256   = 4,194,304
    float* Ap    = Tp + 4194304;             // 16*2048*256   = 8,388,608
    float* logK  = Ap + 8388608;             // 16*1024*2048  = 33,554,432
    float* Aal   = logK + 33554432;          // 4,194,304
    float* resid = Aal + 4194304;            // 4,194,304
    float* rnt   = resid + 4194304;          // 16,384
    float* rna   = rnt + 16384;              // 32,768
    float* lu    = rna + 32768;              // 16,384
    float* lv    = lu + 16384;               // 32,768
    float* Sb    = lv + 32768;               // 16,384
    float* Gb    = Sb + 16384;               // 49,152
    size_t need_bytes = (size_t)(54689792) * 4;
    if (ws_size < need_bytes) {
        fprintf(stderr, "kernel_launch: ws_size %zu < needed %zu\n", ws_size, need_bytes);
        return;
    }
    // aliases (regions dead after k_pigemm)
    float* H   = Ap;                 // router hidden, 4.19M <= Ap 8.39M
    float* hb  = logK;               // expert h, 1.05M
    float* hcb = logK + 1048576;     // expert hc, 1.05M

    const float inv_eps = 1.0f / (float)(0.1 + 1e-8);

    k_lnproj<<<NRT / 8, 256, 0, stream>>>(text, ln_g, ln_b, W_sh, b_sh, Tp, rnt);
    k_lnproj<<<NRA / 8, 256, 0, stream>>>(audio, ln_g, ln_b, W_sh, b_sh, Ap, rna);
    k_cost<<<dim3(LA / 64, LT / 64, NB), 256, 0, stream>>>(Tp, Ap, rnt, rna, logK, inv_eps);
    k_zero<<<192, 256, 0, stream>>>(lu, 16384 + 32768);
    for (int it = 0; it < 10; it++) {
        k_rowlse<<<NRT, 256, 0, stream>>>(logK, lv, lu);
        k_collse<<<dim3(LA / 64, NB), 256, 0, stream>>>(logK, lu, lv);
    }
    k_pigemm<<<dim3(D_ / 128, LT / 64, NB), 256, 0, stream>>>(logK, Ap, lu, lv, Aal);
    k_sresid<<<NRT, 256, 0, stream>>>(Tp, Aal, resid, Sb);
    k_router1<<<dim3(D_ / 64, NRT / 64), 256, 0, stream>>>(resid, Wr1, br1, Sb, H);
    k_router2<<<NRT, 256, 0, stream>>>(H, Wr2, br2, Gb);
    for (int e = 0; e < 3; e++) {
        const float* cw = (e == 0) ? cw1 : ((e == 1) ? cw3 : cw5);
        int ksz = (e == 0) ? 1 : ((e == 1) ? 3 : 5);
        k_down<<<NRT / 8, 256, 0, stream>>>(resid, down_W + (long)e * 64 * 256, down_b + e * 64, hb);
        k_conv<<<NRT / 8, 256, 0, stream>>>(hb, cw, conv_b + e * 64, hcb, ksz);
        k_up<<<NRT / 8, 256, 0, stream>>>(hcb, up_W + (long)e * 256 * 64, up_b + e * 256,
                                          resid, en_g + e * 256, en_b + e * 256,
                                          Gb + (long)e * NRT, (float*)d_out, e == 0 ? 1 : 0);
    }
}

// Round 2
// 1683.908 us; speedup vs baseline: 1.5628x; 1.5628x over previous
//
#include <hip/hip_runtime.h>
#include <cstdio>

#define D_ 256
#define LT 1024
#define LA 2048
#define NB 16
#define RR_ 64
#define NRT (NB*LT)   // 16384 text rows
#define NRA (NB*LA)   // 32768 audio rows

__device__ __forceinline__ float gelu_f(float x) {
    return 0.5f * x * (1.0f + erff(x * 0.70710678118654752f));
}

// ---------------- K1: LayerNorm + shared projection + inv-norm ----------------
// 8 rows per block, 256 threads. Phase1: LN (32 lanes/row). Phase2: out = xh @ W^T + b.
__global__ __launch_bounds__(256) void k_lnproj(
    const float* __restrict__ X, const float* __restrict__ g, const float* __restrict__ bln,
    const float* __restrict__ W, const float* __restrict__ bsh,
    float* __restrict__ P, float* __restrict__ rinv)
{
    __shared__ float xh[8][256];
    int tid = threadIdx.x;
    long blk = blockIdx.x;
    int r = tid >> 5, lane = tid & 31;
    long row = blk * 8 + r;
    const float* xp = X + row * D_;
    float v[8];
    float s = 0.f;
#pragma unroll
    for (int j = 0; j < 8; j++) { v[j] = xp[lane + 32 * j]; s += v[j]; }
#pragma unroll
    for (int off = 16; off >= 1; off >>= 1) s += __shfl_xor(s, off, 32);
    float mean = s * (1.0f / 256.0f);
    float q = 0.f;
#pragma unroll
    for (int j = 0; j < 8; j++) { float d = v[j] - mean; q += d * d; }
#pragma unroll
    for (int off = 16; off >= 1; off >>= 1) q += __shfl_xor(q, off, 32);
    float ivar = rsqrtf(q * (1.0f / 256.0f) + 1e-5f);
#pragma unroll
    for (int j = 0; j < 8; j++) {
        int c = lane + 32 * j;
        xh[r][c] = (v[j] - mean) * ivar * g[c] + bln[c];
    }
    __syncthreads();
    // phase 2: each thread owns output column c for all 8 rows
    int c = tid;
    float acc[8];
    float bv = bsh[c];
#pragma unroll
    for (int rr = 0; rr < 8; rr++) acc[rr] = bv;
    const float4* W4 = (const float4*)(W + (long)c * D_);
    for (int k4 = 0; k4 < 64; k4++) {
        float4 w = W4[k4];
#pragma unroll
        for (int rr = 0; rr < 8; rr++) {
            float4 xv = *(const float4*)&xh[rr][k4 * 4];
            acc[rr] += xv.x * w.x + xv.y * w.y + xv.z * w.z + xv.w * w.w;
        }
    }
#pragma unroll
    for (int rr = 0; rr < 8; rr++) P[(blk * 8 + rr) * D_ + c] = acc[rr];
    __syncthreads();   // all xh reads done
#pragma unroll
    for (int rr = 0; rr < 8; rr++) xh[rr][c] = acc[rr] * acc[rr];
    __syncthreads();
    for (int sr = 128; sr >= 1; sr >>= 1) {
        if (c < sr) {
#pragma unroll
            for (int rr = 0; rr < 8; rr++) xh[rr][c] += xh[rr][c + sr];
        }
        __syncthreads();
    }
    if (c < 8) {
        float nrm = sqrtf(xh[c][0]);
        rinv[blk * 8 + c] = 1.0f / fmaxf(nrm, 1e-12f);
    }
}

// ---------------- K2: cost GEMM -> logK ----------------
// 64x64 tile, BK=32, LDS k-major tiles, 4x4 micro-tile per thread.
__global__ __launch_bounds__(256) void k_cost(
    const float* __restrict__ Tp, const float* __restrict__ Ap,
    const float* __restrict__ rnt, const float* __restrict__ rna,
    float* __restrict__ logK, float inv_eps)
{
    __shared__ float As[32][68];
    __shared__ float Bs[32][68];
    int b = blockIdx.z;
    int m0 = blockIdx.y * 64, n0 = blockIdx.x * 64;
    const float* Aptr = Tp + ((long)b * LT + m0) * D_;
    const float* Bptr = Ap + ((long)b * LA + n0) * D_;
    int tid = threadIdx.x;
    int tx = tid & 15, ty = tid >> 4;
    float acc[4][4] = {};
    for (int kt = 0; kt < 8; kt++) {
        int k0 = kt * 32;
#pragma unroll
        for (int h = 0; h < 2; h++) {
            int chunk = tid + 256 * h;
            int rowi = chunk >> 3, kc = chunk & 7;
            float4 a = *(const float4*)(Aptr + (long)rowi * D_ + k0 + kc * 4);
            float4 bb = *(const float4*)(Bptr + (long)rowi * D_ + k0 + kc * 4);
            As[kc * 4 + 0][rowi] = a.x; As[kc * 4 + 1][rowi] = a.y;
            As[kc * 4 + 2][rowi] = a.z; As[kc * 4 + 3][rowi] = a.w;
            Bs[kc * 4 + 0][rowi] = bb.x; Bs[kc * 4 + 1][rowi] = bb.y;
            Bs[kc * 4 + 2][rowi] = bb.z; Bs[kc * 4 + 3][rowi] = bb.w;
        }
        __syncthreads();
#pragma unroll
        for (int kk = 0; kk < 32; kk++) {
            float4 av = *(const float4*)&As[kk][ty * 4];
            float4 bv = *(const float4*)&Bs[kk][tx * 4];
            float aa[4] = { av.x, av.y, av.z, av.w };
            float bb4[4] = { bv.x, bv.y, bv.z, bv.w };
#pragma unroll
            for (int i = 0; i < 4; i++)
#pragma unroll
                for (int j = 0; j < 4; j++) acc[i][j] += aa[i] * bb4[j];
        }
        __syncthreads();
    }
    int n = n0 + tx * 4;
    float ra0 = rna[b * LA + n + 0], ra1 = rna[b * LA + n + 1];
    float ra2 = rna[b * LA + n + 2], ra3 = rna[b * LA + n + 3];
#pragma unroll
    for (int i = 0; i < 4; i++) {
        int m = m0 + ty * 4 + i;
        float rt = rnt[b * LT + m];
        float4 o;
        o.x = (acc[i][0] * rt * ra0 - 1.0f) * inv_eps;
        o.y = (acc[i][1] * rt * ra1 - 1.0f) * inv_eps;
        o.z = (acc[i][2] * rt * ra2 - 1.0f) * inv_eps;
        o.w = (acc[i][3] * rt * ra3 - 1.0f) * inv_eps;
        *(float4*)(logK + ((long)(b * LT + m)) * LA + n) = o;
    }
}

// ---------------- K3: row logsumexp -> lu ----------------
__global__ __launch_bounds__(256) void k_rowlse(
    const float* __restrict__ logK, const float* __restrict__ lv, float* __restrict__ lu)
{
    __shared__ float red[4];
    long blk = blockIdx.x;             // b*LT + m
    int b = (int)(blk >> 10);
    const float* p = logK + blk * LA;
    const float* lvp = lv + (long)b * LA;
    int tid = threadIdx.x;
    float v[8];
    float mx = -INFINITY;
#pragma unroll
    for (int j = 0; j < 8; j++) {
        v[j] = p[tid + 256 * j] + lvp[tid + 256 * j];
        mx = fmaxf(mx, v[j]);
    }
#pragma unroll
    for (int off = 32; off >= 1; off >>= 1) mx = fmaxf(mx, __shfl_xor(mx, off));
    if ((tid & 63) == 0) red[tid >> 6] = mx;
    __syncthreads();
    mx = fmaxf(fmaxf(red[0], red[1]), fmaxf(red[2], red[3]));
    __syncthreads();
    float s = 0.f;
#pragma unroll
    for (int j = 0; j < 8; j++) s += __expf(v[j] - mx);
#pragma unroll
    for (int off = 32; off >= 1; off >>= 1) s += __shfl_xor(s, off);
    if ((tid & 63) == 0) red[tid >> 6] = s;
    __syncthreads();
    s = red[0] + red[1] + red[2] + red[3];
    if (tid == 0) lu[blk] = -6.9314718055994531f - (mx + __logf(s));
}

// ---------------- K4: col logsumexp -> lv ----------------
__global__ __launch_bounds__(256) void k_collse(
    const float* __restrict__ logK, const float* __restrict__ lu, float* __restrict__ lv)
{
    __shared__ float lus[1024];
    __shared__ float redM[4][64];
    __shared__ float redS[4][64];
    int b = blockIdx.y;
    int n0 = blockIdx.x * 64;
    int tid = threadIdx.x;
    for (int i = tid; i < 1024; i += 256) lus[i] = lu[(long)b * LT + i];
    __syncthreads();
    int n = n0 + (tid & 63);
    int g = tid >> 6;
    const float* base = logK + (long)b * LT * LA + n;
    float M = -INFINITY, S = 0.f;
#pragma unroll 4
    for (int m = g; m < 1024; m += 4) {
        float vv = base[(long)m * LA] + lus[m];
        float Mn = fmaxf(M, vv);
        S = S * __expf(M - Mn) + __expf(vv - Mn);
        M = Mn;
    }
    redM[g][tid & 63] = M; redS[g][tid & 63] = S;
    __syncthreads();
    if (tid < 64) {
        float Mx = fmaxf(fmaxf(redM[0][tid], redM[1][tid]), fmaxf(redM[2][tid], redM[3][tid]));
        float Ss = 0.f;
#pragma unroll
        for (int gg = 0; gg < 4; gg++) Ss += redS[gg][tid] * __expf(redM[gg][tid] - Mx);
        lv[(long)b * LA + n0 + tid] = -7.6246189861593985f - (Mx + __logf(Ss));
    }
}

// ---------------- K5: A_al = pi @ Ap (exp fused into A staging) ----------------
// 64(m) x 128(d) tile, BK=32 over n. 8x4 micro-tile per thread.
__global__ __launch_bounds__(256) void k_pigemm(
    const float* __restrict__ logK, const float* __restrict__ Ap,
    const float* __restrict__ lu, const float* __restrict__ lv,
    float* __restrict__ Aal)
{
    __shared__ float As[32][68];
    __shared__ float Bs[32][132];
    int b = blockIdx.z;
    int m0 = blockIdx.y * 64;
    int d0 = blockIdx.x * 128;
    int tid = threadIdx.x;
    int tx = tid & 31;       // d: tx*4
    int ty = tid >> 5;       // m: ty*8 .. +7
    float acc[8][4] = {};
    const float* Kb = logK + ((long)b * LT + m0) * LA;
    const float* Bb = Ap + (long)b * LA * D_ + d0;
    const float* lup = lu + (long)b * LT + m0;
    const float* lvp = lv + (long)b * LA;
    for (int kt = 0; kt < 64; kt++) {
        int k0 = kt * 32;
#pragma unroll
        for (int h = 0; h < 2; h++) {
            int chunk = tid + 256 * h;
            int rowi = chunk >> 3, kc = chunk & 7;
            float4 a = *(const float4*)(Kb + (long)rowi * LA + k0 + kc * 4);
            float lum = lup[rowi];
            As[kc * 4 + 0][rowi] = __expf(lum + a.x + lvp[k0 + kc * 4 + 0]);
            As[kc * 4 + 1][rowi] = __expf(lum + a.y + lvp[k0 + kc * 4 + 1]);
            As[kc * 4 + 2][rowi] = __expf(lum + a.z + lvp[k0 + kc * 4 + 2]);
            As[kc * 4 + 3][rowi] = __expf(lum + a.w + lvp[k0 + kc * 4 + 3]);
        }
#pragma unroll
        for (int h = 0; h < 4; h++) {
            int chunk = tid + 256 * h;   // 0..1023
            int krow = chunk >> 5, dc = chunk & 31;
            float4 vv = *(const float4*)(Bb + (long)(k0 + krow) * D_ + dc * 4);
            *(float4*)&Bs[krow][dc * 4] = vv;
        }
        __syncthreads();
#pragma unroll
        for (int kk = 0; kk < 32; kk++) {
            float4 a0 = *(const float4*)&As[kk][ty * 8];
            float4 a1 = *(const float4*)&As[kk][ty * 8 + 4];
            float4 bv = *(const float4*)&Bs[kk][tx * 4];
            float aa[8] = { a0.x, a0.y, a0.z, a0.w, a1.x, a1.y, a1.z, a1.w };
            float bb4[4] = { bv.x, bv.y, bv.z, bv.w };
#pragma unroll
            for (int mi = 0; mi < 8; mi++)
#pragma unroll
                for (int j = 0; j < 4; j++) acc[mi][j] += aa[mi] * bb4[j];
        }
        __syncthreads();
    }
#pragma unroll
    for (int mi = 0; mi < 8; mi++) {
        long m = m0 + ty * 8 + mi;
        float4 o = { acc[mi][0], acc[mi][1], acc[mi][2], acc[mi][3] };
        *(float4*)(Aal + ((long)b * LT + m) * D_ + d0 + tx * 4) = o;
    }
}

// ---------------- K6: S = <Tp, A_al>, resid = |Tp - A_al| ----------------
__global__ __launch_bounds__(256) void k_sresid(
    const float* __restrict__ Tp, const float* __restrict__ Aal,
    float* __restrict__ resid, float* __restrict__ S)
{
    __shared__ float red[4];
    long row = blockIdx.x;
    int tid = threadIdx.x;
    float t = Tp[row * D_ + tid], a = Aal[row * D_ + tid];
    resid[row * D_ + tid] = fabsf(t - a);
    float p = t * a;
#pragma unroll
    for (int off = 32; off >= 1; off >>= 1) p += __shfl_xor(p, off);
    if ((tid & 63) == 0) red[tid >> 6] = p;
    __syncthreads();
    if (tid == 0) S[row] = red[0] + red[1] + red[2] + red[3];
}

// ---------------- K7a: H = gelu([S,resid] @ Wr1^T + br1) as GEMM + rank-1 ----------------
__global__ __launch_bounds__(256) void k_router1(
    const float* __restrict__ resid, const float* __restrict__ Wr1,
    const float* __restrict__ br1, const float* __restrict__ S,
    float* __restrict__ H)
{
    __shared__ float As[32][68];
    __shared__ float Bs[32][68];
    int m0 = blockIdx.y * 64;
    int n0 = blockIdx.x * 64;
    const float* Aptr = resid + (long)m0 * D_;
    int tid = threadIdx.x;
    int tx = tid & 15, ty = tid >> 4;
    float acc[4][4] = {};
    for (int kt = 0; kt < 8; kt++) {
        int k0 = kt * 32;
#pragma unroll
        for (int h = 0; h < 2; h++) {
            int chunk = tid + 256 * h;
            int rowi = chunk >> 3, kc = chunk & 7;
            float4 a = *(const float4*)(Aptr + (long)rowi * D_ + k0 + kc * 4);
            As[kc * 4 + 0][rowi] = a.x; As[kc * 4 + 1][rowi] = a.y;
            As[kc * 4 + 2][rowi] = a.z; As[kc * 4 + 3][rowi] = a.w;
            const float* wrow = Wr1 + (long)(n0 + rowi) * 257 + 1 + k0 + kc * 4;
            Bs[kc * 4 + 0][rowi] = wrow[0]; Bs[kc * 4 + 1][rowi] = wrow[1];
            Bs[kc * 4 + 2][rowi] = wrow[2]; Bs[kc * 4 + 3][rowi] = wrow[3];
        }
        __syncthreads();
#pragma unroll
        for (int kk = 0; kk < 32; kk++) {
            float4 av = *(const float4*)&As[kk][ty * 4];
            float4 bv = *(const float4*)&Bs[kk][tx * 4];
            float aa[4] = { av.x, av.y, av.z, av.w };
            float bb4[4] = { bv.x, bv.y, bv.z, bv.w };
#pragma unroll
            for (int i = 0; i < 4; i++)
#pragma unroll
                for (int j = 0; j < 4; j++) acc[i][j] += aa[i] * bb4[j];
        }
        __syncthreads();
    }
#pragma unroll
    for (int i = 0; i < 4; i++) {
        int m = m0 + ty * 4 + i;
        float sm = S[m];
#pragma unroll
        for (int j = 0; j < 4; j++) {
            int n = n0 + tx * 4 + j;
            float val = acc[i][j] + sm * Wr1[(long)n * 257] + br1[n];
            H[(long)m * D_ + n] = gelu_f(val);
        }
    }
}

// ---------------- K7b: logits + softmax -> G planes [3][16384] ----------------
__global__ __launch_bounds__(256) void k_router2(
    const float* __restrict__ H, const float* __restrict__ Wr2,
    const float* __restrict__ br2, float* __restrict__ G)
{
    __shared__ float rd[3][4];
    long row = blockIdx.x;
    int tid = threadIdx.x;
    float h = H[row * D_ + tid];
    float l0 = h * Wr2[tid], l1 = h * Wr2[256 + tid], l2 = h * Wr2[512 + tid];
#pragma unroll
    for (int off = 32; off >= 1; off >>= 1) {
        l0 += __shfl_xor(l0, off); l1 += __shfl_xor(l1, off); l2 += __shfl_xor(l2, off);
    }
    if ((tid & 63) == 0) { int w = tid >> 6; rd[0][w] = l0; rd[1][w] = l1; rd[2][w] = l2; }
    __syncthreads();
    if (tid == 0) {
        float L0 = rd[0][0] + rd[0][1] + rd[0][2] + rd[0][3] + br2[0];
        float L1 = rd[1][0] + rd[1][1] + rd[1][2] + rd[1][3] + br2[1];
        float L2 = rd[2][0] + rd[2][1] + rd[2][2] + rd[2][3] + br2[2];
        float mx = fmaxf(L0, fmaxf(L1, L2));
        float e0 = __expf(L0 - mx), e1 = __expf(L1 - mx), e2 = __expf(L2 - mx);
        float inv = 1.0f / (e0 + e1 + e2);
        G[row] = e0 * inv; G[NRT + row] = e1 * inv; G[2 * NRT + row] = e2 * inv;
    }
}

// ---------------- K8a: h = gelu(resid @ down_W^T + down_b) ----------------
__global__ __launch_bounds__(256) void k_down(
    const float* __restrict__ resid, const float* __restrict__ dW,
    const float* __restrict__ db, float* __restrict__ h)
{
    __shared__ float rs[8][256];
    long row0 = (long)blockIdx.x * 8;
    int tid = threadIdx.x;
    for (int idx = tid; idx < 8 * 256; idx += 256) rs[idx >> 8][idx & 255] = resid[row0 * D_ + idx];
    __syncthreads();
    int j = tid & 63, rg = tid >> 6;
    const float4* w4 = (const float4*)(dW + (long)j * D_);
    float a0 = db[j], a1 = a0;
    for (int k4 = 0; k4 < 64; k4++) {
        float4 w = w4[k4];
        float4 x0 = *(const float4*)&rs[rg * 2][k4 * 4];
        float4 x1 = *(const float4*)&rs[rg * 2 + 1][k4 * 4];
        a0 += x0.x * w.x + x0.y * w.y + x0.z * w.z + x0.w * w.w;
        a1 += x1.x * w.x + x1.y * w.y + x1.z * w.z + x1.w * w.w;
    }
    h[(row0 + rg * 2) * RR_ + j] = gelu_f(a0);
    h[(row0 + rg * 2 + 1) * RR_ + j] = gelu_f(a1);
}

// ---------------- K8b: depth-conv over sequence (tap-sliced LDS GEMM) ----------------
// 64 rows per block (+2 halo each side). Per tap t: stage w[:,:,t] transposed
// to wt[i][j] in LDS (16 KB), then VALU-bound 4x4 micro-tile FMA from LDS.
// Old version did a scalar uncoalesced GLOBAL weight load per FMA -> 568 us.
__global__ __launch_bounds__(256) void k_conv(
    const float* __restrict__ h, const float* __restrict__ w,
    const float* __restrict__ cb, float* __restrict__ hc, int ksz)
{
    __shared__ float hs[68][68];   // rows m0-2 .. m0+65; stride 68 words: ty-groups hit disjoint banks
    __shared__ float wt[64][64];   // [in_ch i][out_ch j] for current tap
    int blk = blockIdx.x;
    int b = blk >> 4, m0 = (blk & 15) * 64;   // 16 m-blocks per batch
    int tid = threadIdx.x;
    int pad = (ksz - 1) >> 1;
    // stage h rows m0-2 .. m0+65 (zero-fill out of range)
    for (int idx = tid; idx < 68 * 16; idx += 256) {
        int mr = idx >> 4, i4 = idx & 15;
        int mm = m0 - 2 + mr;
        float4 vv = { 0.f, 0.f, 0.f, 0.f };
        if (mm >= 0 && mm < LT) vv = *(const float4*)(h + ((long)b * LT + mm) * RR_ + i4 * 4);
        *(float4*)&hs[mr][i4 * 4] = vv;
    }
    int tx = tid & 15, ty = tid >> 4;   // j = tx*4..+3, rows = ty*4..+3
    float acc[4][4] = {};
    for (int t = 0; t < ksz; t++) {
        __syncthreads();   // hs staged (t=0) / wt readers done (t>0)
        for (int idx = tid; idx < 4096; idx += 256) {
            int i = idx & 63, j = idx >> 6;
            wt[i][j] = w[(long)j * RR_ * ksz + i * ksz + t];
        }
        __syncthreads();
        int roff = ty * 4 + 2 + t - pad;   // hs row of conv input for local row ty*4
        for (int i4 = 0; i4 < 16; i4++) {
            float4 h0 = *(const float4*)&hs[roff + 0][i4 * 4];
            float4 h1 = *(const float4*)&hs[roff + 1][i4 * 4];
            float4 h2 = *(const float4*)&hs[roff + 2][i4 * 4];
            float4 h3 = *(const float4*)&hs[roff + 3][i4 * 4];
            float hh[4][4] = { { h0.x, h0.y, h0.z, h0.w }, { h1.x, h1.y, h1.z, h1.w },
                               { h2.x, h2.y, h2.z, h2.w }, { h3.x, h3.y, h3.z, h3.w } };
#pragma unroll
            for (int s = 0; s < 4; s++) {
                float4 wv = *(const float4*)&wt[i4 * 4 + s][tx * 4];
#pragma unroll
                for (int r = 0; r < 4; r++) {
                    acc[r][0] += hh[r][s] * wv.x;
                    acc[r][1] += hh[r][s] * wv.y;
                    acc[r][2] += hh[r][s] * wv.z;
                    acc[r][3] += hh[r][s] * wv.w;
                }
            }
        }
    }
    float4 bb = *(const float4*)(cb + tx * 4);
#pragma unroll
    for (int r = 0; r < 4; r++) {
        long m = (long)b * LT + m0 + ty * 4 + r;
        float4 o;
        o.x = gelu_f(acc[r][0] + bb.x);
        o.y = gelu_f(acc[r][1] + bb.y);
        o.z = gelu_f(acc[r][2] + bb.z);
        o.w = gelu_f(acc[r][3] + bb.w);
        *(float4*)(hc + m * RR_ + tx * 4) = o;
    }
}

// ---------------- K8c: up-proj + residual + LN + gated accumulate ----------------
__global__ __launch_bounds__(256) void k_up(
    const float* __restrict__ hc, const float* __restrict__ uW, const float* __restrict__ ub,
    const float* __restrict__ resid, const float* __restrict__ eg, const float* __restrict__ eb,
    const float* __restrict__ G, float* __restrict__ out, int isFirst)
{
    __shared__ float hs[8][64];
    __shared__ float red[8][256];
    long row0 = (long)blockIdx.x * 8;
    int tid = threadIdx.x;
    for (int idx = tid; idx < 512; idx += 256) hs[idx >> 6][idx & 63] = hc[row0 * RR_ + idx];
    __syncthreads();
    int c = tid;
    const float4* w4 = (const float4*)(uW + (long)c * RR_);
    float v[8];
    float ubc = ub[c];
#pragma unroll
    for (int r = 0; r < 8; r++) v[r] = ubc;
    for (int k4 = 0; k4 < 16; k4++) {
        float4 w = w4[k4];
#pragma unroll
        for (int r = 0; r < 8; r++) {
            float4 x = *(const float4*)&hs[r][k4 * 4];
            v[r] += x.x * w.x + x.y * w.y + x.z * w.z + x.w * w.w;
        }
    }
#pragma unroll
    for (int r = 0; r < 8; r++) v[r] += resid[(row0 + r) * D_ + c];
#pragma unroll
    for (int r = 0; r < 8; r++) red[r][c] = v[r];
    __syncthreads();
    for (int sr = 128; sr >= 1; sr >>= 1) {
        if (c < sr) {
#pragma unroll
            for (int r = 0; r < 8; r++) red[r][c] += red[r][c + sr];
        }
        __syncthreads();
    }
    float mn[8];
#pragma unroll
    for (int r = 0; r < 8; r++) mn[r] = red[r][0] * (1.0f / 256.0f);
    __syncthreads();
#pragma unroll
    for (int r = 0; r < 8; r++) { float d = v[r] - mn[r]; red[r][c] = d * d; }
    __syncthreads();
    for (int sr = 128; sr >= 1; sr >>= 1) {
        if (c < sr) {
#pragma unroll
            for (int r = 0; r < 8; r++) red[r][c] += red[r][c + sr];
        }
        __syncthreads();
    }
#pragma unroll
    for (int r = 0; r < 8; r++) {
        float var = red[r][0] * (1.0f / 256.0f);
        float iv = rsqrtf(var + 1e-5f);
        float eo = (v[r] - mn[r]) * iv * eg[c] + eb[c];
        float gc = G[row0 + r];
        long o = (row0 + r) * D_ + c;
        if (isFirst) out[o] = gc * eo;
        else out[o] += gc * eo;
    }
}

__global__ void k_zero(float* p, int n) {
    int i = blockIdx.x * 256 + threadIdx.x;
    if (i < n) p[i] = 0.f;
}

extern "C" void kernel_launch(void* const* d_in, const int* in_sizes, int n_in,
                              void* d_out, int out_size, void* d_ws, size_t ws_size,
                              hipStream_t stream)
{
    const float* text   = (const float*)d_in[0];
    const float* audio  = (const float*)d_in[1];
    const float* ln_g   = (const float*)d_in[2];
    const float* ln_b   = (const float*)d_in[3];
    const float* W_sh   = (const float*)d_in[4];
    const float* b_sh   = (const float*)d_in[5];
    const float* Wr1    = (const float*)d_in[6];
    const float* br1    = (const float*)d_in[7];
    const float* Wr2    = (const float*)d_in[8];
    const float* br2    = (const float*)d_in[9];
    const float* down_W = (const float*)d_in[10];
    const float* down_b = (const float*)d_in[11];
    const float* cw1    = (const float*)d_in[12];
    const float* cw3    = (const float*)d_in[13];
    const float* cw5    = (const float*)d_in[14];
    const float* conv_b = (const float*)d_in[15];
    const float* up_W   = (const float*)d_in[16];
    const float* up_b   = (const float*)d_in[17];
    const float* en_g   = (const float*)d_in[18];
    const float* en_b   = (const float*)d_in[19];

    float* ws = (float*)d_ws;
    float* Tp    = ws;                       // 16*1024*256   = 4,194,304
    float* Ap    = Tp + 4194304;             // 16*2048*256   = 8,388,608
    float* logK  = Ap + 8388608;             // 16*1024*2048  = 33,554,432
    float* Aal   = logK + 33554432;          // 4,194,304
    float* resid = Aal + 4194304;            // 4,194,304
    float* rnt   = resid + 4194304;          // 16,384
    float* rna   = rnt + 16384;              // 32,768
    float* lu    = rna + 32768;              // 16,384
    float* lv    = lu + 16384;               // 32,768
    float* Sb    = lv + 32768;               // 16,384
    float* Gb    = Sb + 16384;               // 49,152
    size_t need_bytes = (size_t)(54689792) * 4;
    if (ws_size < need_bytes) {
        fprintf(stderr, "kernel_launch: ws_size %zu < needed %zu\n", ws_size, need_bytes);
        return;
    }
    // aliases (regions dead after k_pigemm)
    float* H   = Ap;                 // router hidden, 4.19M <= Ap 8.39M
    float* hb  = logK;               // expert h, 1.05M
    float* hcb = logK + 1048576;     // expert hc, 1.05M

    const float inv_eps = 1.0f / (float)(0.1 + 1e-8);

    k_lnproj<<<NRT / 8, 256, 0, stream>>>(text, ln_g, ln_b, W_sh, b_sh, Tp, rnt);
    k_lnproj<<<NRA / 8, 256, 0, stream>>>(audio, ln_g, ln_b, W_sh, b_sh, Ap, rna);
    k_cost<<<dim3(LA / 64, LT / 64, NB), 256, 0, stream>>>(Tp, Ap, rnt, rna, logK, inv_eps);
    k_zero<<<192, 256, 0, stream>>>(lu, 16384 + 32768);
    for (int it = 0; it < 10; it++) {
        k_rowlse<<<NRT, 256, 0, stream>>>(logK, lv, lu);
        k_collse<<<dim3(LA / 64, NB), 256, 0, stream>>>(logK, lu, lv);
    }
    k_pigemm<<<dim3(D_ / 128, LT / 64, NB), 256, 0, stream>>>(logK, Ap, lu, lv, Aal);
    k_sresid<<<NRT, 256, 0, stream>>>(Tp, Aal, resid, Sb);
    k_router1<<<dim3(D_ / 64, NRT / 64), 256, 0, stream>>>(resid, Wr1, br1, Sb, H);
    k_router2<<<NRT, 256, 0, stream>>>(H, Wr2, br2, Gb);
    for (int e = 0; e < 3; e++) {
        const float* cw = (e == 0) ? cw1 : ((e == 1) ? cw3 : cw5);
        int ksz = (e == 0) ? 1 : ((e == 1) ? 3 : 5);
        k_down<<<NRT / 8, 256, 0, stream>>>(resid, down_W + (long)e * 64 * 256, down_b + e * 64, hb);
        k_conv<<<NRT / 64, 256, 0, stream>>>(hb, cw, conv_b + e * 64, hcb, ksz);
        k_up<<<NRT / 8, 256, 0, stream>>>(hcb, up_W + (long)e * 256 * 64, up_b + e * 256,
                                          resid, en_g + e * 256, en_b + e * 256,
                                          Gb + (long)e * NRT, (float*)d_out, e == 0 ? 1 : 0);
    }
}

// Round 3
// 1238.032 us; speedup vs baseline: 2.1257x; 1.3601x over previous
//
#include <hip/hip_runtime.h>
#include <cstdio>

#define D_ 256
#define LT 1024
#define LA 2048
#define NB 16
#define RR_ 64
#define NRT (NB*LT)   // 16384 text rows
#define NRA (NB*LA)   // 32768 audio rows

typedef short bf16x8 __attribute__((ext_vector_type(8)));
typedef float f32x4 __attribute__((ext_vector_type(4)));

__device__ __forceinline__ float gelu_f(float x) {
    return 0.5f * x * (1.0f + erff(x * 0.70710678118654752f));
}
__device__ __forceinline__ float bf2f(unsigned short u) {
    union { unsigned int i; float f; } c; c.i = ((unsigned int)u) << 16; return c.f;
}
__device__ __forceinline__ unsigned short f2bf(float f) {   // RNE
    union { float f; unsigned int i; } c; c.f = f;
    unsigned int x = c.i;
    return (unsigned short)((x + 0x7fffu + ((x >> 16) & 1u)) >> 16);
}

// ---------------- K1: LayerNorm + shared projection ----------------
// Outputs: Pf fp32 [row][256] (optional), Nb bf16 normalized [row][256],
//          PT bf16 unnormalized transposed [b][256][Lseq] (optional).
__global__ __launch_bounds__(256) void k_lnproj(
    const float* __restrict__ X, const float* __restrict__ g, const float* __restrict__ bln,
    const float* __restrict__ W, const float* __restrict__ bsh,
    float* __restrict__ Pf, unsigned short* __restrict__ Nb,
    unsigned short* __restrict__ PT, int Lseq)
{
    __shared__ float xh[8][256];
    int tid = threadIdx.x;
    long blk = blockIdx.x;
    int r = tid >> 5, lane = tid & 31;
    long row = blk * 8 + r;
    const float* xp = X + row * D_;
    float v[8];
    float s = 0.f;
#pragma unroll
    for (int j = 0; j < 8; j++) { v[j] = xp[lane + 32 * j]; s += v[j]; }
#pragma unroll
    for (int off = 16; off >= 1; off >>= 1) s += __shfl_xor(s, off, 32);
    float mean = s * (1.0f / 256.0f);
    float q = 0.f;
#pragma unroll
    for (int j = 0; j < 8; j++) { float d = v[j] - mean; q += d * d; }
#pragma unroll
    for (int off = 16; off >= 1; off >>= 1) q += __shfl_xor(q, off, 32);
    float ivar = rsqrtf(q * (1.0f / 256.0f) + 1e-5f);
#pragma unroll
    for (int j = 0; j < 8; j++) {
        int c = lane + 32 * j;
        xh[r][c] = (v[j] - mean) * ivar * g[c] + bln[c];
    }
    __syncthreads();
    // phase 2: thread owns output column c for all 8 rows
    int c = tid;
    float acc[8];
    float bv = bsh[c];
#pragma unroll
    for (int rr = 0; rr < 8; rr++) acc[rr] = bv;
    const float4* W4 = (const float4*)(W + (long)c * D_);
    for (int k4 = 0; k4 < 64; k4++) {
        float4 w = W4[k4];
#pragma unroll
        for (int rr = 0; rr < 8; rr++) {
            float4 xv = *(const float4*)&xh[rr][k4 * 4];
            acc[rr] += xv.x * w.x + xv.y * w.y + xv.z * w.z + xv.w * w.w;
        }
    }
    __syncthreads();   // all xh reads done
#pragma unroll
    for (int rr = 0; rr < 8; rr++) xh[rr][c] = acc[rr] * acc[rr];
    __syncthreads();
    for (int sr = 128; sr >= 1; sr >>= 1) {
        if (c < sr) {
#pragma unroll
            for (int rr = 0; rr < 8; rr++) xh[rr][c] += xh[rr][c + sr];
        }
        __syncthreads();
    }
    float rinvs[8];
#pragma unroll
    for (int rr = 0; rr < 8; rr++) rinvs[rr] = 1.0f / fmaxf(sqrtf(xh[rr][0]), 1e-12f);
    long row0 = blk * 8;
#pragma unroll
    for (int rr = 0; rr < 8; rr++) {
        if (Pf) Pf[(row0 + rr) * D_ + c] = acc[rr];
        Nb[(row0 + rr) * D_ + c] = f2bf(acc[rr] * rinvs[rr]);
    }
    if (PT) {
        int bb = (int)(row0 / Lseq);
        int n0l = (int)(row0 % Lseq);
        unsigned int t[8];
#pragma unroll
        for (int rr = 0; rr < 8; rr++) t[rr] = f2bf(acc[rr]);
        int4 ov;
        ov.x = (int)(t[0] | (t[1] << 16));
        ov.y = (int)(t[2] | (t[3] << 16));
        ov.z = (int)(t[4] | (t[5] << 16));
        ov.w = (int)(t[6] | (t[7] << 16));
        *(int4*)(PT + ((long)bb * D_ + c) * Lseq + n0l) = ov;
    }
}

// ---------------- K2: cost GEMM (MFMA bf16) -> logK bf16 ----------------
// 128x128 tile, K=256 in 8 steps of 32. 4 waves, each 64x64 (4x4 mfma tiles).
__global__ __launch_bounds__(256) void k_cost_mfma(
    const unsigned short* __restrict__ Tnb, const unsigned short* __restrict__ Anb,
    unsigned short* __restrict__ logKb, float inv_eps)
{
    __shared__ short As[128][48];   // [m][k] pad 32->48 shorts
    __shared__ short Bs[128][48];   // [n][k]
    int b = blockIdx.z;
    int m_blk = blockIdx.y * 128, n_blk = blockIdx.x * 128;
    int tid = threadIdx.x;
    int wid = tid >> 6, lane = tid & 63;
    int l15 = lane & 15, kq = lane >> 4;
    int wm0 = (wid >> 1) * 64, wn0 = (wid & 1) * 64;
    const unsigned short* Ab = Tnb + ((long)b * LT + m_blk) * D_;
    const unsigned short* Bb = Anb + ((long)b * LA + n_blk) * D_;
    f32x4 acc[4][4];
#pragma unroll
    for (int i = 0; i < 4; i++)
#pragma unroll
        for (int j = 0; j < 4; j++) acc[i][j] = (f32x4){0.f, 0.f, 0.f, 0.f};
    for (int kt = 0; kt < 8; kt++) {
        int k0 = kt * 32;
#pragma unroll
        for (int h = 0; h < 2; h++) {
            int idx = tid + 256 * h;
            int row = idx >> 2, ch = idx & 3;
            *(int4*)&As[row][ch * 8] = *(const int4*)(Ab + (long)row * D_ + k0 + ch * 8);
            *(int4*)&Bs[row][ch * 8] = *(const int4*)(Bb + (long)row * D_ + k0 + ch * 8);
        }
        __syncthreads();
        bf16x8 af[4], bfv[4];
#pragma unroll
        for (int i = 0; i < 4; i++) af[i] = *(const bf16x8*)&As[wm0 + i * 16 + l15][kq * 8];
#pragma unroll
        for (int j = 0; j < 4; j++) bfv[j] = *(const bf16x8*)&Bs[wn0 + j * 16 + l15][kq * 8];
#pragma unroll
        for (int i = 0; i < 4; i++)
#pragma unroll
            for (int j = 0; j < 4; j++)
                acc[i][j] = __builtin_amdgcn_mfma_f32_16x16x32_bf16(af[i], bfv[j], acc[i][j], 0, 0, 0);
        __syncthreads();
    }
#pragma unroll
    for (int i = 0; i < 4; i++) {
#pragma unroll
        for (int r = 0; r < 4; r++) {
            int m = m_blk + wm0 + i * 16 + kq * 4 + r;
            long base = ((long)b * LT + m) * (long)LA + n_blk;
#pragma unroll
            for (int j = 0; j < 4; j++) {
                int n = wn0 + j * 16 + l15;
                logKb[base + n] = f2bf((acc[i][j][r] - 1.0f) * inv_eps);
            }
        }
    }
}

// ---------------- K3: row sum-exp -> lu (no max needed: args in [-35,0]) ----------------
__global__ __launch_bounds__(256) void k_rowlse(
    const unsigned short* __restrict__ logKb, const float* __restrict__ lv, float* __restrict__ lu)
{
    __shared__ float red[4];
    long blk = blockIdx.x;             // b*LT + m
    int b = (int)(blk >> 10);
    const unsigned short* p = logKb + blk * (long)LA;
    const float* lvp = lv + (long)b * LA;
    int tid = threadIdx.x;
    int4 raw = *(const int4*)(p + tid * 8);
    unsigned int w[4] = { (unsigned int)raw.x, (unsigned int)raw.y, (unsigned int)raw.z, (unsigned int)raw.w };
    float4 l0 = *(const float4*)(lvp + tid * 8);
    float4 l1 = *(const float4*)(lvp + tid * 8 + 4);
    float lvv[8] = { l0.x, l0.y, l0.z, l0.w, l1.x, l1.y, l1.z, l1.w };
    float s = 0.f;
#pragma unroll
    for (int j = 0; j < 8; j++) {
        float v = bf2f((unsigned short)((w[j >> 1] >> ((j & 1) * 16)) & 0xffffu)) + lvv[j];
        s += __expf(v);
    }
#pragma unroll
    for (int off = 32; off >= 1; off >>= 1) s += __shfl_xor(s, off);
    if ((tid & 63) == 0) red[tid >> 6] = s;
    __syncthreads();
    if (tid == 0) lu[blk] = -6.9314718055994531f - __logf(red[0] + red[1] + red[2] + red[3]);
}

// ---------------- K4: col sum-exp -> lv ----------------
__global__ __launch_bounds__(256) void k_collse(
    const unsigned short* __restrict__ logKb, const float* __restrict__ lu, float* __restrict__ lv)
{
    __shared__ float lus[1024];
    __shared__ float redS[4][128];
    int b = blockIdx.y;
    int n0 = blockIdx.x * 128;
    int tid = threadIdx.x;
    for (int i = tid; i < 1024; i += 256) lus[i] = lu[(long)b * LT + i];
    __syncthreads();
    int c2 = (tid & 63) * 2;
    int g = tid >> 6;
    const unsigned short* base = logKb + (long)b * LT * LA + n0 + c2;
    float S0 = 0.f, S1 = 0.f;
#pragma unroll 4
    for (int m = g; m < 1024; m += 4) {
        unsigned int raw = *(const unsigned int*)(base + (long)m * LA);
        float lm = lus[m];
        S0 += __expf(bf2f((unsigned short)(raw & 0xffffu)) + lm);
        S1 += __expf(bf2f((unsigned short)(raw >> 16)) + lm);
    }
    redS[g][c2] = S0; redS[g][c2 + 1] = S1;
    __syncthreads();
    if (tid < 128) {
        float s = redS[0][tid] + redS[1][tid] + redS[2][tid] + redS[3][tid];
        lv[(long)b * LA + n0 + tid] = -7.6246189861593985f - __logf(s);
    }
}

// ---------------- K5: A_al = pi @ Ap (MFMA; exp fused into A staging) ----------------
// 64(m) x 128(d) tile, gemm-K = n (2048) in 64 steps of 32.
__global__ __launch_bounds__(256) void k_pi_mfma(
    const unsigned short* __restrict__ logKb, const unsigned short* __restrict__ ApbT,
    const float* __restrict__ lu, const float* __restrict__ lv, float* __restrict__ Aal)
{
    __shared__ short As[64][48];    // pi [m][n-k]
    __shared__ short Bs[128][48];   // ApT [d][n-k]
    __shared__ float lv_s[2048];
    __shared__ float lu_s[64];
    int b = blockIdx.z;
    int m_blk = blockIdx.y * 64;
    int d_blk = blockIdx.x * 128;
    int tid = threadIdx.x;
    for (int i = tid; i < 2048; i += 256) lv_s[i] = lv[(long)b * LA + i];
    if (tid < 64) lu_s[tid] = lu[(long)b * LT + m_blk + tid];
    __syncthreads();
    int wid = tid >> 6, lane = tid & 63;
    int l15 = lane & 15, kq = lane >> 4;
    int wm0 = (wid & 1) * 32, wd0 = (wid >> 1) * 64;
    f32x4 acc[2][4];
#pragma unroll
    for (int i = 0; i < 2; i++)
#pragma unroll
        for (int j = 0; j < 4; j++) acc[i][j] = (f32x4){0.f, 0.f, 0.f, 0.f};
    const unsigned short* Kbase = logKb + ((long)b * LT + m_blk) * (long)LA;
    const unsigned short* Bbase = ApbT + ((long)b * D_ + d_blk) * (long)LA;
    int arow = tid >> 2, ach = tid & 3;
    for (int kt = 0; kt < 64; kt++) {
        int n0 = kt * 32;
        {   // A: pi tile 64x32 with exp
            int4 raw = *(const int4*)(Kbase + (long)arow * LA + n0 + ach * 8);
            unsigned int w[4] = { (unsigned int)raw.x, (unsigned int)raw.y, (unsigned int)raw.z, (unsigned int)raw.w };
            float lum = lu_s[arow];
            const float* lvp = &lv_s[n0 + ach * 8];
            unsigned int o[8];
#pragma unroll
            for (int j = 0; j < 8; j++) {
                float v = bf2f((unsigned short)((w[j >> 1] >> ((j & 1) * 16)) & 0xffffu)) + lum + lvp[j];
                o[j] = f2bf(__expf(v));
            }
            int4 ov;
            ov.x = (int)(o[0] | (o[1] << 16));
            ov.y = (int)(o[2] | (o[3] << 16));
            ov.z = (int)(o[4] | (o[5] << 16));
            ov.w = (int)(o[6] | (o[7] << 16));
            *(int4*)&As[arow][ach * 8] = ov;
        }
#pragma unroll
        for (int h = 0; h < 2; h++) {   // B: 128x32
            int idx = tid + 256 * h;
            int row = idx >> 2, ch = idx & 3;
            *(int4*)&Bs[row][ch * 8] = *(const int4*)(Bbase + (long)row * LA + n0 + ch * 8);
        }
        __syncthreads();
        bf16x8 af[2], bfv[4];
        af[0] = *(const bf16x8*)&As[wm0 + l15][kq * 8];
        af[1] = *(const bf16x8*)&As[wm0 + 16 + l15][kq * 8];
#pragma unroll
        for (int j = 0; j < 4; j++) bfv[j] = *(const bf16x8*)&Bs[wd0 + j * 16 + l15][kq * 8];
#pragma unroll
        for (int i = 0; i < 2; i++)
#pragma unroll
            for (int j = 0; j < 4; j++)
                acc[i][j] = __builtin_amdgcn_mfma_f32_16x16x32_bf16(af[i], bfv[j], acc[i][j], 0, 0, 0);
        __syncthreads();
    }
#pragma unroll
    for (int i = 0; i < 2; i++) {
#pragma unroll
        for (int r = 0; r < 4; r++) {
            int m = m_blk + wm0 + i * 16 + kq * 4 + r;
            long obase = ((long)b * LT + m) * D_ + d_blk;
#pragma unroll
            for (int j = 0; j < 4; j++)
                Aal[obase + wd0 + j * 16 + l15] = acc[i][j][r];
        }
    }
}

// ---------------- K6: S = <Tp, A_al>, resid = |Tp - A_al| ----------------
__global__ __launch_bounds__(256) void k_sresid(
    const float* __restrict__ Tp, const float* __restrict__ Aal,
    float* __restrict__ resid, float* __restrict__ S)
{
    __shared__ float red[4];
    long row = blockIdx.x;
    int tid = threadIdx.x;
    float t = Tp[row * D_ + tid], a = Aal[row * D_ + tid];
    resid[row * D_ + tid] = fabsf(t - a);
    float p = t * a;
#pragma unroll
    for (int off = 32; off >= 1; off >>= 1) p += __shfl_xor(p, off);
    if ((tid & 63) == 0) red[tid >> 6] = p;
    __syncthreads();
    if (tid == 0) S[row] = red[0] + red[1] + red[2] + red[3];
}

// ---------------- K7a: H = gelu([S,resid] @ Wr1^T + br1) ----------------
__global__ __launch_bounds__(256) void k_router1(
    const float* __restrict__ resid, const float* __restrict__ Wr1,
    const float* __restrict__ br1, const float* __restrict__ S,
    float* __restrict__ H)
{
    __shared__ float As[32][68];
    __shared__ float Bs[32][68];
    int m0 = blockIdx.y * 64;
    int n0 = blockIdx.x * 64;
    const float* Aptr = resid + (long)m0 * D_;
    int tid = threadIdx.x;
    int tx = tid & 15, ty = tid >> 4;
    float acc[4][4] = {};
    for (int kt = 0; kt < 8; kt++) {
        int k0 = kt * 32;
#pragma unroll
        for (int h = 0; h < 2; h++) {
            int chunk = tid + 256 * h;
            int rowi = chunk >> 3, kc = chunk & 7;
            float4 a = *(const float4*)(Aptr + (long)rowi * D_ + k0 + kc * 4);
            As[kc * 4 + 0][rowi] = a.x; As[kc * 4 + 1][rowi] = a.y;
            As[kc * 4 + 2][rowi] = a.z; As[kc * 4 + 3][rowi] = a.w;
            const float* wrow = Wr1 + (long)(n0 + rowi) * 257 + 1 + k0 + kc * 4;
            Bs[kc * 4 + 0][rowi] = wrow[0]; Bs[kc * 4 + 1][rowi] = wrow[1];
            Bs[kc * 4 + 2][rowi] = wrow[2]; Bs[kc * 4 + 3][rowi] = wrow[3];
        }
        __syncthreads();
#pragma unroll
        for (int kk = 0; kk < 32; kk++) {
            float4 av = *(const float4*)&As[kk][ty * 4];
            float4 bv = *(const float4*)&Bs[kk][tx * 4];
            float aa[4] = { av.x, av.y, av.z, av.w };
            float bb4[4] = { bv.x, bv.y, bv.z, bv.w };
#pragma unroll
            for (int i = 0; i < 4; i++)
#pragma unroll
                for (int j = 0; j < 4; j++) acc[i][j] += aa[i] * bb4[j];
        }
        __syncthreads();
    }
#pragma unroll
    for (int i = 0; i < 4; i++) {
        int m = m0 + ty * 4 + i;
        float sm = S[m];
#pragma unroll
        for (int j = 0; j < 4; j++) {
            int n = n0 + tx * 4 + j;
            float val = acc[i][j] + sm * Wr1[(long)n * 257] + br1[n];
            H[(long)m * D_ + n] = gelu_f(val);
        }
    }
}

// ---------------- K7b: logits + softmax -> G planes [3][16384] ----------------
__global__ __launch_bounds__(256) void k_router2(
    const float* __restrict__ H, const float* __restrict__ Wr2,
    const float* __restrict__ br2, float* __restrict__ G)
{
    __shared__ float rd[3][4];
    long row = blockIdx.x;
    int tid = threadIdx.x;
    float h = H[row * D_ + tid];
    float l0 = h * Wr2[tid], l1 = h * Wr2[256 + tid], l2 = h * Wr2[512 + tid];
#pragma unroll
    for (int off = 32; off >= 1; off >>= 1) {
        l0 += __shfl_xor(l0, off); l1 += __shfl_xor(l1, off); l2 += __shfl_xor(l2, off);
    }
    if ((tid & 63) == 0) { int w = tid >> 6; rd[0][w] = l0; rd[1][w] = l1; rd[2][w] = l2; }
    __syncthreads();
    if (tid == 0) {
        float L0 = rd[0][0] + rd[0][1] + rd[0][2] + rd[0][3] + br2[0];
        float L1 = rd[1][0] + rd[1][1] + rd[1][2] + rd[1][3] + br2[1];
        float L2 = rd[2][0] + rd[2][1] + rd[2][2] + rd[2][3] + br2[2];
        float mx = fmaxf(L0, fmaxf(L1, L2));
        float e0 = __expf(L0 - mx), e1 = __expf(L1 - mx), e2 = __expf(L2 - mx);
        float inv = 1.0f / (e0 + e1 + e2);
        G[row] = e0 * inv; G[NRT + row] = e1 * inv; G[2 * NRT + row] = e2 * inv;
    }
}

// ---------------- K8a: h = gelu(resid @ down_W^T + down_b) ----------------
__global__ __launch_bounds__(256) void k_down(
    const float* __restrict__ resid, const float* __restrict__ dW,
    const float* __restrict__ db, float* __restrict__ h)
{
    __shared__ float rs[8][256];
    long row0 = (long)blockIdx.x * 8;
    int tid = threadIdx.x;
    for (int idx = tid; idx < 8 * 256; idx += 256) rs[idx >> 8][idx & 255] = resid[row0 * D_ + idx];
    __syncthreads();
    int j = tid & 63, rg = tid >> 6;
    const float4* w4 = (const float4*)(dW + (long)j * D_);
    float a0 = db[j], a1 = a0;
    for (int k4 = 0; k4 < 64; k4++) {
        float4 w = w4[k4];
        float4 x0 = *(const float4*)&rs[rg * 2][k4 * 4];
        float4 x1 = *(const float4*)&rs[rg * 2 + 1][k4 * 4];
        a0 += x0.x * w.x + x0.y * w.y + x0.z * w.z + x0.w * w.w;
        a1 += x1.x * w.x + x1.y * w.y + x1.z * w.z + x1.w * w.w;
    }
    h[(row0 + rg * 2) * RR_ + j] = gelu_f(a0);
    h[(row0 + rg * 2 + 1) * RR_ + j] = gelu_f(a1);
}

// ---------------- K8b: depth-conv over sequence (tap-sliced LDS GEMM) ----------------
__global__ __launch_bounds__(256) void k_conv(
    const float* __restrict__ h, const float* __restrict__ w,
    const float* __restrict__ cb, float* __restrict__ hc, int ksz)
{
    __shared__ float hs[68][68];
    __shared__ float wt[64][64];
    int blk = blockIdx.x;
    int b = blk >> 4, m0 = (blk & 15) * 64;
    int tid = threadIdx.x;
    int pad = (ksz - 1) >> 1;
    for (int idx = tid; idx < 68 * 16; idx += 256) {
        int mr = idx >> 4, i4 = idx & 15;
        int mm = m0 - 2 + mr;
        float4 vv = { 0.f, 0.f, 0.f, 0.f };
        if (mm >= 0 && mm < LT) vv = *(const float4*)(h + ((long)b * LT + mm) * RR_ + i4 * 4);
        *(float4*)&hs[mr][i4 * 4] = vv;
    }
    int tx = tid & 15, ty = tid >> 4;
    float acc[4][4] = {};
    for (int t = 0; t < ksz; t++) {
        __syncthreads();
        for (int idx = tid; idx < 4096; idx += 256) {
            int i = idx & 63, j = idx >> 6;
            wt[i][j] = w[(long)j * RR_ * ksz + i * ksz + t];
        }
        __syncthreads();
        int roff = ty * 4 + 2 + t - pad;
        for (int i4 = 0; i4 < 16; i4++) {
            float4 h0 = *(const float4*)&hs[roff + 0][i4 * 4];
            float4 h1 = *(const float4*)&hs[roff + 1][i4 * 4];
            float4 h2 = *(const float4*)&hs[roff + 2][i4 * 4];
            float4 h3 = *(const float4*)&hs[roff + 3][i4 * 4];
            float hh[4][4] = { { h0.x, h0.y, h0.z, h0.w }, { h1.x, h1.y, h1.z, h1.w },
                               { h2.x, h2.y, h2.z, h2.w }, { h3.x, h3.y, h3.z, h3.w } };
#pragma unroll
            for (int s = 0; s < 4; s++) {
                float4 wv = *(const float4*)&wt[i4 * 4 + s][tx * 4];
#pragma unroll
                for (int r = 0; r < 4; r++) {
                    acc[r][0] += hh[r][s] * wv.x;
                    acc[r][1] += hh[r][s] * wv.y;
                    acc[r][2] += hh[r][s] * wv.z;
                    acc[r][3] += hh[r][s] * wv.w;
                }
            }
        }
    }
    float4 bb = *(const float4*)(cb + tx * 4);
#pragma unroll
    for (int r = 0; r < 4; r++) {
        long m = (long)b * LT + m0 + ty * 4 + r;
        float4 o;
        o.x = gelu_f(acc[r][0] + bb.x);
        o.y = gelu_f(acc[r][1] + bb.y);
        o.z = gelu_f(acc[r][2] + bb.z);
        o.w = gelu_f(acc[r][3] + bb.w);
        *(float4*)(hc + m * RR_ + tx * 4) = o;
    }
}

// ---------------- K8c: up-proj + residual + LN + gated accumulate ----------------
__global__ __launch_bounds__(256) void k_up(
    const float* __restrict__ hc, const float* __restrict__ uW, const float* __restrict__ ub,
    const float* __restrict__ resid, const float* __restrict__ eg, const float* __restrict__ eb,
    const float* __restrict__ G, float* __restrict__ out, int isFirst)
{
    __shared__ float hs[8][64];
    __shared__ float red[8][256];
    long row0 = (long)blockIdx.x * 8;
    int tid = threadIdx.x;
    for (int idx = tid; idx < 512; idx += 256) hs[idx >> 6][idx & 63] = hc[row0 * RR_ + idx];
    __syncthreads();
    int c = tid;
    const float4* w4 = (const float4*)(uW + (long)c * RR_);
    float v[8];
    float ubc = ub[c];
#pragma unroll
    for (int r = 0; r < 8; r++) v[r] = ubc;
    for (int k4 = 0; k4 < 16; k4++) {
        float4 w = w4[k4];
#pragma unroll
        for (int r = 0; r < 8; r++) {
            float4 x = *(const float4*)&hs[r][k4 * 4];
            v[r] += x.x * w.x + x.y * w.y + x.z * w.z + x.w * w.w;
        }
    }
#pragma unroll
    for (int r = 0; r < 8; r++) v[r] += resid[(row0 + r) * D_ + c];
#pragma unroll
    for (int r = 0; r < 8; r++) red[r][c] = v[r];
    __syncthreads();
    for (int sr = 128; sr >= 1; sr >>= 1) {
        if (c < sr) {
#pragma unroll
            for (int r = 0; r < 8; r++) red[r][c] += red[r][c + sr];
        }
        __syncthreads();
    }
    float mn[8];
#pragma unroll
    for (int r = 0; r < 8; r++) mn[r] = red[r][0] * (1.0f / 256.0f);
    __syncthreads();
#pragma unroll
    for (int r = 0; r < 8; r++) { float d = v[r] - mn[r]; red[r][c] = d * d; }
    __syncthreads();
    for (int sr = 128; sr >= 1; sr >>= 1) {
        if (c < sr) {
#pragma unroll
            for (int r = 0; r < 8; r++) red[r][c] += red[r][c + sr];
        }
        __syncthreads();
    }
#pragma unroll
    for (int r = 0; r < 8; r++) {
        float var = red[r][0] * (1.0f / 256.0f);
        float iv = rsqrtf(var + 1e-5f);
        float eo = (v[r] - mn[r]) * iv * eg[c] + eb[c];
        float gc = G[row0 + r];
        long o = (row0 + r) * D_ + c;
        if (isFirst) out[o] = gc * eo;
        else out[o] += gc * eo;
    }
}

__global__ void k_zero(float* p, int n) {
    int i = blockIdx.x * 256 + threadIdx.x;
    if (i < n) p[i] = 0.f;
}

extern "C" void kernel_launch(void* const* d_in, const int* in_sizes, int n_in,
                              void* d_out, int out_size, void* d_ws, size_t ws_size,
                              hipStream_t stream)
{
    const float* text   = (const float*)d_in[0];
    const float* audio  = (const float*)d_in[1];
    const float* ln_g   = (const float*)d_in[2];
    const float* ln_b   = (const float*)d_in[3];
    const float* W_sh   = (const float*)d_in[4];
    const float* b_sh   = (const float*)d_in[5];
    const float* Wr1    = (const float*)d_in[6];
    const float* br1    = (const float*)d_in[7];
    const float* Wr2    = (const float*)d_in[8];
    const float* br2    = (const float*)d_in[9];
    const float* down_W = (const float*)d_in[10];
    const float* down_b = (const float*)d_in[11];
    const float* cw1    = (const float*)d_in[12];
    const float* cw3    = (const float*)d_in[13];
    const float* cw5    = (const float*)d_in[14];
    const float* conv_b = (const float*)d_in[15];
    const float* up_W   = (const float*)d_in[16];
    const float* up_b   = (const float*)d_in[17];
    const float* en_g   = (const float*)d_in[18];
    const float* en_b   = (const float*)d_in[19];

    float* ws = (float*)d_ws;
    float*          Tp    = ws;                               // 4,194,304 f
    unsigned short* Tnb   = (unsigned short*)(ws + 4194304);  // 4,194,304 bf16
    unsigned short* Anb   = (unsigned short*)(ws + 6291456);  // 8,388,608 bf16
    unsigned short* ApbT  = (unsigned short*)(ws + 10485760); // 8,388,608 bf16 [b][d][n]
    unsigned short* logKb = (unsigned short*)(ws + 14680064); // 33,554,432 bf16
    float*          Aal   = ws + 31457280;                    // 4,194,304 f
    float*          resid = ws + 35651584;                    // 4,194,304 f
    float*          lu    = ws + 39845888;                    // 16,384 f
    float*          lv    = ws + 39862272;                    // 32,768 f
    float*          Sb    = ws + 39895040;                    // 16,384 f
    float*          Gb    = ws + 39911424;                    // 49,152 f
    size_t need_bytes = (size_t)39960576 * 4;
    if (ws_size < need_bytes) {
        fprintf(stderr, "kernel_launch: ws_size %zu < needed %zu\n", ws_size, need_bytes);
        return;
    }
    // aliases (logKb region dead after k_pi_mfma)
    float* H   = ws + 14680064;          // router hidden, 4.19M f
    float* hb  = H + 4194304;            // expert h, 1.05M f
    float* hcb = hb + 1048576;           // expert hc, 1.05M f

    const float inv_eps = (float)(1.0 / (0.1 + 1e-8));

    k_lnproj<<<NRT / 8, 256, 0, stream>>>(text, ln_g, ln_b, W_sh, b_sh, Tp, Tnb, nullptr, LT);
    k_lnproj<<<NRA / 8, 256, 0, stream>>>(audio, ln_g, ln_b, W_sh, b_sh, nullptr, Anb, ApbT, LA);
    k_cost_mfma<<<dim3(LA / 128, LT / 128, NB), 256, 0, stream>>>(Tnb, Anb, logKb, inv_eps);
    k_zero<<<192, 256, 0, stream>>>(lu, 16384 + 32768);
    for (int it = 0; it < 10; it++) {
        k_rowlse<<<NRT, 256, 0, stream>>>(logKb, lv, lu);
        k_collse<<<dim3(LA / 128, NB), 256, 0, stream>>>(logKb, lu, lv);
    }
    k_pi_mfma<<<dim3(D_ / 128, LT / 64, NB), 256, 0, stream>>>(logKb, ApbT, lu, lv, Aal);
    k_sresid<<<NRT, 256, 0, stream>>>(Tp, Aal, resid, Sb);
    k_router1<<<dim3(D_ / 64, NRT / 64), 256, 0, stream>>>(resid, Wr1, br1, Sb, H);
    k_router2<<<NRT, 256, 0, stream>>>(H, Wr2, br2, Gb);
    for (int e = 0; e < 3; e++) {
        const float* cw = (e == 0) ? cw1 : ((e == 1) ? cw3 : cw5);
        int ksz = (e == 0) ? 1 : ((e == 1) ? 3 : 5);
        k_down<<<NRT / 8, 256, 0, stream>>>(resid, down_W + (long)e * 64 * 256, down_b + e * 64, hb);
        k_conv<<<NRT / 64, 256, 0, stream>>>(hb, cw, conv_b + e * 64, hcb, ksz);
        k_up<<<NRT / 8, 256, 0, stream>>>(hcb, up_W + (long)e * 256 * 64, up_b + e * 256,
                                          resid, en_g + e * 256, en_b + e * 256,
                                          Gb + (long)e * NRT, (float*)d_out, e == 0 ? 1 : 0);
    }
}

// Round 4
// 1052.490 us; speedup vs baseline: 2.5004x; 1.1763x over previous
//
#include <hip/hip_runtime.h>
#include <cstdio>

#define D_ 256
#define LT 1024
#define LA 2048
#define NB 16
#define RR_ 64
#define NRT (NB*LT)   // 16384 text rows
#define NRA (NB*LA)   // 32768 audio rows

typedef short bf16x8 __attribute__((ext_vector_type(8)));
typedef float f32x4 __attribute__((ext_vector_type(4)));

__device__ __forceinline__ float gelu_f(float x) {
    return 0.5f * x * (1.0f + erff(x * 0.70710678118654752f));
}
__device__ __forceinline__ float bf2f(unsigned short u) {
    union { unsigned int i; float f; } c; c.i = ((unsigned int)u) << 16; return c.f;
}
__device__ __forceinline__ unsigned short f2bf(float f) {   // RNE
    union { float f; unsigned int i; } c; c.f = f;
    unsigned int x = c.i;
    return (unsigned short)((x + 0x7fffu + ((x >> 16) & 1u)) >> 16);
}

// ---------------- K0: W_sh -> bf16 once ----------------
__global__ __launch_bounds__(256) void k_prep_w(const float* __restrict__ W, unsigned short* __restrict__ Wb) {
    int i = blockIdx.x * 256 + threadIdx.x;
    Wb[i] = f2bf(W[i]);
}

// ---------------- K1: LayerNorm + shared projection (MFMA) ----------------
// 64 rows/block. LN -> xb bf16 in LDS; GEMM vs Wb (bf16, staged per k-chunk);
// per-wave 16-row band x full 256 cols so row-norm reduces in-wave.
// Outputs: Pf fp32 (optional), Nb bf16 normalized, PT bf16 transposed [b][c][n] (optional).
__global__ __launch_bounds__(256) void k_lnproj_mfma(
    const float* __restrict__ X, const float* __restrict__ g, const float* __restrict__ bln,
    const unsigned short* __restrict__ Wb, const float* __restrict__ bsh,
    float* __restrict__ Pf, unsigned short* __restrict__ Nb,
    unsigned short* __restrict__ PT, int Lseq)
{
    __shared__ short xb[64][264];   // [row][k] bf16, stride 264 (16B-aligned rows)
    __shared__ short Bs[256][40];   // [out col n][k-chunk 32] bf16
    int tid = threadIdx.x;
    long row0 = (long)blockIdx.x * 64;
    // ---- LN phase: 8 iterations of 8 rows; 32 lanes per row ----
    {
        int lane = tid & 31, rg = tid >> 5;
        float4 ga = *(const float4*)(g + lane * 8);
        float4 gb2 = *(const float4*)(g + lane * 8 + 4);
        float4 ba = *(const float4*)(bln + lane * 8);
        float4 bb2 = *(const float4*)(bln + lane * 8 + 4);
        for (int it = 0; it < 8; it++) {
            int r = it * 8 + rg;
            const float4* xp4 = (const float4*)(X + (row0 + r) * D_);
            float4 a = xp4[lane * 2], b = xp4[lane * 2 + 1];
            float s = a.x + a.y + a.z + a.w + b.x + b.y + b.z + b.w;
#pragma unroll
            for (int off = 16; off >= 1; off >>= 1) s += __shfl_xor(s, off);
            float mean = s * (1.0f / 256.0f);
            float q = (a.x - mean) * (a.x - mean) + (a.y - mean) * (a.y - mean)
                    + (a.z - mean) * (a.z - mean) + (a.w - mean) * (a.w - mean)
                    + (b.x - mean) * (b.x - mean) + (b.y - mean) * (b.y - mean)
                    + (b.z - mean) * (b.z - mean) + (b.w - mean) * (b.w - mean);
#pragma unroll
            for (int off = 16; off >= 1; off >>= 1) q += __shfl_xor(q, off);
            float ivar = rsqrtf(q * (1.0f / 256.0f) + 1e-5f);
            unsigned int u0 = f2bf((a.x - mean) * ivar * ga.x + ba.x);
            unsigned int u1 = f2bf((a.y - mean) * ivar * ga.y + ba.y);
            unsigned int u2 = f2bf((a.z - mean) * ivar * ga.z + ba.z);
            unsigned int u3 = f2bf((a.w - mean) * ivar * ga.w + ba.w);
            unsigned int u4 = f2bf((b.x - mean) * ivar * gb2.x + bb2.x);
            unsigned int u5 = f2bf((b.y - mean) * ivar * gb2.y + bb2.y);
            unsigned int u6 = f2bf((b.z - mean) * ivar * gb2.z + bb2.z);
            unsigned int u7 = f2bf((b.w - mean) * ivar * gb2.w + bb2.w);
            int4 pv;
            pv.x = (int)(u0 | (u1 << 16)); pv.y = (int)(u2 | (u3 << 16));
            pv.z = (int)(u4 | (u5 << 16)); pv.w = (int)(u6 | (u7 << 16));
            *(int4*)&xb[r][lane * 8] = pv;
        }
    }
    __syncthreads();
    // ---- GEMM phase ----
    int wid = tid >> 6, lane = tid & 63;
    int l15 = lane & 15, kq = lane >> 4;
    int m_local = wid * 16;
    f32x4 acc[16];
#pragma unroll
    for (int j = 0; j < 16; j++) acc[j] = (f32x4){0.f, 0.f, 0.f, 0.f};
    for (int kt = 0; kt < 8; kt++) {
        int k0 = kt * 32;
#pragma unroll
        for (int h = 0; h < 4; h++) {
            int idx = tid + 256 * h;        // 1024 chunks of 8 shorts
            int n = idx >> 2, qc = idx & 3;
            *(int4*)&Bs[n][qc * 8] = *(const int4*)(Wb + (long)n * D_ + k0 + qc * 8);
        }
        __syncthreads();
        bf16x8 af = *(const bf16x8*)&xb[m_local + l15][k0 + kq * 8];
#pragma unroll
        for (int j = 0; j < 16; j++) {
            bf16x8 bf = *(const bf16x8*)&Bs[j * 16 + l15][kq * 8];
            acc[j] = __builtin_amdgcn_mfma_f32_16x16x32_bf16(af, bf, acc[j], 0, 0, 0);
        }
        __syncthreads();
    }
    // ---- epilogue: bias, row-norm (in-wave over l15), stores ----
#pragma unroll
    for (int j = 0; j < 16; j++) {
        float bv = bsh[j * 16 + l15];
#pragma unroll
        for (int r = 0; r < 4; r++) acc[j][r] += bv;
    }
    float sq[4] = {0.f, 0.f, 0.f, 0.f};
#pragma unroll
    for (int j = 0; j < 16; j++)
#pragma unroll
        for (int r = 0; r < 4; r++) sq[r] += acc[j][r] * acc[j][r];
#pragma unroll
    for (int off = 8; off >= 1; off >>= 1) {
#pragma unroll
        for (int r = 0; r < 4; r++) sq[r] += __shfl_xor(sq[r], off);
    }
    float rinv[4];
#pragma unroll
    for (int r = 0; r < 4; r++) rinv[r] = 1.0f / fmaxf(sqrtf(sq[r]), 1e-12f);
    int bb = (int)(row0 / Lseq);
    int nloc = (int)(row0 % Lseq) + m_local + kq * 4;
#pragma unroll
    for (int j = 0; j < 16; j++) {
        int col = j * 16 + l15;
#pragma unroll
        for (int r = 0; r < 4; r++) {
            long m = row0 + m_local + kq * 4 + r;
            if (Pf) Pf[m * D_ + col] = acc[j][r];
            Nb[m * D_ + col] = f2bf(acc[j][r] * rinv[r]);
        }
        if (PT) {
            unsigned long long pv =
                  (unsigned long long)f2bf(acc[j][0])
                | ((unsigned long long)f2bf(acc[j][1]) << 16)
                | ((unsigned long long)f2bf(acc[j][2]) << 32)
                | ((unsigned long long)f2bf(acc[j][3]) << 48);
            *(unsigned long long*)(PT + ((long)bb * D_ + col) * Lseq + nloc) = pv;
        }
    }
}

// ---------------- K2: cost GEMM (MFMA bf16) -> logK bf16 ----------------
__global__ __launch_bounds__(256) void k_cost_mfma(
    const unsigned short* __restrict__ Tnb, const unsigned short* __restrict__ Anb,
    unsigned short* __restrict__ logKb, float inv_eps)
{
    __shared__ short As[128][48];
    __shared__ short Bs[128][48];
    int b = blockIdx.z;
    int m_blk = blockIdx.y * 128, n_blk = blockIdx.x * 128;
    int tid = threadIdx.x;
    int wid = tid >> 6, lane = tid & 63;
    int l15 = lane & 15, kq = lane >> 4;
    int wm0 = (wid >> 1) * 64, wn0 = (wid & 1) * 64;
    const unsigned short* Ab = Tnb + ((long)b * LT + m_blk) * D_;
    const unsigned short* Bb = Anb + ((long)b * LA + n_blk) * D_;
    f32x4 acc[4][4];
#pragma unroll
    for (int i = 0; i < 4; i++)
#pragma unroll
        for (int j = 0; j < 4; j++) acc[i][j] = (f32x4){0.f, 0.f, 0.f, 0.f};
    for (int kt = 0; kt < 8; kt++) {
        int k0 = kt * 32;
#pragma unroll
        for (int h = 0; h < 2; h++) {
            int idx = tid + 256 * h;
            int row = idx >> 2, ch = idx & 3;
            *(int4*)&As[row][ch * 8] = *(const int4*)(Ab + (long)row * D_ + k0 + ch * 8);
            *(int4*)&Bs[row][ch * 8] = *(const int4*)(Bb + (long)row * D_ + k0 + ch * 8);
        }
        __syncthreads();
        bf16x8 af[4], bfv[4];
#pragma unroll
        for (int i = 0; i < 4; i++) af[i] = *(const bf16x8*)&As[wm0 + i * 16 + l15][kq * 8];
#pragma unroll
        for (int j = 0; j < 4; j++) bfv[j] = *(const bf16x8*)&Bs[wn0 + j * 16 + l15][kq * 8];
#pragma unroll
        for (int i = 0; i < 4; i++)
#pragma unroll
            for (int j = 0; j < 4; j++)
                acc[i][j] = __builtin_amdgcn_mfma_f32_16x16x32_bf16(af[i], bfv[j], acc[i][j], 0, 0, 0);
        __syncthreads();
    }
#pragma unroll
    for (int i = 0; i < 4; i++) {
#pragma unroll
        for (int r = 0; r < 4; r++) {
            int m = m_blk + wm0 + i * 16 + kq * 4 + r;
            long base = ((long)b * LT + m) * (long)LA + n_blk;
#pragma unroll
            for (int j = 0; j < 4; j++) {
                int n = wn0 + j * 16 + l15;
                logKb[base + n] = f2bf((acc[i][j][r] - 1.0f) * inv_eps);
            }
        }
    }
}

// ---------------- K3: row sum-exp -> lu (args in [-35,0]: no max trick needed) ----------------
__global__ __launch_bounds__(256) void k_rowlse(
    const unsigned short* __restrict__ logKb, const float* __restrict__ lv, float* __restrict__ lu)
{
    __shared__ float red[4];
    long blk = blockIdx.x;             // b*LT + m
    int b = (int)(blk >> 10);
    const unsigned short* p = logKb + blk * (long)LA;
    const float* lvp = lv + (long)b * LA;
    int tid = threadIdx.x;
    int4 raw = *(const int4*)(p + tid * 8);
    unsigned int w[4] = { (unsigned int)raw.x, (unsigned int)raw.y, (unsigned int)raw.z, (unsigned int)raw.w };
    float4 l0 = *(const float4*)(lvp + tid * 8);
    float4 l1 = *(const float4*)(lvp + tid * 8 + 4);
    float lvv[8] = { l0.x, l0.y, l0.z, l0.w, l1.x, l1.y, l1.z, l1.w };
    float s = 0.f;
#pragma unroll
    for (int j = 0; j < 8; j++) {
        float v = bf2f((unsigned short)((w[j >> 1] >> ((j & 1) * 16)) & 0xffffu)) + lvv[j];
        s += __expf(v);
    }
#pragma unroll
    for (int off = 32; off >= 1; off >>= 1) s += __shfl_xor(s, off);
    if ((tid & 63) == 0) red[tid >> 6] = s;
    __syncthreads();
    if (tid == 0) lu[blk] = -6.9314718055994531f - __logf(red[0] + red[1] + red[2] + red[3]);
}

// ---------------- K4: col sum-exp -> lv ----------------
__global__ __launch_bounds__(256) void k_collse(
    const unsigned short* __restrict__ logKb, const float* __restrict__ lu, float* __restrict__ lv)
{
    __shared__ float lus[1024];
    __shared__ float redS[4][128];
    int b = blockIdx.y;
    int n0 = blockIdx.x * 128;
    int tid = threadIdx.x;
    for (int i = tid; i < 1024; i += 256) lus[i] = lu[(long)b * LT + i];
    __syncthreads();
    int c2 = (tid & 63) * 2;
    int g = tid >> 6;
    const unsigned short* base = logKb + (long)b * LT * LA + n0 + c2;
    float S0 = 0.f, S1 = 0.f;
#pragma unroll 4
    for (int m = g; m < 1024; m += 4) {
        unsigned int raw = *(const unsigned int*)(base + (long)m * LA);
        float lm = lus[m];
        S0 += __expf(bf2f((unsigned short)(raw & 0xffffu)) + lm);
        S1 += __expf(bf2f((unsigned short)(raw >> 16)) + lm);
    }
    redS[g][c2] = S0; redS[g][c2 + 1] = S1;
    __syncthreads();
    if (tid < 128) {
        float s = redS[0][tid] + redS[1][tid] + redS[2][tid] + redS[3][tid];
        lv[(long)b * LA + n0 + tid] = -7.6246189861593985f - __logf(s);
    }
}

// ---------------- K5: A_al = pi @ Ap (MFMA; exp fused into A staging) ----------------
__global__ __launch_bounds__(256) void k_pi_mfma(
    const unsigned short* __restrict__ logKb, const unsigned short* __restrict__ ApbT,
    const float* __restrict__ lu, const float* __restrict__ lv, float* __restrict__ Aal)
{
    __shared__ short As[64][48];    // pi [m][n-k]
    __shared__ short Bs[128][48];   // ApT [d][n-k]
    __shared__ float lv_s[2048];
    __shared__ float lu_s[64];
    int b = blockIdx.z;
    int m_blk = blockIdx.y * 64;
    int d_blk = blockIdx.x * 128;
    int tid = threadIdx.x;
    for (int i = tid; i < 2048; i += 256) lv_s[i] = lv[(long)b * LA + i];
    if (tid < 64) lu_s[tid] = lu[(long)b * LT + m_blk + tid];
    __syncthreads();
    int wid = tid >> 6, lane = tid & 63;
    int l15 = lane & 15, kq = lane >> 4;
    int wm0 = (wid & 1) * 32, wd0 = (wid >> 1) * 64;
    f32x4 acc[2][4];
#pragma unroll
    for (int i = 0; i < 2; i++)
#pragma unroll
        for (int j = 0; j < 4; j++) acc[i][j] = (f32x4){0.f, 0.f, 0.f, 0.f};
    const unsigned short* Kbase = logKb + ((long)b * LT + m_blk) * (long)LA;
    const unsigned short* Bbase = ApbT + ((long)b * D_ + d_blk) * (long)LA;
    int arow = tid >> 2, ach = tid & 3;
    for (int kt = 0; kt < 64; kt++) {
        int n0 = kt * 32;
        {   // A: pi tile 64x32 with exp
            int4 raw = *(const int4*)(Kbase + (long)arow * LA + n0 + ach * 8);
            unsigned int w[4] = { (unsigned int)raw.x, (unsigned int)raw.y, (unsigned int)raw.z, (unsigned int)raw.w };
            float lum = lu_s[arow];
            const float* lvp = &lv_s[n0 + ach * 8];
            unsigned int o[8];
#pragma unroll
            for (int j = 0; j < 8; j++) {
                float v = bf2f((unsigned short)((w[j >> 1] >> ((j & 1) * 16)) & 0xffffu)) + lum + lvp[j];
                o[j] = f2bf(__expf(v));
            }
            int4 ov;
            ov.x = (int)(o[0] | (o[1] << 16));
            ov.y = (int)(o[2] | (o[3] << 16));
            ov.z = (int)(o[4] | (o[5] << 16));
            ov.w = (int)(o[6] | (o[7] << 16));
            *(int4*)&As[arow][ach * 8] = ov;
        }
#pragma unroll
        for (int h = 0; h < 2; h++) {   // B: 128x32
            int idx = tid + 256 * h;
            int row = idx >> 2, ch = idx & 3;
            *(int4*)&Bs[row][ch * 8] = *(const int4*)(Bbase + (long)row * LA + n0 + ch * 8);
        }
        __syncthreads();
        bf16x8 af[2], bfv[4];
        af[0] = *(const bf16x8*)&As[wm0 + l15][kq * 8];
        af[1] = *(const bf16x8*)&As[wm0 + 16 + l15][kq * 8];
#pragma unroll
        for (int j = 0; j < 4; j++) bfv[j] = *(const bf16x8*)&Bs[wd0 + j * 16 + l15][kq * 8];
#pragma unroll
        for (int i = 0; i < 2; i++)
#pragma unroll
            for (int j = 0; j < 4; j++)
                acc[i][j] = __builtin_amdgcn_mfma_f32_16x16x32_bf16(af[i], bfv[j], acc[i][j], 0, 0, 0);
        __syncthreads();
    }
#pragma unroll
    for (int i = 0; i < 2; i++) {
#pragma unroll
        for (int r = 0; r < 4; r++) {
            int m = m_blk + wm0 + i * 16 + kq * 4 + r;
            long obase = ((long)b * LT + m) * D_ + d_blk;
#pragma unroll
            for (int j = 0; j < 4; j++)
                Aal[obase + wd0 + j * 16 + l15] = acc[i][j][r];
        }
    }
}

// ---------------- K6: S = <Tp, A_al>, resid = |Tp - A_al| ----------------
__global__ __launch_bounds__(256) void k_sresid(
    const float* __restrict__ Tp, const float* __restrict__ Aal,
    float* __restrict__ resid, float* __restrict__ S)
{
    __shared__ float red[4];
    long row = blockIdx.x;
    int tid = threadIdx.x;
    float t = Tp[row * D_ + tid], a = Aal[row * D_ + tid];
    resid[row * D_ + tid] = fabsf(t - a);
    float p = t * a;
#pragma unroll
    for (int off = 32; off >= 1; off >>= 1) p += __shfl_xor(p, off);
    if ((tid & 63) == 0) red[tid >> 6] = p;
    __syncthreads();
    if (tid == 0) S[row] = red[0] + red[1] + red[2] + red[3];
}

// ---------------- K7a: H = gelu([S,resid] @ Wr1^T + br1) ----------------
__global__ __launch_bounds__(256) void k_router1(
    const float* __restrict__ resid, const float* __restrict__ Wr1,
    const float* __restrict__ br1, const float* __restrict__ S,
    float* __restrict__ H)
{
    __shared__ float As[32][68];
    __shared__ float Bs[32][68];
    int m0 = blockIdx.y * 64;
    int n0 = blockIdx.x * 64;
    const float* Aptr = resid + (long)m0 * D_;
    int tid = threadIdx.x;
    int tx = tid & 15, ty = tid >> 4;
    float acc[4][4] = {};
    for (int kt = 0; kt < 8; kt++) {
        int k0 = kt * 32;
#pragma unroll
        for (int h = 0; h < 2; h++) {
            int chunk = tid + 256 * h;
            int rowi = chunk >> 3, kc = chunk & 7;
            float4 a = *(const float4*)(Aptr + (long)rowi * D_ + k0 + kc * 4);
            As[kc * 4 + 0][rowi] = a.x; As[kc * 4 + 1][rowi] = a.y;
            As[kc * 4 + 2][rowi] = a.z; As[kc * 4 + 3][rowi] = a.w;
            const float* wrow = Wr1 + (long)(n0 + rowi) * 257 + 1 + k0 + kc * 4;
            Bs[kc * 4 + 0][rowi] = wrow[0]; Bs[kc * 4 + 1][rowi] = wrow[1];
            Bs[kc * 4 + 2][rowi] = wrow[2]; Bs[kc * 4 + 3][rowi] = wrow[3];
        }
        __syncthreads();
#pragma unroll
        for (int kk = 0; kk < 32; kk++) {
            float4 av = *(const float4*)&As[kk][ty * 4];
            float4 bv = *(const float4*)&Bs[kk][tx * 4];
            float aa[4] = { av.x, av.y, av.z, av.w };
            float bb4[4] = { bv.x, bv.y, bv.z, bv.w };
#pragma unroll
            for (int i = 0; i < 4; i++)
#pragma unroll
                for (int j = 0; j < 4; j++) acc[i][j] += aa[i] * bb4[j];
        }
        __syncthreads();
    }
#pragma unroll
    for (int i = 0; i < 4; i++) {
        int m = m0 + ty * 4 + i;
        float sm = S[m];
#pragma unroll
        for (int j = 0; j < 4; j++) {
            int n = n0 + tx * 4 + j;
            float val = acc[i][j] + sm * Wr1[(long)n * 257] + br1[n];
            H[(long)m * D_ + n] = gelu_f(val);
        }
    }
}

// ---------------- K7b: logits + softmax -> G planes [3][16384] ----------------
__global__ __launch_bounds__(256) void k_router2(
    const float* __restrict__ H, const float* __restrict__ Wr2,
    const float* __restrict__ br2, float* __restrict__ G)
{
    __shared__ float rd[3][4];
    long row = blockIdx.x;
    int tid = threadIdx.x;
    float h = H[row * D_ + tid];
    float l0 = h * Wr2[tid], l1 = h * Wr2[256 + tid], l2 = h * Wr2[512 + tid];
#pragma unroll
    for (int off = 32; off >= 1; off >>= 1) {
        l0 += __shfl_xor(l0, off); l1 += __shfl_xor(l1, off); l2 += __shfl_xor(l2, off);
    }
    if ((tid & 63) == 0) { int w = tid >> 6; rd[0][w] = l0; rd[1][w] = l1; rd[2][w] = l2; }
    __syncthreads();
    if (tid == 0) {
        float L0 = rd[0][0] + rd[0][1] + rd[0][2] + rd[0][3] + br2[0];
        float L1 = rd[1][0] + rd[1][1] + rd[1][2] + rd[1][3] + br2[1];
        float L2 = rd[2][0] + rd[2][1] + rd[2][2] + rd[2][3] + br2[2];
        float mx = fmaxf(L0, fmaxf(L1, L2));
        float e0 = __expf(L0 - mx), e1 = __expf(L1 - mx), e2 = __expf(L2 - mx);
        float inv = 1.0f / (e0 + e1 + e2);
        G[row] = e0 * inv; G[NRT + row] = e1 * inv; G[2 * NRT + row] = e2 * inv;
    }
}

// ---------------- K8a: h = gelu(resid @ down_W^T + down_b) ----------------
__global__ __launch_bounds__(256) void k_down(
    const float* __restrict__ resid, const float* __restrict__ dW,
    const float* __restrict__ db, float* __restrict__ h)
{
    __shared__ float rs[8][256];
    long row0 = (long)blockIdx.x * 8;
    int tid = threadIdx.x;
    for (int idx = tid; idx < 8 * 256; idx += 256) rs[idx >> 8][idx & 255] = resid[row0 * D_ + idx];
    __syncthreads();
    int j = tid & 63, rg = tid >> 6;
    const float4* w4 = (const float4*)(dW + (long)j * D_);
    float a0 = db[j], a1 = a0;
    for (int k4 = 0; k4 < 64; k4++) {
        float4 w = w4[k4];
        float4 x0 = *(const float4*)&rs[rg * 2][k4 * 4];
        float4 x1 = *(const float4*)&rs[rg * 2 + 1][k4 * 4];
        a0 += x0.x * w.x + x0.y * w.y + x0.z * w.z + x0.w * w.w;
        a1 += x1.x * w.x + x1.y * w.y + x1.z * w.z + x1.w * w.w;
    }
    h[(row0 + rg * 2) * RR_ + j] = gelu_f(a0);
    h[(row0 + rg * 2 + 1) * RR_ + j] = gelu_f(a1);
}

// ---------------- K8b: depth-conv over sequence (tap-sliced LDS GEMM) ----------------
__global__ __launch_bounds__(256) void k_conv(
    const float* __restrict__ h, const float* __restrict__ w,
    const float* __restrict__ cb, float* __restrict__ hc, int ksz)
{
    __shared__ float hs[68][68];
    __shared__ float wt[64][64];
    int blk = blockIdx.x;
    int b = blk >> 4, m0 = (blk & 15) * 64;
    int tid = threadIdx.x;
    int pad = (ksz - 1) >> 1;
    for (int idx = tid; idx < 68 * 16; idx += 256) {
        int mr = idx >> 4, i4 = idx & 15;
        int mm = m0 - 2 + mr;
        float4 vv = { 0.f, 0.f, 0.f, 0.f };
        if (mm >= 0 && mm < LT) vv = *(const float4*)(h + ((long)b * LT + mm) * RR_ + i4 * 4);
        *(float4*)&hs[mr][i4 * 4] = vv;
    }
    int tx = tid & 15, ty = tid >> 4;
    float acc[4][4] = {};
    for (int t = 0; t < ksz; t++) {
        __syncthreads();
        for (int idx = tid; idx < 4096; idx += 256) {
            int i = idx & 63, j = idx >> 6;
            wt[i][j] = w[(long)j * RR_ * ksz + i * ksz + t];
        }
        __syncthreads();
        int roff = ty * 4 + 2 + t - pad;
        for (int i4 = 0; i4 < 16; i4++) {
            float4 h0 = *(const float4*)&hs[roff + 0][i4 * 4];
            float4 h1 = *(const float4*)&hs[roff + 1][i4 * 4];
            float4 h2 = *(const float4*)&hs[roff + 2][i4 * 4];
            float4 h3 = *(const float4*)&hs[roff + 3][i4 * 4];
            float hh[4][4] = { { h0.x, h0.y, h0.z, h0.w }, { h1.x, h1.y, h1.z, h1.w },
                               { h2.x, h2.y, h2.z, h2.w }, { h3.x, h3.y, h3.z, h3.w } };
#pragma unroll
            for (int s = 0; s < 4; s++) {
                float4 wv = *(const float4*)&wt[i4 * 4 + s][tx * 4];
#pragma unroll
                for (int r = 0; r < 4; r++) {
                    acc[r][0] += hh[r][s] * wv.x;
                    acc[r][1] += hh[r][s] * wv.y;
                    acc[r][2] += hh[r][s] * wv.z;
                    acc[r][3] += hh[r][s] * wv.w;
                }
            }
        }
    }
    float4 bb = *(const float4*)(cb + tx * 4);
#pragma unroll
    for (int r = 0; r < 4; r++) {
        long m = (long)b * LT + m0 + ty * 4 + r;
        float4 o;
        o.x = gelu_f(acc[r][0] + bb.x);
        o.y = gelu_f(acc[r][1] + bb.y);
        o.z = gelu_f(acc[r][2] + bb.z);
        o.w = gelu_f(acc[r][3] + bb.w);
        *(float4*)(hc + m * RR_ + tx * 4) = o;
    }
}

// ---------------- K8c: up-proj + residual + LN + gated accumulate ----------------
__global__ __launch_bounds__(256) void k_up(
    const float* __restrict__ hc, const float* __restrict__ uW, const float* __restrict__ ub,
    const float* __restrict__ resid, const float* __restrict__ eg, const float* __restrict__ eb,
    const float* __restrict__ G, float* __restrict__ out, int isFirst)
{
    __shared__ float hs[8][64];
    __shared__ float red[8][256];
    long row0 = (long)blockIdx.x * 8;
    int tid = threadIdx.x;
    for (int idx = tid; idx < 512; idx += 256) hs[idx >> 6][idx & 63] = hc[row0 * RR_ + idx];
    __syncthreads();
    int c = tid;
    const float4* w4 = (const float4*)(uW + (long)c * RR_);
    float v[8];
    float ubc = ub[c];
#pragma unroll
    for (int r = 0; r < 8; r++) v[r] = ubc;
    for (int k4 = 0; k4 < 16; k4++) {
        float4 w = w4[k4];
#pragma unroll
        for (int r = 0; r < 8; r++) {
            float4 x = *(const float4*)&hs[r][k4 * 4];
            v[r] += x.x * w.x + x.y * w.y + x.z * w.z + x.w * w.w;
        }
    }
#pragma unroll
    for (int r = 0; r < 8; r++) v[r] += resid[(row0 + r) * D_ + c];
#pragma unroll
    for (int r = 0; r < 8; r++) red[r][c] = v[r];
    __syncthreads();
    for (int sr = 128; sr >= 1; sr >>= 1) {
        if (c < sr) {
#pragma unroll
            for (int r = 0; r < 8; r++) red[r][c] += red[r][c + sr];
        }
        __syncthreads();
    }
    float mn[8];
#pragma unroll
    for (int r = 0; r < 8; r++) mn[r] = red[r][0] * (1.0f / 256.0f);
    __syncthreads();
#pragma unroll
    for (int r = 0; r < 8; r++) { float d = v[r] - mn[r]; red[r][c] = d * d; }
    __syncthreads();
    for (int sr = 128; sr >= 1; sr >>= 1) {
        if (c < sr) {
#pragma unroll
            for (int r = 0; r < 8; r++) red[r][c] += red[r][c + sr];
        }
        __syncthreads();
    }
#pragma unroll
    for (int r = 0; r < 8; r++) {
        float var = red[r][0] * (1.0f / 256.0f);
        float iv = rsqrtf(var + 1e-5f);
        float eo = (v[r] - mn[r]) * iv * eg[c] + eb[c];
        float gc = G[row0 + r];
        long o = (row0 + r) * D_ + c;
        if (isFirst) out[o] = gc * eo;
        else out[o] += gc * eo;
    }
}

__global__ void k_zero(float* p, int n) {
    int i = blockIdx.x * 256 + threadIdx.x;
    if (i < n) p[i] = 0.f;
}

extern "C" void kernel_launch(void* const* d_in, const int* in_sizes, int n_in,
                              void* d_out, int out_size, void* d_ws, size_t ws_size,
                              hipStream_t stream)
{
    const float* text   = (const float*)d_in[0];
    const float* audio  = (const float*)d_in[1];
    const float* ln_g   = (const float*)d_in[2];
    const float* ln_b   = (const float*)d_in[3];
    const float* W_sh   = (const float*)d_in[4];
    const float* b_sh   = (const float*)d_in[5];
    const float* Wr1    = (const float*)d_in[6];
    const float* br1    = (const float*)d_in[7];
    const float* Wr2    = (const float*)d_in[8];
    const float* br2    = (const float*)d_in[9];
    const float* down_W = (const float*)d_in[10];
    const float* down_b = (const float*)d_in[11];
    const float* cw1    = (const float*)d_in[12];
    const float* cw3    = (const float*)d_in[13];
    const float* cw5    = (const float*)d_in[14];
    const float* conv_b = (const float*)d_in[15];
    const float* up_W   = (const float*)d_in[16];
    const float* up_b   = (const float*)d_in[17];
    const float* en_g   = (const float*)d_in[18];
    const float* en_b   = (const float*)d_in[19];

    float* ws = (float*)d_ws;
    float*          Tp    = ws;                               // 4,194,304 f
    unsigned short* Tnb   = (unsigned short*)(ws + 4194304);  // 4,194,304 bf16
    unsigned short* Anb   = (unsigned short*)(ws + 6291456);  // 8,388,608 bf16
    unsigned short* ApbT  = (unsigned short*)(ws + 10485760); // 8,388,608 bf16 [b][d][n]
    unsigned short* logKb = (unsigned short*)(ws + 14680064); // 33,554,432 bf16
    float*          Aal   = ws + 31457280;                    // 4,194,304 f
    float*          resid = ws + 35651584;                    // 4,194,304 f
    float*          lu    = ws + 39845888;                    // 16,384 f
    float*          lv    = ws + 39862272;                    // 32,768 f
    float*          Sb    = ws + 39895040;                    // 16,384 f
    float*          Gb    = ws + 39911424;                    // 49,152 f
    unsigned short* Wb    = (unsigned short*)(ws + 39960576); // 65,536 bf16
    size_t need_bytes = (size_t)39976960 * 4;
    if (ws_size < need_bytes) {
        fprintf(stderr, "kernel_launch: ws_size %zu < needed %zu\n", ws_size, need_bytes);
        return;
    }
    // aliases (logKb region dead after k_pi_mfma)
    float* H   = ws + 14680064;          // router hidden, 4.19M f
    float* hb  = H + 4194304;            // expert h, 1.05M f
    float* hcb = hb + 1048576;           // expert hc, 1.05M f

    const float inv_eps = (float)(1.0 / (0.1 + 1e-8));

    k_prep_w<<<256, 256, 0, stream>>>(W_sh, Wb);
    k_lnproj_mfma<<<NRT / 64, 256, 0, stream>>>(text, ln_g, ln_b, Wb, b_sh, Tp, Tnb, nullptr, LT);
    k_lnproj_mfma<<<NRA / 64, 256, 0, stream>>>(audio, ln_g, ln_b, Wb, b_sh, nullptr, Anb, ApbT, LA);
    k_cost_mfma<<<dim3(LA / 128, LT / 128, NB), 256, 0, stream>>>(Tnb, Anb, logKb, inv_eps);
    k_zero<<<192, 256, 0, stream>>>(lu, 16384 + 32768);
    for (int it = 0; it < 10; it++) {
        k_rowlse<<<NRT, 256, 0, stream>>>(logKb, lv, lu);
        k_collse<<<dim3(LA / 128, NB), 256, 0, stream>>>(logKb, lu, lv);
    }
    k_pi_mfma<<<dim3(D_ / 128, LT / 64, NB), 256, 0, stream>>>(logKb, ApbT, lu, lv, Aal);
    k_sresid<<<NRT, 256, 0, stream>>>(Tp, Aal, resid, Sb);
    k_router1<<<dim3(D_ / 64, NRT / 64), 256, 0, stream>>>(resid, Wr1, br1, Sb, H);
    k_router2<<<NRT, 256, 0, stream>>>(H, Wr2, br2, Gb);
    for (int e = 0; e < 3; e++) {
        const float* cw = (e == 0) ? cw1 : ((e == 1) ? cw3 : cw5);
        int ksz = (e == 0) ? 1 : ((e == 1) ? 3 : 5);
        k_down<<<NRT / 8, 256, 0, stream>>>(resid, down_W + (long)e * 64 * 256, down_b + e * 64, hb);
        k_conv<<<NRT / 64, 256, 0, stream>>>(hb, cw, conv_b + e * 64, hcb, ksz);
        k_up<<<NRT / 8, 256, 0, stream>>>(hcb, up_W + (long)e * 256 * 64, up_b + e * 256,
                                          resid, en_g + e * 256, en_b + e * 256,
                                          Gb + (long)e * NRT, (float*)d_out, e == 0 ? 1 : 0);
    }
}

// Round 5
// 974.096 us; speedup vs baseline: 2.7017x; 1.0805x over previous
//
#include <hip/hip_runtime.h>
#include <cstdio>

#define D_ 256
#define LT 1024
#define LA 2048
#define NB 16
#define RR_ 64
#define NRT (NB*LT)   // 16384 text rows
#define NRA (NB*LA)   // 32768 audio rows

typedef short bf16x8 __attribute__((ext_vector_type(8)));
typedef float f32x4 __attribute__((ext_vector_type(4)));

__device__ __forceinline__ float gelu_f(float x) {
    return 0.5f * x * (1.0f + erff(x * 0.70710678118654752f));
}
__device__ __forceinline__ float bf2f(unsigned short u) {
    union { unsigned int i; float f; } c; c.i = ((unsigned int)u) << 16; return c.f;
}
__device__ __forceinline__ unsigned short f2bf(float f) {   // RNE
    union { float f; unsigned int i; } c; c.f = f;
    unsigned int x = c.i;
    return (unsigned short)((x + 0x7fffu + ((x >> 16) & 1u)) >> 16);
}

// ---------------- prep: fp32 -> bf16 ----------------
__global__ __launch_bounds__(256) void k_prep_w(const float* __restrict__ W, unsigned short* __restrict__ Wb, int n) {
    int i = blockIdx.x * 256 + threadIdx.x;
    if (i < n) Wb[i] = f2bf(W[i]);
}
// Wr1 [256][257] -> Wr1b [256][256] (drop col 0, kept fp32 for rank-1 term)
__global__ __launch_bounds__(256) void k_prep_wr1(const float* __restrict__ Wr1, unsigned short* __restrict__ Wr1b) {
    int i = blockIdx.x * 256 + threadIdx.x;
    int n = i >> 8, k = i & 255;
    Wr1b[i] = f2bf(Wr1[(long)n * 257 + 1 + k]);
}

// ---------------- K1: LayerNorm + shared projection (MFMA) ----------------
__global__ __launch_bounds__(256) void k_lnproj_mfma(
    const float* __restrict__ X, const float* __restrict__ g, const float* __restrict__ bln,
    const unsigned short* __restrict__ Wb, const float* __restrict__ bsh,
    float* __restrict__ Pf, unsigned short* __restrict__ Nb,
    unsigned short* __restrict__ PT, int Lseq)
{
    __shared__ short xb[64][264];
    __shared__ short Bs[256][40];
    int tid = threadIdx.x;
    long row0 = (long)blockIdx.x * 64;
    {
        int lane = tid & 31, rg = tid >> 5;
        float4 ga = *(const float4*)(g + lane * 8);
        float4 gb2 = *(const float4*)(g + lane * 8 + 4);
        float4 ba = *(const float4*)(bln + lane * 8);
        float4 bb2 = *(const float4*)(bln + lane * 8 + 4);
        for (int it = 0; it < 8; it++) {
            int r = it * 8 + rg;
            const float4* xp4 = (const float4*)(X + (row0 + r) * D_);
            float4 a = xp4[lane * 2], b = xp4[lane * 2 + 1];
            float s = a.x + a.y + a.z + a.w + b.x + b.y + b.z + b.w;
#pragma unroll
            for (int off = 16; off >= 1; off >>= 1) s += __shfl_xor(s, off);
            float mean = s * (1.0f / 256.0f);
            float q = (a.x - mean) * (a.x - mean) + (a.y - mean) * (a.y - mean)
                    + (a.z - mean) * (a.z - mean) + (a.w - mean) * (a.w - mean)
                    + (b.x - mean) * (b.x - mean) + (b.y - mean) * (b.y - mean)
                    + (b.z - mean) * (b.z - mean) + (b.w - mean) * (b.w - mean);
#pragma unroll
            for (int off = 16; off >= 1; off >>= 1) q += __shfl_xor(q, off);
            float ivar = rsqrtf(q * (1.0f / 256.0f) + 1e-5f);
            unsigned int u0 = f2bf((a.x - mean) * ivar * ga.x + ba.x);
            unsigned int u1 = f2bf((a.y - mean) * ivar * ga.y + ba.y);
            unsigned int u2 = f2bf((a.z - mean) * ivar * ga.z + ba.z);
            unsigned int u3 = f2bf((a.w - mean) * ivar * ga.w + ba.w);
            unsigned int u4 = f2bf((b.x - mean) * ivar * gb2.x + bb2.x);
            unsigned int u5 = f2bf((b.y - mean) * ivar * gb2.y + bb2.y);
            unsigned int u6 = f2bf((b.z - mean) * ivar * gb2.z + bb2.z);
            unsigned int u7 = f2bf((b.w - mean) * ivar * gb2.w + bb2.w);
            int4 pv;
            pv.x = (int)(u0 | (u1 << 16)); pv.y = (int)(u2 | (u3 << 16));
            pv.z = (int)(u4 | (u5 << 16)); pv.w = (int)(u6 | (u7 << 16));
            *(int4*)&xb[r][lane * 8] = pv;
        }
    }
    __syncthreads();
    int wid = tid >> 6, lane = tid & 63;
    int l15 = lane & 15, kq = lane >> 4;
    int m_local = wid * 16;
    f32x4 acc[16];
#pragma unroll
    for (int j = 0; j < 16; j++) acc[j] = (f32x4){0.f, 0.f, 0.f, 0.f};
    for (int kt = 0; kt < 8; kt++) {
        int k0 = kt * 32;
#pragma unroll
        for (int h = 0; h < 4; h++) {
            int idx = tid + 256 * h;
            int n = idx >> 2, qc = idx & 3;
            *(int4*)&Bs[n][qc * 8] = *(const int4*)(Wb + (long)n * D_ + k0 + qc * 8);
        }
        __syncthreads();
        bf16x8 af = *(const bf16x8*)&xb[m_local + l15][k0 + kq * 8];
#pragma unroll
        for (int j = 0; j < 16; j++) {
            bf16x8 bf = *(const bf16x8*)&Bs[j * 16 + l15][kq * 8];
            acc[j] = __builtin_amdgcn_mfma_f32_16x16x32_bf16(af, bf, acc[j], 0, 0, 0);
        }
        __syncthreads();
    }
#pragma unroll
    for (int j = 0; j < 16; j++) {
        float bv = bsh[j * 16 + l15];
#pragma unroll
        for (int r = 0; r < 4; r++) acc[j][r] += bv;
    }
    float sq[4] = {0.f, 0.f, 0.f, 0.f};
#pragma unroll
    for (int j = 0; j < 16; j++)
#pragma unroll
        for (int r = 0; r < 4; r++) sq[r] += acc[j][r] * acc[j][r];
#pragma unroll
    for (int off = 8; off >= 1; off >>= 1) {
#pragma unroll
        for (int r = 0; r < 4; r++) sq[r] += __shfl_xor(sq[r], off);
    }
    float rinv[4];
#pragma unroll
    for (int r = 0; r < 4; r++) rinv[r] = 1.0f / fmaxf(sqrtf(sq[r]), 1e-12f);
    int bb = (int)(row0 / Lseq);
    int nloc = (int)(row0 % Lseq) + m_local + kq * 4;
#pragma unroll
    for (int j = 0; j < 16; j++) {
        int col = j * 16 + l15;
#pragma unroll
        for (int r = 0; r < 4; r++) {
            long m = row0 + m_local + kq * 4 + r;
            if (Pf) Pf[m * D_ + col] = acc[j][r];
            Nb[m * D_ + col] = f2bf(acc[j][r] * rinv[r]);
        }
        if (PT) {
            unsigned long long pv =
                  (unsigned long long)f2bf(acc[j][0])
                | ((unsigned long long)f2bf(acc[j][1]) << 16)
                | ((unsigned long long)f2bf(acc[j][2]) << 32)
                | ((unsigned long long)f2bf(acc[j][3]) << 48);
            *(unsigned long long*)(PT + ((long)bb * D_ + col) * Lseq + nloc) = pv;
        }
    }
}

// ---------------- K2: cost GEMM (MFMA bf16) -> logK bf16 ----------------
__global__ __launch_bounds__(256) void k_cost_mfma(
    const unsigned short* __restrict__ Tnb, const unsigned short* __restrict__ Anb,
    unsigned short* __restrict__ logKb, float inv_eps)
{
    __shared__ short As[128][40];
    __shared__ short Bs[128][40];
    int b = blockIdx.z;
    int m_blk = blockIdx.y * 128, n_blk = blockIdx.x * 128;
    int tid = threadIdx.x;
    int wid = tid >> 6, lane = tid & 63;
    int l15 = lane & 15, kq = lane >> 4;
    int wm0 = (wid >> 1) * 64, wn0 = (wid & 1) * 64;
    const unsigned short* Ab = Tnb + ((long)b * LT + m_blk) * D_;
    const unsigned short* Bb = Anb + ((long)b * LA + n_blk) * D_;
    f32x4 acc[4][4];
#pragma unroll
    for (int i = 0; i < 4; i++)
#pragma unroll
        for (int j = 0; j < 4; j++) acc[i][j] = (f32x4){0.f, 0.f, 0.f, 0.f};
    for (int kt = 0; kt < 8; kt++) {
        int k0 = kt * 32;
#pragma unroll
        for (int h = 0; h < 2; h++) {
            int idx = tid + 256 * h;
            int row = idx >> 2, ch = idx & 3;
            *(int4*)&As[row][ch * 8] = *(const int4*)(Ab + (long)row * D_ + k0 + ch * 8);
            *(int4*)&Bs[row][ch * 8] = *(const int4*)(Bb + (long)row * D_ + k0 + ch * 8);
        }
        __syncthreads();
        bf16x8 af[4], bfv[4];
#pragma unroll
        for (int i = 0; i < 4; i++) af[i] = *(const bf16x8*)&As[wm0 + i * 16 + l15][kq * 8];
#pragma unroll
        for (int j = 0; j < 4; j++) bfv[j] = *(const bf16x8*)&Bs[wn0 + j * 16 + l15][kq * 8];
#pragma unroll
        for (int i = 0; i < 4; i++)
#pragma unroll
            for (int j = 0; j < 4; j++)
                acc[i][j] = __builtin_amdgcn_mfma_f32_16x16x32_bf16(af[i], bfv[j], acc[i][j], 0, 0, 0);
        __syncthreads();
    }
#pragma unroll
    for (int i = 0; i < 4; i++) {
#pragma unroll
        for (int r = 0; r < 4; r++) {
            int m = m_blk + wm0 + i * 16 + kq * 4 + r;
            long base = ((long)b * LT + m) * (long)LA + n_blk;
#pragma unroll
            for (int j = 0; j < 4; j++) {
                int n = wn0 + j * 16 + l15;
                logKb[base + n] = f2bf((acc[i][j][r] - 1.0f) * inv_eps);
            }
        }
    }
}

// ---------------- K3: row sum-exp -> lu ----------------
__global__ __launch_bounds__(256) void k_rowlse(
    const unsigned short* __restrict__ logKb, const float* __restrict__ lv, float* __restrict__ lu)
{
    __shared__ float red[4];
    long blk = blockIdx.x;
    int b = (int)(blk >> 10);
    const unsigned short* p = logKb + blk * (long)LA;
    const float* lvp = lv + (long)b * LA;
    int tid = threadIdx.x;
    int4 raw = *(const int4*)(p + tid * 8);
    unsigned int w[4] = { (unsigned int)raw.x, (unsigned int)raw.y, (unsigned int)raw.z, (unsigned int)raw.w };
    float4 l0 = *(const float4*)(lvp + tid * 8);
    float4 l1 = *(const float4*)(lvp + tid * 8 + 4);
    float lvv[8] = { l0.x, l0.y, l0.z, l0.w, l1.x, l1.y, l1.z, l1.w };
    float s = 0.f;
#pragma unroll
    for (int j = 0; j < 8; j++) {
        float v = bf2f((unsigned short)((w[j >> 1] >> ((j & 1) * 16)) & 0xffffu)) + lvv[j];
        s += __expf(v);
    }
#pragma unroll
    for (int off = 32; off >= 1; off >>= 1) s += __shfl_xor(s, off);
    if ((tid & 63) == 0) red[tid >> 6] = s;
    __syncthreads();
    if (tid == 0) lu[blk] = -6.9314718055994531f - __logf(red[0] + red[1] + red[2] + red[3]);
}

// ---------------- K4: col sum-exp -> lv ----------------
__global__ __launch_bounds__(256) void k_collse(
    const unsigned short* __restrict__ logKb, const float* __restrict__ lu, float* __restrict__ lv)
{
    __shared__ float lus[1024];
    __shared__ float redS[4][128];
    int b = blockIdx.y;
    int n0 = blockIdx.x * 128;
    int tid = threadIdx.x;
    for (int i = tid; i < 1024; i += 256) lus[i] = lu[(long)b * LT + i];
    __syncthreads();
    int c2 = (tid & 63) * 2;
    int g = tid >> 6;
    const unsigned short* base = logKb + (long)b * LT * LA + n0 + c2;
    float S0 = 0.f, S1 = 0.f;
#pragma unroll 4
    for (int m = g; m < 1024; m += 4) {
        unsigned int raw = *(const unsigned int*)(base + (long)m * LA);
        float lm = lus[m];
        S0 += __expf(bf2f((unsigned short)(raw & 0xffffu)) + lm);
        S1 += __expf(bf2f((unsigned short)(raw >> 16)) + lm);
    }
    redS[g][c2] = S0; redS[g][c2 + 1] = S1;
    __syncthreads();
    if (tid < 128) {
        float s = redS[0][tid] + redS[1][tid] + redS[2][tid] + redS[3][tid];
        lv[(long)b * LA + n0 + tid] = -7.6246189861593985f - __logf(s);
    }
}

// ---------------- K5: A_al = pi @ Ap (MFMA; exp fused into A staging) ----------------
__global__ __launch_bounds__(256) void k_pi_mfma(
    const unsigned short* __restrict__ logKb, const unsigned short* __restrict__ ApbT,
    const float* __restrict__ lu, const float* __restrict__ lv, float* __restrict__ Aal)
{
    __shared__ short As[64][40];
    __shared__ short Bs[128][40];
    __shared__ float lv_s[2048];
    __shared__ float lu_s[64];
    int b = blockIdx.z;
    int m_blk = blockIdx.y * 64;
    int d_blk = blockIdx.x * 128;
    int tid = threadIdx.x;
    for (int i = tid; i < 2048; i += 256) lv_s[i] = lv[(long)b * LA + i];
    if (tid < 64) lu_s[tid] = lu[(long)b * LT + m_blk + tid];
    __syncthreads();
    int wid = tid >> 6, lane = tid & 63;
    int l15 = lane & 15, kq = lane >> 4;
    int wm0 = (wid & 1) * 32, wd0 = (wid >> 1) * 64;
    f32x4 acc[2][4];
#pragma unroll
    for (int i = 0; i < 2; i++)
#pragma unroll
        for (int j = 0; j < 4; j++) acc[i][j] = (f32x4){0.f, 0.f, 0.f, 0.f};
    const unsigned short* Kbase = logKb + ((long)b * LT + m_blk) * (long)LA;
    const unsigned short* Bbase = ApbT + ((long)b * D_ + d_blk) * (long)LA;
    int arow = tid >> 2, ach = tid & 3;
    for (int kt = 0; kt < 64; kt++) {
        int n0 = kt * 32;
        {
            int4 raw = *(const int4*)(Kbase + (long)arow * LA + n0 + ach * 8);
            unsigned int w[4] = { (unsigned int)raw.x, (unsigned int)raw.y, (unsigned int)raw.z, (unsigned int)raw.w };
            float lum = lu_s[arow];
            const float* lvp = &lv_s[n0 + ach * 8];
            unsigned int o[8];
#pragma unroll
            for (int j = 0; j < 8; j++) {
                float v = bf2f((unsigned short)((w[j >> 1] >> ((j & 1) * 16)) & 0xffffu)) + lum + lvp[j];
                o[j] = f2bf(__expf(v));
            }
            int4 ov;
            ov.x = (int)(o[0] | (o[1] << 16));
            ov.y = (int)(o[2] | (o[3] << 16));
            ov.z = (int)(o[4] | (o[5] << 16));
            ov.w = (int)(o[6] | (o[7] << 16));
            *(int4*)&As[arow][ach * 8] = ov;
        }
#pragma unroll
        for (int h = 0; h < 2; h++) {
            int idx = tid + 256 * h;
            int row = idx >> 2, ch = idx & 3;
            *(int4*)&Bs[row][ch * 8] = *(const int4*)(Bbase + (long)row * LA + n0 + ch * 8);
        }
        __syncthreads();
        bf16x8 af[2], bfv[4];
        af[0] = *(const bf16x8*)&As[wm0 + l15][kq * 8];
        af[1] = *(const bf16x8*)&As[wm0 + 16 + l15][kq * 8];
#pragma unroll
        for (int j = 0; j < 4; j++) bfv[j] = *(const bf16x8*)&Bs[wd0 + j * 16 + l15][kq * 8];
#pragma unroll
        for (int i = 0; i < 2; i++)
#pragma unroll
            for (int j = 0; j < 4; j++)
                acc[i][j] = __builtin_amdgcn_mfma_f32_16x16x32_bf16(af[i], bfv[j], acc[i][j], 0, 0, 0);
        __syncthreads();
    }
#pragma unroll
    for (int i = 0; i < 2; i++) {
#pragma unroll
        for (int r = 0; r < 4; r++) {
            int m = m_blk + wm0 + i * 16 + kq * 4 + r;
            long obase = ((long)b * LT + m) * D_ + d_blk;
#pragma unroll
            for (int j = 0; j < 4; j++)
                Aal[obase + wd0 + j * 16 + l15] = acc[i][j][r];
        }
    }
}

// ---------------- K6: S = <Tp, A_al>, resid = |Tp - A_al| (+ bf16 copy) ----------------
__global__ __launch_bounds__(256) void k_sresid(
    const float* __restrict__ Tp, const float* __restrict__ Aal,
    float* __restrict__ resid, unsigned short* __restrict__ residb, float* __restrict__ S)
{
    __shared__ float red[4];
    long row = blockIdx.x;
    int tid = threadIdx.x;
    float t = Tp[row * D_ + tid], a = Aal[row * D_ + tid];
    float rr = fabsf(t - a);
    resid[row * D_ + tid] = rr;
    residb[row * D_ + tid] = f2bf(rr);
    float p = t * a;
#pragma unroll
    for (int off = 32; off >= 1; off >>= 1) p += __shfl_xor(p, off);
    if ((tid & 63) == 0) red[tid >> 6] = p;
    __syncthreads();
    if (tid == 0) S[row] = red[0] + red[1] + red[2] + red[3];
}

// ---------------- K7a: H = gelu(residb @ Wr1b^T + S*w0 + br1) (MFMA) ----------------
__global__ __launch_bounds__(256) void k_router1_mfma(
    const unsigned short* __restrict__ residb, const unsigned short* __restrict__ Wr1b,
    const float* __restrict__ Wr1, const float* __restrict__ br1,
    const float* __restrict__ S, float* __restrict__ H)
{
    __shared__ short xb[64][264];
    __shared__ short Bs[256][40];
    int tid = threadIdx.x;
    long row0 = (long)blockIdx.x * 64;
#pragma unroll
    for (int h = 0; h < 8; h++) {
        int idx = tid + 256 * h;
        int row = idx >> 5, ch = idx & 31;
        *(int4*)&xb[row][ch * 8] = *(const int4*)(residb + (row0 + row) * D_ + ch * 8);
    }
    __syncthreads();
    int wid = tid >> 6, lane = tid & 63;
    int l15 = lane & 15, kq = lane >> 4;
    int m_local = wid * 16;
    f32x4 acc[16];
#pragma unroll
    for (int j = 0; j < 16; j++) acc[j] = (f32x4){0.f, 0.f, 0.f, 0.f};
    for (int kt = 0; kt < 8; kt++) {
        int k0 = kt * 32;
#pragma unroll
        for (int h = 0; h < 4; h++) {
            int idx = tid + 256 * h;
            int n = idx >> 2, qc = idx & 3;
            *(int4*)&Bs[n][qc * 8] = *(const int4*)(Wr1b + (long)n * D_ + k0 + qc * 8);
        }
        __syncthreads();
        bf16x8 af = *(const bf16x8*)&xb[m_local + l15][k0 + kq * 8];
#pragma unroll
        for (int j = 0; j < 16; j++) {
            bf16x8 bf = *(const bf16x8*)&Bs[j * 16 + l15][kq * 8];
            acc[j] = __builtin_amdgcn_mfma_f32_16x16x32_bf16(af, bf, acc[j], 0, 0, 0);
        }
        __syncthreads();
    }
    float sv[4];
#pragma unroll
    for (int r = 0; r < 4; r++) sv[r] = S[row0 + m_local + kq * 4 + r];
#pragma unroll
    for (int j = 0; j < 16; j++) {
        int col = j * 16 + l15;
        float w0 = Wr1[(long)col * 257];
        float bv = br1[col];
#pragma unroll
        for (int r = 0; r < 4; r++) {
            long m = row0 + m_local + kq * 4 + r;
            H[m * D_ + col] = gelu_f(acc[j][r] + sv[r] * w0 + bv);
        }
    }
}

// ---------------- K7b: logits + softmax -> G planes [3][16384] ----------------
__global__ __launch_bounds__(256) void k_router2(
    const float* __restrict__ H, const float* __restrict__ Wr2,
    const float* __restrict__ br2, float* __restrict__ G)
{
    __shared__ float rd[3][4];
    long row = blockIdx.x;
    int tid = threadIdx.x;
    float h = H[row * D_ + tid];
    float l0 = h * Wr2[tid], l1 = h * Wr2[256 + tid], l2 = h * Wr2[512 + tid];
#pragma unroll
    for (int off = 32; off >= 1; off >>= 1) {
        l0 += __shfl_xor(l0, off); l1 += __shfl_xor(l1, off); l2 += __shfl_xor(l2, off);
    }
    if ((tid & 63) == 0) { int w = tid >> 6; rd[0][w] = l0; rd[1][w] = l1; rd[2][w] = l2; }
    __syncthreads();
    if (tid == 0) {
        float L0 = rd[0][0] + rd[0][1] + rd[0][2] + rd[0][3] + br2[0];
        float L1 = rd[1][0] + rd[1][1] + rd[1][2] + rd[1][3] + br2[1];
        float L2 = rd[2][0] + rd[2][1] + rd[2][2] + rd[2][3] + br2[2];
        float mx = fmaxf(L0, fmaxf(L1, L2));
        float e0 = __expf(L0 - mx), e1 = __expf(L1 - mx), e2 = __expf(L2 - mx);
        float inv = 1.0f / (e0 + e1 + e2);
        G[row] = e0 * inv; G[NRT + row] = e1 * inv; G[2 * NRT + row] = e2 * inv;
    }
}

// ---------------- K8a: h[e] = gelu(residb @ down_W[e]^T + down_b[e]) (MFMA, all experts) ----------------
__global__ __launch_bounds__(256) void k_down_mfma(
    const unsigned short* __restrict__ residb, const unsigned short* __restrict__ dWb,
    const float* __restrict__ db, float* __restrict__ hall)
{
    __shared__ short xb[64][264];
    __shared__ short Bs[64][40];
    int tid = threadIdx.x;
    int e = blockIdx.y;
    long row0 = (long)blockIdx.x * 64;
    const unsigned short* dWe = dWb + (long)e * RR_ * D_;
    float* h = hall + (long)e * NRT * RR_;
#pragma unroll
    for (int hh = 0; hh < 8; hh++) {
        int idx = tid + 256 * hh;
        int row = idx >> 5, ch = idx & 31;
        *(int4*)&xb[row][ch * 8] = *(const int4*)(residb + (row0 + row) * D_ + ch * 8);
    }
    __syncthreads();
    int wid = tid >> 6, lane = tid & 63;
    int l15 = lane & 15, kq = lane >> 4;
    int m_local = wid * 16;
    f32x4 acc[4];
#pragma unroll
    for (int j = 0; j < 4; j++) acc[j] = (f32x4){0.f, 0.f, 0.f, 0.f};
    for (int kt = 0; kt < 8; kt++) {
        int k0 = kt * 32;
        {   // stage dW chunk: 64 rows x 32 k = 256 int4
            int n = tid >> 2, qc = tid & 3;
            *(int4*)&Bs[n][qc * 8] = *(const int4*)(dWe + (long)n * D_ + k0 + qc * 8);
        }
        __syncthreads();
        bf16x8 af = *(const bf16x8*)&xb[m_local + l15][k0 + kq * 8];
#pragma unroll
        for (int j = 0; j < 4; j++) {
            bf16x8 bf = *(const bf16x8*)&Bs[j * 16 + l15][kq * 8];
            acc[j] = __builtin_amdgcn_mfma_f32_16x16x32_bf16(af, bf, acc[j], 0, 0, 0);
        }
        __syncthreads();
    }
#pragma unroll
    for (int j = 0; j < 4; j++) {
        int col = j * 16 + l15;
        float bv = db[e * RR_ + col];
#pragma unroll
        for (int r = 0; r < 4; r++) {
            long m = row0 + m_local + kq * 4 + r;
            h[m * RR_ + col] = gelu_f(acc[j][r] + bv);
        }
    }
}

// ---------------- K8b: depth-conv over sequence (tap-sliced LDS GEMM) -> bf16 ----------------
__global__ __launch_bounds__(256) void k_conv(
    const float* __restrict__ h, const float* __restrict__ w,
    const float* __restrict__ cb, unsigned short* __restrict__ hcb, int ksz)
{
    __shared__ float hs[68][68];
    __shared__ float wt[64][64];
    int blk = blockIdx.x;
    int b = blk >> 4, m0 = (blk & 15) * 64;
    int tid = threadIdx.x;
    int pad = (ksz - 1) >> 1;
    for (int idx = tid; idx < 68 * 16; idx += 256) {
        int mr = idx >> 4, i4 = idx & 15;
        int mm = m0 - 2 + mr;
        float4 vv = { 0.f, 0.f, 0.f, 0.f };
        if (mm >= 0 && mm < LT) vv = *(const float4*)(h + ((long)b * LT + mm) * RR_ + i4 * 4);
        *(float4*)&hs[mr][i4 * 4] = vv;
    }
    int tx = tid & 15, ty = tid >> 4;
    float acc[4][4] = {};
    for (int t = 0; t < ksz; t++) {
        __syncthreads();
        for (int idx = tid; idx < 4096; idx += 256) {
            int i = idx & 63, j = idx >> 6;
            wt[i][j] = w[(long)j * RR_ * ksz + i * ksz + t];
        }
        __syncthreads();
        int roff = ty * 4 + 2 + t - pad;
        for (int i4 = 0; i4 < 16; i4++) {
            float4 h0 = *(const float4*)&hs[roff + 0][i4 * 4];
            float4 h1 = *(const float4*)&hs[roff + 1][i4 * 4];
            float4 h2 = *(const float4*)&hs[roff + 2][i4 * 4];
            float4 h3 = *(const float4*)&hs[roff + 3][i4 * 4];
            float hh[4][4] = { { h0.x, h0.y, h0.z, h0.w }, { h1.x, h1.y, h1.z, h1.w },
                               { h2.x, h2.y, h2.z, h2.w }, { h3.x, h3.y, h3.z, h3.w } };
#pragma unroll
            for (int s = 0; s < 4; s++) {
                float4 wv = *(const float4*)&wt[i4 * 4 + s][tx * 4];
#pragma unroll
                for (int r = 0; r < 4; r++) {
                    acc[r][0] += hh[r][s] * wv.x;
                    acc[r][1] += hh[r][s] * wv.y;
                    acc[r][2] += hh[r][s] * wv.z;
                    acc[r][3] += hh[r][s] * wv.w;
                }
            }
        }
    }
    float4 bb = *(const float4*)(cb + tx * 4);
#pragma unroll
    for (int r = 0; r < 4; r++) {
        long m = (long)b * LT + m0 + ty * 4 + r;
        unsigned long long pv =
              (unsigned long long)f2bf(gelu_f(acc[r][0] + bb.x))
            | ((unsigned long long)f2bf(gelu_f(acc[r][1] + bb.y)) << 16)
            | ((unsigned long long)f2bf(gelu_f(acc[r][2] + bb.z)) << 32)
            | ((unsigned long long)f2bf(gelu_f(acc[r][3] + bb.w)) << 48);
        *(unsigned long long*)(hcb + m * RR_ + tx * 4) = pv;
    }
}

// ---------------- K8c: up-proj + residual + LN (in-wave) + gated accumulate (MFMA) ----------------
__global__ __launch_bounds__(256) void k_up_mfma(
    const unsigned short* __restrict__ hcb, const unsigned short* __restrict__ uWb,
    const float* __restrict__ ub, const float* __restrict__ resid,
    const float* __restrict__ eg, const float* __restrict__ eb,
    const float* __restrict__ G, float* __restrict__ out, int isFirst)
{
    __shared__ short hs[64][88];    // 64 rows x 64 k bf16 (stride 88: 16B-aligned, conflict-free)
    __shared__ short Bs[256][40];
    int tid = threadIdx.x;
    long row0 = (long)blockIdx.x * 64;
#pragma unroll
    for (int hh = 0; hh < 2; hh++) {
        int idx = tid + 256 * hh;
        int row = idx >> 3, ch = idx & 7;
        *(int4*)&hs[row][ch * 8] = *(const int4*)(hcb + (row0 + row) * RR_ + ch * 8);
    }
    __syncthreads();
    int wid = tid >> 6, lane = tid & 63;
    int l15 = lane & 15, kq = lane >> 4;
    int m_local = wid * 16;
    f32x4 acc[16];
#pragma unroll
    for (int j = 0; j < 16; j++) acc[j] = (f32x4){0.f, 0.f, 0.f, 0.f};
    for (int kt = 0; kt < 2; kt++) {
        int k0 = kt * 32;
#pragma unroll
        for (int hh = 0; hh < 4; hh++) {
            int idx = tid + 256 * hh;
            int n = idx >> 2, qc = idx & 3;
            *(int4*)&Bs[n][qc * 8] = *(const int4*)(uWb + (long)n * RR_ + k0 + qc * 8);
        }
        __syncthreads();
        bf16x8 af = *(const bf16x8*)&hs[m_local + l15][k0 + kq * 8];
#pragma unroll
        for (int j = 0; j < 16; j++) {
            bf16x8 bf = *(const bf16x8*)&Bs[j * 16 + l15][kq * 8];
            acc[j] = __builtin_amdgcn_mfma_f32_16x16x32_bf16(af, bf, acc[j], 0, 0, 0);
        }
        __syncthreads();
    }
    // epilogue: + up_b + resid, in-wave LN over 256 cols, gate, accumulate
    long mrow[4];
#pragma unroll
    for (int r = 0; r < 4; r++) mrow[r] = row0 + m_local + kq * 4 + r;
#pragma unroll
    for (int j = 0; j < 16; j++) {
        int col = j * 16 + l15;
        float bv = ub[col];
#pragma unroll
        for (int r = 0; r < 4; r++)
            acc[j][r] += bv + resid[mrow[r] * D_ + col];
    }
    float s[4] = {0.f, 0.f, 0.f, 0.f};
#pragma unroll
    for (int j = 0; j < 16; j++)
#pragma unroll
        for (int r = 0; r < 4; r++) s[r] += acc[j][r];
#pragma unroll
    for (int off = 8; off >= 1; off >>= 1)
#pragma unroll
        for (int r = 0; r < 4; r++) s[r] += __shfl_xor(s[r], off);
    float mn[4];
#pragma unroll
    for (int r = 0; r < 4; r++) mn[r] = s[r] * (1.0f / 256.0f);
    float q[4] = {0.f, 0.f, 0.f, 0.f};
#pragma unroll
    for (int j = 0; j < 16; j++)
#pragma unroll
        for (int r = 0; r < 4; r++) { float d = acc[j][r] - mn[r]; q[r] += d * d; }
#pragma unroll
    for (int off = 8; off >= 1; off >>= 1)
#pragma unroll
        for (int r = 0; r < 4; r++) q[r] += __shfl_xor(q[r], off);
    float iv[4], gv[4];
#pragma unroll
    for (int r = 0; r < 4; r++) {
        iv[r] = rsqrtf(q[r] * (1.0f / 256.0f) + 1e-5f);
        gv[r] = G[mrow[r]];
    }
#pragma unroll
    for (int j = 0; j < 16; j++) {
        int col = j * 16 + l15;
        float egc = eg[col], ebc = eb[col];
#pragma unroll
        for (int r = 0; r < 4; r++) {
            float eo = (acc[j][r] - mn[r]) * iv[r] * egc + ebc;
            long o = mrow[r] * D_ + col;
            if (isFirst) out[o] = gv[r] * eo;
            else out[o] += gv[r] * eo;
        }
    }
}

__global__ void k_zero(float* p, int n) {
    int i = blockIdx.x * 256 + threadIdx.x;
    if (i < n) p[i] = 0.f;
}

extern "C" void kernel_launch(void* const* d_in, const int* in_sizes, int n_in,
                              void* d_out, int out_size, void* d_ws, size_t ws_size,
                              hipStream_t stream)
{
    const float* text   = (const float*)d_in[0];
    const float* audio  = (const float*)d_in[1];
    const float* ln_g   = (const float*)d_in[2];
    const float* ln_b   = (const float*)d_in[3];
    const float* W_sh   = (const float*)d_in[4];
    const float* b_sh   = (const float*)d_in[5];
    const float* Wr1    = (const float*)d_in[6];
    const float* br1    = (const float*)d_in[7];
    const float* Wr2    = (const float*)d_in[8];
    const float* br2    = (const float*)d_in[9];
    const float* down_W = (const float*)d_in[10];
    const float* down_b = (const float*)d_in[11];
    const float* cw1    = (const float*)d_in[12];
    const float* cw3    = (const float*)d_in[13];
    const float* cw5    = (const float*)d_in[14];
    const float* conv_b = (const float*)d_in[15];
    const float* up_W   = (const float*)d_in[16];
    const float* up_b   = (const float*)d_in[17];
    const float* en_g   = (const float*)d_in[18];
    const float* en_b   = (const float*)d_in[19];

    float* ws = (float*)d_ws;
    float*          Tp    = ws;                               // 4,194,304 f
    unsigned short* Tnb   = (unsigned short*)(ws + 4194304);
    unsigned short* Anb   = (unsigned short*)(ws + 6291456);
    unsigned short* ApbT  = (unsigned short*)(ws + 10485760);
    unsigned short* logKb = (unsigned short*)(ws + 14680064); // 16,777,216 f region (aliased later)
    float*          Aal   = ws + 31457280;
    float*          resid = ws + 35651584;
    unsigned short* residb= (unsigned short*)(ws + 39845888); // 2,097,152 f
    float*          lu    = ws + 41943040;
    float*          lv    = ws + 41959424;
    float*          Sb    = ws + 41992192;
    float*          Gb    = ws + 42008576;
    unsigned short* Wb    = (unsigned short*)(ws + 42057728); // 32,768 f
    unsigned short* dWb   = (unsigned short*)(ws + 42090496); // 24,576 f
    unsigned short* uWb   = (unsigned short*)(ws + 42115072); // 24,576 f
    unsigned short* Wr1b  = (unsigned short*)(ws + 42139648); // 32,768 f
    size_t need_bytes = (size_t)42172416 * 4;
    if (ws_size < need_bytes) {
        fprintf(stderr, "kernel_launch: ws_size %zu < needed %zu\n", ws_size, need_bytes);
        return;
    }
    // aliases in logKb region (dead after k_pi_mfma)
    float*          H    = ws + 14680064;                     // 4,194,304 f
    float*          hall = ws + 18874368;                     // 3 x 1,048,576 f
    unsigned short* hcbb = (unsigned short*)(ws + 22020096);  // 3 x 1,048,576 shorts

    const float inv_eps = (float)(1.0 / (0.1 + 1e-8));

    k_prep_w<<<256, 256, 0, stream>>>(W_sh, Wb, 65536);
    k_prep_w<<<192, 256, 0, stream>>>(down_W, dWb, 49152);
    k_prep_w<<<192, 256, 0, stream>>>(up_W, uWb, 49152);
    k_prep_wr1<<<256, 256, 0, stream>>>(Wr1, Wr1b);
    k_lnproj_mfma<<<NRT / 64, 256, 0, stream>>>(text, ln_g, ln_b, Wb, b_sh, Tp, Tnb, nullptr, LT);
    k_lnproj_mfma<<<NRA / 64, 256, 0, stream>>>(audio, ln_g, ln_b, Wb, b_sh, nullptr, Anb, ApbT, LA);
    k_cost_mfma<<<dim3(LA / 128, LT / 128, NB), 256, 0, stream>>>(Tnb, Anb, logKb, inv_eps);
    k_zero<<<192, 256, 0, stream>>>(lu, 16384 + 32768);
    for (int it = 0; it < 10; it++) {
        k_rowlse<<<NRT, 256, 0, stream>>>(logKb, lv, lu);
        k_collse<<<dim3(LA / 128, NB), 256, 0, stream>>>(logKb, lu, lv);
    }
    k_pi_mfma<<<dim3(D_ / 128, LT / 64, NB), 256, 0, stream>>>(logKb, ApbT, lu, lv, Aal);
    k_sresid<<<NRT, 256, 0, stream>>>(Tp, Aal, resid, residb, Sb);
    k_router1_mfma<<<NRT / 64, 256, 0, stream>>>(residb, Wr1b, Wr1, br1, Sb, H);
    k_router2<<<NRT, 256, 0, stream>>>(H, Wr2, br2, Gb);
    k_down_mfma<<<dim3(NRT / 64, 3), 256, 0, stream>>>(residb, dWb, down_b, hall);
    for (int e = 0; e < 3; e++) {
        const float* cw = (e == 0) ? cw1 : ((e == 1) ? cw3 : cw5);
        int ksz = (e == 0) ? 1 : ((e == 1) ? 3 : 5);
        k_conv<<<NRT / 64, 256, 0, stream>>>(hall + (long)e * NRT * RR_, cw, conv_b + e * 64,
                                             hcbb + (long)e * NRT * RR_, ksz);
    }
    for (int e = 0; e < 3; e++) {
        k_up_mfma<<<NRT / 64, 256, 0, stream>>>(hcbb + (long)e * NRT * RR_, uWb + (long)e * 16384,
                                                up_b + e * 256, resid, en_g + e * 256, en_b + e * 256,
                                                Gb + (long)e * NRT, (float*)d_out, e == 0 ? 1 : 0);
    }
}

// Round 6
// 830.879 us; speedup vs baseline: 3.1674x; 1.1724x over previous
//
#include <hip/hip_runtime.h>
#include <cstdio>

#define D_ 256
#define LT 1024
#define LA 2048
#define NB 16
#define RR_ 64
#define NRT (NB*LT)   // 16384 text rows
#define NRA (NB*LA)   // 32768 audio rows

// logK u8 quantization: q = rint((1-cos)*124), logK_hat = q * DECQ, DECQ = -1/12.4
#define DECQ (-0.080645161f)

typedef short bf16x8 __attribute__((ext_vector_type(8)));
typedef float f32x4 __attribute__((ext_vector_type(4)));

__device__ __forceinline__ float gelu_f(float x) {
    return 0.5f * x * (1.0f + erff(x * 0.70710678118654752f));
}
__device__ __forceinline__ float bf2f(unsigned short u) {
    union { unsigned int i; float f; } c; c.i = ((unsigned int)u) << 16; return c.f;
}
__device__ __forceinline__ unsigned short f2bf(float f) {   // RNE
    union { float f; unsigned int i; } c; c.f = f;
    unsigned int x = c.i;
    return (unsigned short)((x + 0x7fffu + ((x >> 16) & 1u)) >> 16);
}

// ---------------- prep: fp32 -> bf16 ----------------
__global__ __launch_bounds__(256) void k_prep_w(const float* __restrict__ W, unsigned short* __restrict__ Wb, int n) {
    int i = blockIdx.x * 256 + threadIdx.x;
    if (i < n) Wb[i] = f2bf(W[i]);
}
// Wr1 [256][257] -> Wr1b [256][256] (drop col 0, kept fp32 for rank-1 term)
__global__ __launch_bounds__(256) void k_prep_wr1(const float* __restrict__ Wr1, unsigned short* __restrict__ Wr1b) {
    int i = blockIdx.x * 256 + threadIdx.x;
    int n = i >> 8, k = i & 255;
    Wr1b[i] = f2bf(Wr1[(long)n * 257 + 1 + k]);
}

// ---------------- K1: LayerNorm + shared projection (MFMA) ----------------
__global__ __launch_bounds__(256) void k_lnproj_mfma(
    const float* __restrict__ X, const float* __restrict__ g, const float* __restrict__ bln,
    const unsigned short* __restrict__ Wb, const float* __restrict__ bsh,
    float* __restrict__ Pf, unsigned short* __restrict__ Nb,
    unsigned short* __restrict__ PT, int Lseq)
{
    __shared__ short xb[64][264];
    __shared__ short Bs[256][40];
    int tid = threadIdx.x;
    long row0 = (long)blockIdx.x * 64;
    {
        int lane = tid & 31, rg = tid >> 5;
        float4 ga = *(const float4*)(g + lane * 8);
        float4 gb2 = *(const float4*)(g + lane * 8 + 4);
        float4 ba = *(const float4*)(bln + lane * 8);
        float4 bb2 = *(const float4*)(bln + lane * 8 + 4);
        for (int it = 0; it < 8; it++) {
            int r = it * 8 + rg;
            const float4* xp4 = (const float4*)(X + (row0 + r) * D_);
            float4 a = xp4[lane * 2], b = xp4[lane * 2 + 1];
            float s = a.x + a.y + a.z + a.w + b.x + b.y + b.z + b.w;
#pragma unroll
            for (int off = 16; off >= 1; off >>= 1) s += __shfl_xor(s, off);
            float mean = s * (1.0f / 256.0f);
            float q = (a.x - mean) * (a.x - mean) + (a.y - mean) * (a.y - mean)
                    + (a.z - mean) * (a.z - mean) + (a.w - mean) * (a.w - mean)
                    + (b.x - mean) * (b.x - mean) + (b.y - mean) * (b.y - mean)
                    + (b.z - mean) * (b.z - mean) + (b.w - mean) * (b.w - mean);
#pragma unroll
            for (int off = 16; off >= 1; off >>= 1) q += __shfl_xor(q, off);
            float ivar = rsqrtf(q * (1.0f / 256.0f) + 1e-5f);
            unsigned int u0 = f2bf((a.x - mean) * ivar * ga.x + ba.x);
            unsigned int u1 = f2bf((a.y - mean) * ivar * ga.y + ba.y);
            unsigned int u2 = f2bf((a.z - mean) * ivar * ga.z + ba.z);
            unsigned int u3 = f2bf((a.w - mean) * ivar * ga.w + ba.w);
            unsigned int u4 = f2bf((b.x - mean) * ivar * gb2.x + bb2.x);
            unsigned int u5 = f2bf((b.y - mean) * ivar * gb2.y + bb2.y);
            unsigned int u6 = f2bf((b.z - mean) * ivar * gb2.z + bb2.z);
            unsigned int u7 = f2bf((b.w - mean) * ivar * gb2.w + bb2.w);
            int4 pv;
            pv.x = (int)(u0 | (u1 << 16)); pv.y = (int)(u2 | (u3 << 16));
            pv.z = (int)(u4 | (u5 << 16)); pv.w = (int)(u6 | (u7 << 16));
            *(int4*)&xb[r][lane * 8] = pv;
        }
    }
    __syncthreads();
    int wid = tid >> 6, lane = tid & 63;
    int l15 = lane & 15, kq = lane >> 4;
    int m_local = wid * 16;
    f32x4 acc[16];
#pragma unroll
    for (int j = 0; j < 16; j++) acc[j] = (f32x4){0.f, 0.f, 0.f, 0.f};
    for (int kt = 0; kt < 8; kt++) {
        int k0 = kt * 32;
#pragma unroll
        for (int h = 0; h < 4; h++) {
            int idx = tid + 256 * h;
            int n = idx >> 2, qc = idx & 3;
            *(int4*)&Bs[n][qc * 8] = *(const int4*)(Wb + (long)n * D_ + k0 + qc * 8);
        }
        __syncthreads();
        bf16x8 af = *(const bf16x8*)&xb[m_local + l15][k0 + kq * 8];
#pragma unroll
        for (int j = 0; j < 16; j++) {
            bf16x8 bf = *(const bf16x8*)&Bs[j * 16 + l15][kq * 8];
            acc[j] = __builtin_amdgcn_mfma_f32_16x16x32_bf16(af, bf, acc[j], 0, 0, 0);
        }
        __syncthreads();
    }
#pragma unroll
    for (int j = 0; j < 16; j++) {
        float bv = bsh[j * 16 + l15];
#pragma unroll
        for (int r = 0; r < 4; r++) acc[j][r] += bv;
    }
    float sq[4] = {0.f, 0.f, 0.f, 0.f};
#pragma unroll
    for (int j = 0; j < 16; j++)
#pragma unroll
        for (int r = 0; r < 4; r++) sq[r] += acc[j][r] * acc[j][r];
#pragma unroll
    for (int off = 8; off >= 1; off >>= 1) {
#pragma unroll
        for (int r = 0; r < 4; r++) sq[r] += __shfl_xor(sq[r], off);
    }
    float rinv[4];
#pragma unroll
    for (int r = 0; r < 4; r++) rinv[r] = 1.0f / fmaxf(sqrtf(sq[r]), 1e-12f);
    int bb = (int)(row0 / Lseq);
    int nloc = (int)(row0 % Lseq) + m_local + kq * 4;
#pragma unroll
    for (int j = 0; j < 16; j++) {
        int col = j * 16 + l15;
#pragma unroll
        for (int r = 0; r < 4; r++) {
            long m = row0 + m_local + kq * 4 + r;
            if (Pf) Pf[m * D_ + col] = acc[j][r];
            Nb[m * D_ + col] = f2bf(acc[j][r] * rinv[r]);
        }
        if (PT) {
            unsigned long long pv =
                  (unsigned long long)f2bf(acc[j][0])
                | ((unsigned long long)f2bf(acc[j][1]) << 16)
                | ((unsigned long long)f2bf(acc[j][2]) << 32)
                | ((unsigned long long)f2bf(acc[j][3]) << 48);
            *(unsigned long long*)(PT + ((long)bb * D_ + col) * Lseq + nloc) = pv;
        }
    }
}

// ---------------- K2: cost GEMM (MFMA bf16) -> logK u8 ----------------
__global__ __launch_bounds__(256) void k_cost_mfma(
    const unsigned short* __restrict__ Tnb, const unsigned short* __restrict__ Anb,
    unsigned char* __restrict__ logK8)
{
    __shared__ short As[128][48];
    __shared__ short Bs[128][48];
    int b = blockIdx.z;
    int m_blk = blockIdx.y * 128, n_blk = blockIdx.x * 128;
    int tid = threadIdx.x;
    int wid = tid >> 6, lane = tid & 63;
    int l15 = lane & 15, kq = lane >> 4;
    int wm0 = (wid >> 1) * 64, wn0 = (wid & 1) * 64;
    const unsigned short* Ab = Tnb + ((long)b * LT + m_blk) * D_;
    const unsigned short* Bb = Anb + ((long)b * LA + n_blk) * D_;
    f32x4 acc[4][4];
#pragma unroll
    for (int i = 0; i < 4; i++)
#pragma unroll
        for (int j = 0; j < 4; j++) acc[i][j] = (f32x4){0.f, 0.f, 0.f, 0.f};
    for (int kt = 0; kt < 8; kt++) {
        int k0 = kt * 32;
#pragma unroll
        for (int h = 0; h < 2; h++) {
            int idx = tid + 256 * h;
            int row = idx >> 2, ch = idx & 3;
            *(int4*)&As[row][ch * 8] = *(const int4*)(Ab + (long)row * D_ + k0 + ch * 8);
            *(int4*)&Bs[row][ch * 8] = *(const int4*)(Bb + (long)row * D_ + k0 + ch * 8);
        }
        __syncthreads();
        bf16x8 af[4], bfv[4];
#pragma unroll
        for (int i = 0; i < 4; i++) af[i] = *(const bf16x8*)&As[wm0 + i * 16 + l15][kq * 8];
#pragma unroll
        for (int j = 0; j < 4; j++) bfv[j] = *(const bf16x8*)&Bs[wn0 + j * 16 + l15][kq * 8];
#pragma unroll
        for (int i = 0; i < 4; i++)
#pragma unroll
            for (int j = 0; j < 4; j++)
                acc[i][j] = __builtin_amdgcn_mfma_f32_16x16x32_bf16(af[i], bfv[j], acc[i][j], 0, 0, 0);
        __syncthreads();
    }
#pragma unroll
    for (int i = 0; i < 4; i++) {
#pragma unroll
        for (int r = 0; r < 4; r++) {
            int m = m_blk + wm0 + i * 16 + kq * 4 + r;
            long base = ((long)b * LT + m) * (long)LA + n_blk;
#pragma unroll
            for (int j = 0; j < 4; j++) {
                int n = wn0 + j * 16 + l15;
                float q = rintf((1.0f - acc[i][j][r]) * 124.0f);
                q = fminf(fmaxf(q, 0.0f), 255.0f);
                logK8[base + n] = (unsigned char)q;
            }
        }
    }
}

// ---------------- K3: row sum-exp -> lu (u8 logK) ----------------
__global__ __launch_bounds__(256) void k_rowlse(
    const unsigned char* __restrict__ logK8, const float* __restrict__ lv, float* __restrict__ lu)
{
    __shared__ float red[4];
    long blk = blockIdx.x;
    int b = (int)(blk >> 10);
    const unsigned char* p = logK8 + blk * (long)LA;
    const float* lvp = lv + (long)b * LA;
    int tid = threadIdx.x;
    uint2 raw = *(const uint2*)(p + tid * 8);
    float4 l0 = *(const float4*)(lvp + tid * 8);
    float4 l1 = *(const float4*)(lvp + tid * 8 + 4);
    unsigned int w0 = raw.x, w1 = raw.y;
    float s = 0.f;
    s += __expf((float)(w0 & 0xffu) * DECQ + l0.x);
    s += __expf((float)((w0 >> 8) & 0xffu) * DECQ + l0.y);
    s += __expf((float)((w0 >> 16) & 0xffu) * DECQ + l0.z);
    s += __expf((float)(w0 >> 24) * DECQ + l0.w);
    s += __expf((float)(w1 & 0xffu) * DECQ + l1.x);
    s += __expf((float)((w1 >> 8) & 0xffu) * DECQ + l1.y);
    s += __expf((float)((w1 >> 16) & 0xffu) * DECQ + l1.z);
    s += __expf((float)(w1 >> 24) * DECQ + l1.w);
#pragma unroll
    for (int off = 32; off >= 1; off >>= 1) s += __shfl_xor(s, off);
    if ((tid & 63) == 0) red[tid >> 6] = s;
    __syncthreads();
    if (tid == 0) lu[blk] = -6.9314718055994531f - __logf(red[0] + red[1] + red[2] + red[3]);
}

// ---------------- K4: col sum-exp -> lv (u8 logK) ----------------
__global__ __launch_bounds__(256) void k_collse(
    const unsigned char* __restrict__ logK8, const float* __restrict__ lu, float* __restrict__ lv)
{
    __shared__ float lus[1024];
    __shared__ float redS[4][128];
    int b = blockIdx.y;
    int n0 = blockIdx.x * 128;
    int tid = threadIdx.x;
    for (int i = tid; i < 1024; i += 256) lus[i] = lu[(long)b * LT + i];
    __syncthreads();
    int c2 = (tid & 63) * 2;
    int g = tid >> 6;
    const unsigned char* base = logK8 + (long)b * LT * LA + n0 + c2;
    float S0 = 0.f, S1 = 0.f;
#pragma unroll 4
    for (int m = g; m < 1024; m += 4) {
        unsigned short raw = *(const unsigned short*)(base + (long)m * LA);
        float lm = lus[m];
        S0 += __expf((float)(raw & 0xffu) * DECQ + lm);
        S1 += __expf((float)(raw >> 8) * DECQ + lm);
    }
    redS[g][c2] = S0; redS[g][c2 + 1] = S1;
    __syncthreads();
    if (tid < 128) {
        float s = redS[0][tid] + redS[1][tid] + redS[2][tid] + redS[3][tid];
        lv[(long)b * LA + n0 + tid] = -7.6246189861593985f - __logf(s);
    }
}

// ---------------- K5: A_al = pi @ Ap (MFMA; u8 logK read once, K-split x2) ----------------
// grid (kh=2, LT/64, NB). Block: m-tile 64, full d=256, K-half 1024.
// Partials Apart[kh] summed in k_sresid.
__global__ __launch_bounds__(256) void k_pi_mfma(
    const unsigned char* __restrict__ logK8, const unsigned short* __restrict__ ApbT,
    const float* __restrict__ lu, const float* __restrict__ lv, float* __restrict__ Apart)
{
    __shared__ short As[64][48];    // pi [m][n-k] bf16
    __shared__ short Bs[256][48];   // ApT [d][n-k] bf16
    __shared__ float lv_s[1024];
    __shared__ float lu_s[64];
    int b = blockIdx.z;
    int m_blk = blockIdx.y * 64;
    int kh = blockIdx.x;
    int nbase = kh * 1024;
    int tid = threadIdx.x;
    for (int i = tid; i < 1024; i += 256) lv_s[i] = lv[(long)b * LA + nbase + i];
    if (tid < 64) lu_s[tid] = lu[(long)b * LT + m_blk + tid];
    __syncthreads();
    int wid = tid >> 6, lane = tid & 63;
    int l15 = lane & 15, kq = lane >> 4;
    int wm0 = (wid & 1) * 32, wd0 = (wid >> 1) * 128;
    f32x4 acc[2][8];
#pragma unroll
    for (int i = 0; i < 2; i++)
#pragma unroll
        for (int j = 0; j < 8; j++) acc[i][j] = (f32x4){0.f, 0.f, 0.f, 0.f};
    const unsigned char* Kbase = logK8 + ((long)b * LT + m_blk) * (long)LA + nbase;
    const unsigned short* Bbase = ApbT + (long)b * D_ * (long)LA + nbase;
    int arow = tid >> 2, ac8 = (tid & 3) * 8;
    for (int kt = 0; kt < 32; kt++) {
        int n0 = kt * 32;
        {   // A: pi tile 64x32 with decode+exp
            uint2 raw = *(const uint2*)(Kbase + (long)arow * LA + n0 + ac8);
            float lum = lu_s[arow];
            const float* lvp = &lv_s[n0 + ac8];
            unsigned int w0 = raw.x, w1 = raw.y;
            unsigned int o0 = f2bf(__expf((float)(w0 & 0xffu) * DECQ + lum + lvp[0]));
            unsigned int o1 = f2bf(__expf((float)((w0 >> 8) & 0xffu) * DECQ + lum + lvp[1]));
            unsigned int o2 = f2bf(__expf((float)((w0 >> 16) & 0xffu) * DECQ + lum + lvp[2]));
            unsigned int o3 = f2bf(__expf((float)(w0 >> 24) * DECQ + lum + lvp[3]));
            unsigned int o4 = f2bf(__expf((float)(w1 & 0xffu) * DECQ + lum + lvp[4]));
            unsigned int o5 = f2bf(__expf((float)((w1 >> 8) & 0xffu) * DECQ + lum + lvp[5]));
            unsigned int o6 = f2bf(__expf((float)((w1 >> 16) & 0xffu) * DECQ + lum + lvp[6]));
            unsigned int o7 = f2bf(__expf((float)(w1 >> 24) * DECQ + lum + lvp[7]));
            int4 ov;
            ov.x = (int)(o0 | (o1 << 16)); ov.y = (int)(o2 | (o3 << 16));
            ov.z = (int)(o4 | (o5 << 16)); ov.w = (int)(o6 | (o7 << 16));
            *(int4*)&As[arow][ac8] = ov;
        }
#pragma unroll
        for (int h = 0; h < 4; h++) {   // B: 256 d-rows x 32
            int idx = tid + 256 * h;
            int row = idx >> 2, ch = idx & 3;
            *(int4*)&Bs[row][ch * 8] = *(const int4*)(Bbase + (long)row * LA + n0 + ch * 8);
        }
        __syncthreads();
        bf16x8 af[2], bfv[8];
        af[0] = *(const bf16x8*)&As[wm0 + l15][kq * 8];
        af[1] = *(const bf16x8*)&As[wm0 + 16 + l15][kq * 8];
#pragma unroll
        for (int j = 0; j < 8; j++) bfv[j] = *(const bf16x8*)&Bs[wd0 + j * 16 + l15][kq * 8];
#pragma unroll
        for (int i = 0; i < 2; i++)
#pragma unroll
            for (int j = 0; j < 8; j++)
                acc[i][j] = __builtin_amdgcn_mfma_f32_16x16x32_bf16(af[i], bfv[j], acc[i][j], 0, 0, 0);
        __syncthreads();
    }
    float* dst = Apart + (long)kh * (NB * (long)LT * D_);
#pragma unroll
    for (int i = 0; i < 2; i++) {
#pragma unroll
        for (int r = 0; r < 4; r++) {
            int m = m_blk + wm0 + i * 16 + kq * 4 + r;
            long obase = ((long)b * LT + m) * D_;
#pragma unroll
            for (int j = 0; j < 8; j++)
                dst[obase + wd0 + j * 16 + l15] = acc[i][j][r];
        }
    }
}

// ---------------- K6: combine K-halves, S = <Tp, A_al>, resid = |Tp - A_al| ----------------
__global__ __launch_bounds__(256) void k_sresid(
    const float* __restrict__ Tp, const float* __restrict__ Apart,
    float* __restrict__ resid, unsigned short* __restrict__ residb, float* __restrict__ S)
{
    __shared__ float red[4];
    long row = blockIdx.x;
    int tid = threadIdx.x;
    long idx = row * D_ + tid;
    float t = Tp[idx];
    float a = Apart[idx] + Apart[idx + (long)NB * LT * D_];
    float rr = fabsf(t - a);
    resid[idx] = rr;
    residb[idx] = f2bf(rr);
    float p = t * a;
#pragma unroll
    for (int off = 32; off >= 1; off >>= 1) p += __shfl_xor(p, off);
    if ((tid & 63) == 0) red[tid >> 6] = p;
    __syncthreads();
    if (tid == 0) S[row] = red[0] + red[1] + red[2] + red[3];
}

// ---------------- K7a: H = gelu(residb @ Wr1b^T + S*w0 + br1) (MFMA) ----------------
__global__ __launch_bounds__(256) void k_router1_mfma(
    const unsigned short* __restrict__ residb, const unsigned short* __restrict__ Wr1b,
    const float* __restrict__ Wr1, const float* __restrict__ br1,
    const float* __restrict__ S, float* __restrict__ H)
{
    __shared__ short xb[64][264];
    __shared__ short Bs[256][40];
    int tid = threadIdx.x;
    long row0 = (long)blockIdx.x * 64;
#pragma unroll
    for (int h = 0; h < 8; h++) {
        int idx = tid + 256 * h;
        int row = idx >> 5, ch = idx & 31;
        *(int4*)&xb[row][ch * 8] = *(const int4*)(residb + (row0 + row) * D_ + ch * 8);
    }
    __syncthreads();
    int wid = tid >> 6, lane = tid & 63;
    int l15 = lane & 15, kq = lane >> 4;
    int m_local = wid * 16;
    f32x4 acc[16];
#pragma unroll
    for (int j = 0; j < 16; j++) acc[j] = (f32x4){0.f, 0.f, 0.f, 0.f};
    for (int kt = 0; kt < 8; kt++) {
        int k0 = kt * 32;
#pragma unroll
        for (int h = 0; h < 4; h++) {
            int idx = tid + 256 * h;
            int n = idx >> 2, qc = idx & 3;
            *(int4*)&Bs[n][qc * 8] = *(const int4*)(Wr1b + (long)n * D_ + k0 + qc * 8);
        }
        __syncthreads();
        bf16x8 af = *(const bf16x8*)&xb[m_local + l15][k0 + kq * 8];
#pragma unroll
        for (int j = 0; j < 16; j++) {
            bf16x8 bf = *(const bf16x8*)&Bs[j * 16 + l15][kq * 8];
            acc[j] = __builtin_amdgcn_mfma_f32_16x16x32_bf16(af, bf, acc[j], 0, 0, 0);
        }
        __syncthreads();
    }
    float sv[4];
#pragma unroll
    for (int r = 0; r < 4; r++) sv[r] = S[row0 + m_local + kq * 4 + r];
#pragma unroll
    for (int j = 0; j < 16; j++) {
        int col = j * 16 + l15;
        float w0 = Wr1[(long)col * 257];
        float bv = br1[col];
#pragma unroll
        for (int r = 0; r < 4; r++) {
            long m = row0 + m_local + kq * 4 + r;
            H[m * D_ + col] = gelu_f(acc[j][r] + sv[r] * w0 + bv);
        }
    }
}

// ---------------- K7b: logits + softmax -> G planes [3][16384] ----------------
__global__ __launch_bounds__(256) void k_router2(
    const float* __restrict__ H, const float* __restrict__ Wr2,
    const float* __restrict__ br2, float* __restrict__ G)
{
    __shared__ float rd[3][4];
    long row = blockIdx.x;
    int tid = threadIdx.x;
    float h = H[row * D_ + tid];
    float l0 = h * Wr2[tid], l1 = h * Wr2[256 + tid], l2 = h * Wr2[512 + tid];
#pragma unroll
    for (int off = 32; off >= 1; off >>= 1) {
        l0 += __shfl_xor(l0, off); l1 += __shfl_xor(l1, off); l2 += __shfl_xor(l2, off);
    }
    if ((tid & 63) == 0) { int w = tid >> 6; rd[0][w] = l0; rd[1][w] = l1; rd[2][w] = l2; }
    __syncthreads();
    if (tid == 0) {
        float L0 = rd[0][0] + rd[0][1] + rd[0][2] + rd[0][3] + br2[0];
        float L1 = rd[1][0] + rd[1][1] + rd[1][2] + rd[1][3] + br2[1];
        float L2 = rd[2][0] + rd[2][1] + rd[2][2] + rd[2][3] + br2[2];
        float mx = fmaxf(L0, fmaxf(L1, L2));
        float e0 = __expf(L0 - mx), e1 = __expf(L1 - mx), e2 = __expf(L2 - mx);
        float inv = 1.0f / (e0 + e1 + e2);
        G[row] = e0 * inv; G[NRT + row] = e1 * inv; G[2 * NRT + row] = e2 * inv;
    }
}

// ---------------- K8a: h[e] = gelu(residb @ down_W[e]^T + down_b[e]) (MFMA, all experts) ----------------
__global__ __launch_bounds__(256) void k_down_mfma(
    const unsigned short* __restrict__ residb, const unsigned short* __restrict__ dWb,
    const float* __restrict__ db, float* __restrict__ hall)
{
    __shared__ short xb[64][264];
    __shared__ short Bs[64][40];
    int tid = threadIdx.x;
    int e = blockIdx.y;
    long row0 = (long)blockIdx.x * 64;
    const unsigned short* dWe = dWb + (long)e * RR_ * D_;
    float* h = hall + (long)e * NRT * RR_;
#pragma unroll
    for (int hh = 0; hh < 8; hh++) {
        int idx = tid + 256 * hh;
        int row = idx >> 5, ch = idx & 31;
        *(int4*)&xb[row][ch * 8] = *(const int4*)(residb + (row0 + row) * D_ + ch * 8);
    }
    __syncthreads();
    int wid = tid >> 6, lane = tid & 63;
    int l15 = lane & 15, kq = lane >> 4;
    int m_local = wid * 16;
    f32x4 acc[4];
#pragma unroll
    for (int j = 0; j < 4; j++) acc[j] = (f32x4){0.f, 0.f, 0.f, 0.f};
    for (int kt = 0; kt < 8; kt++) {
        int k0 = kt * 32;
        {
            int n = tid >> 2, qc = tid & 3;
            *(int4*)&Bs[n][qc * 8] = *(const int4*)(dWe + (long)n * D_ + k0 + qc * 8);
        }
        __syncthreads();
        bf16x8 af = *(const bf16x8*)&xb[m_local + l15][k0 + kq * 8];
#pragma unroll
        for (int j = 0; j < 4; j++) {
            bf16x8 bf = *(const bf16x8*)&Bs[j * 16 + l15][kq * 8];
            acc[j] = __builtin_amdgcn_mfma_f32_16x16x32_bf16(af, bf, acc[j], 0, 0, 0);
        }
        __syncthreads();
    }
#pragma unroll
    for (int j = 0; j < 4; j++) {
        int col = j * 16 + l15;
        float bv = db[e * RR_ + col];
#pragma unroll
        for (int r = 0; r < 4; r++) {
            long m = row0 + m_local + kq * 4 + r;
            h[m * RR_ + col] = gelu_f(acc[j][r] + bv);
        }
    }
}

// ---------------- K8b: depth-conv over sequence (tap-sliced LDS GEMM) -> bf16 ----------------
__global__ __launch_bounds__(256) void k_conv(
    const float* __restrict__ h, const float* __restrict__ w,
    const float* __restrict__ cb, unsigned short* __restrict__ hcb, int ksz)
{
    __shared__ float hs[68][68];
    __shared__ float wt[64][64];
    int blk = blockIdx.x;
    int b = blk >> 4, m0 = (blk & 15) * 64;
    int tid = threadIdx.x;
    int pad = (ksz - 1) >> 1;
    for (int idx = tid; idx < 68 * 16; idx += 256) {
        int mr = idx >> 4, i4 = idx & 15;
        int mm = m0 - 2 + mr;
        float4 vv = { 0.f, 0.f, 0.f, 0.f };
        if (mm >= 0 && mm < LT) vv = *(const float4*)(h + ((long)b * LT + mm) * RR_ + i4 * 4);
        *(float4*)&hs[mr][i4 * 4] = vv;
    }
    int tx = tid & 15, ty = tid >> 4;
    float acc[4][4] = {};
    for (int t = 0; t < ksz; t++) {
        __syncthreads();
        for (int idx = tid; idx < 4096; idx += 256) {
            int i = idx & 63, j = idx >> 6;
            wt[i][j] = w[(long)j * RR_ * ksz + i * ksz + t];
        }
        __syncthreads();
        int roff = ty * 4 + 2 + t - pad;
        for (int i4 = 0; i4 < 16; i4++) {
            float4 h0 = *(const float4*)&hs[roff + 0][i4 * 4];
            float4 h1 = *(const float4*)&hs[roff + 1][i4 * 4];
            float4 h2 = *(const float4*)&hs[roff + 2][i4 * 4];
            float4 h3 = *(const float4*)&hs[roff + 3][i4 * 4];
            float hh[4][4] = { { h0.x, h0.y, h0.z, h0.w }, { h1.x, h1.y, h1.z, h1.w },
                               { h2.x, h2.y, h2.z, h2.w }, { h3.x, h3.y, h3.z, h3.w } };
#pragma unroll
            for (int s = 0; s < 4; s++) {
                float4 wv = *(const float4*)&wt[i4 * 4 + s][tx * 4];
#pragma unroll
                for (int r = 0; r < 4; r++) {
                    acc[r][0] += hh[r][s] * wv.x;
                    acc[r][1] += hh[r][s] * wv.y;
                    acc[r][2] += hh[r][s] * wv.z;
                    acc[r][3] += hh[r][s] * wv.w;
                }
            }
        }
    }
    float4 bb = *(const float4*)(cb + tx * 4);
#pragma unroll
    for (int r = 0; r < 4; r++) {
        long m = (long)b * LT + m0 + ty * 4 + r;
        unsigned long long pv =
              (unsigned long long)f2bf(gelu_f(acc[r][0] + bb.x))
            | ((unsigned long long)f2bf(gelu_f(acc[r][1] + bb.y)) << 16)
            | ((unsigned long long)f2bf(gelu_f(acc[r][2] + bb.z)) << 32)
            | ((unsigned long long)f2bf(gelu_f(acc[r][3] + bb.w)) << 48);
        *(unsigned long long*)(hcb + m * RR_ + tx * 4) = pv;
    }
}

// ---------------- K8c: up-proj + residual + LN (in-wave) + gated accumulate (MFMA) ----------------
__global__ __launch_bounds__(256) void k_up_mfma(
    const unsigned short* __restrict__ hcb, const unsigned short* __restrict__ uWb,
    const float* __restrict__ ub, const float* __restrict__ resid,
    const float* __restrict__ eg, const float* __restrict__ eb,
    const float* __restrict__ G, float* __restrict__ out, int isFirst)
{
    __shared__ short hs[64][88];
    __shared__ short Bs[256][40];
    int tid = threadIdx.x;
    long row0 = (long)blockIdx.x * 64;
#pragma unroll
    for (int hh = 0; hh < 2; hh++) {
        int idx = tid + 256 * hh;
        int row = idx >> 3, ch = idx & 7;
        *(int4*)&hs[row][ch * 8] = *(const int4*)(hcb + (row0 + row) * RR_ + ch * 8);
    }
    __syncthreads();
    int wid = tid >> 6, lane = tid & 63;
    int l15 = lane & 15, kq = lane >> 4;
    int m_local = wid * 16;
    f32x4 acc[16];
#pragma unroll
    for (int j = 0; j < 16; j++) acc[j] = (f32x4){0.f, 0.f, 0.f, 0.f};
    for (int kt = 0; kt < 2; kt++) {
        int k0 = kt * 32;
#pragma unroll
        for (int hh = 0; hh < 4; hh++) {
            int idx = tid + 256 * hh;
            int n = idx >> 2, qc = idx & 3;
            *(int4*)&Bs[n][qc * 8] = *(const int4*)(uWb + (long)n * RR_ + k0 + qc * 8);
        }
        __syncthreads();
        bf16x8 af = *(const bf16x8*)&hs[m_local + l15][k0 + kq * 8];
#pragma unroll
        for (int j = 0; j < 16; j++) {
            bf16x8 bf = *(const bf16x8*)&Bs[j * 16 + l15][kq * 8];
            acc[j] = __builtin_amdgcn_mfma_f32_16x16x32_bf16(af, bf, acc[j], 0, 0, 0);
        }
        __syncthreads();
    }
    long mrow[4];
#pragma unroll
    for (int r = 0; r < 4; r++) mrow[r] = row0 + m_local + kq * 4 + r;
#pragma unroll
    for (int j = 0; j < 16; j++) {
        int col = j * 16 + l15;
        float bv = ub[col];
#pragma unroll
        for (int r = 0; r < 4; r++)
            acc[j][r] += bv + resid[mrow[r] * D_ + col];
    }
    float s[4] = {0.f, 0.f, 0.f, 0.f};
#pragma unroll
    for (int j = 0; j < 16; j++)
#pragma unroll
        for (int r = 0; r < 4; r++) s[r] += acc[j][r];
#pragma unroll
    for (int off = 8; off >= 1; off >>= 1)
#pragma unroll
        for (int r = 0; r < 4; r++) s[r] += __shfl_xor(s[r], off);
    float mn[4];
#pragma unroll
    for (int r = 0; r < 4; r++) mn[r] = s[r] * (1.0f / 256.0f);
    float q[4] = {0.f, 0.f, 0.f, 0.f};
#pragma unroll
    for (int j = 0; j < 16; j++)
#pragma unroll
        for (int r = 0; r < 4; r++) { float d = acc[j][r] - mn[r]; q[r] += d * d; }
#pragma unroll
    for (int off = 8; off >= 1; off >>= 1)
#pragma unroll
        for (int r = 0; r < 4; r++) q[r] += __shfl_xor(q[r], off);
    float iv[4], gv[4];
#pragma unroll
    for (int r = 0; r < 4; r++) {
        iv[r] = rsqrtf(q[r] * (1.0f / 256.0f) + 1e-5f);
        gv[r] = G[mrow[r]];
    }
#pragma unroll
    for (int j = 0; j < 16; j++) {
        int col = j * 16 + l15;
        float egc = eg[col], ebc = eb[col];
#pragma unroll
        for (int r = 0; r < 4; r++) {
            float eo = (acc[j][r] - mn[r]) * iv[r] * egc + ebc;
            long o = mrow[r] * D_ + col;
            if (isFirst) out[o] = gv[r] * eo;
            else out[o] += gv[r] * eo;
        }
    }
}

__global__ void k_zero(float* p, int n) {
    int i = blockIdx.x * 256 + threadIdx.x;
    if (i < n) p[i] = 0.f;
}

extern "C" void kernel_launch(void* const* d_in, const int* in_sizes, int n_in,
                              void* d_out, int out_size, void* d_ws, size_t ws_size,
                              hipStream_t stream)
{
    const float* text   = (const float*)d_in[0];
    const float* audio  = (const float*)d_in[1];
    const float* ln_g   = (const float*)d_in[2];
    const float* ln_b   = (const float*)d_in[3];
    const float* W_sh   = (const float*)d_in[4];
    const float* b_sh   = (const float*)d_in[5];
    const float* Wr1    = (const float*)d_in[6];
    const float* br1    = (const float*)d_in[7];
    const float* Wr2    = (const float*)d_in[8];
    const float* br2    = (const float*)d_in[9];
    const float* down_W = (const float*)d_in[10];
    const float* down_b = (const float*)d_in[11];
    const float* cw1    = (const float*)d_in[12];
    const float* cw3    = (const float*)d_in[13];
    const float* cw5    = (const float*)d_in[14];
    const float* conv_b = (const float*)d_in[15];
    const float* up_W   = (const float*)d_in[16];
    const float* up_b   = (const float*)d_in[17];
    const float* en_g   = (const float*)d_in[18];
    const float* en_b   = (const float*)d_in[19];

    float* ws = (float*)d_ws;
    float*          Tp    = ws;                               // [0, 4194304)
    unsigned short* Tnb   = (unsigned short*)(ws + 4194304);  // 2,097,152 f
    unsigned short* Anb   = (unsigned short*)(ws + 6291456);  // 4,194,304 f
    unsigned short* ApbT  = (unsigned short*)(ws + 10485760); // 4,194,304 f
    unsigned char*  logK8 = (unsigned char*)(ws + 14680064);  // 8,388,608 f (33.5 MB u8)
    float*          Apart = ws + 23068672;                    // 2 x 4,194,304 f
    float*          resid = ws + 31457280;                    // 4,194,304 f
    unsigned short* residb= (unsigned short*)(ws + 35651584); // 2,097,152 f
    float*          lu    = ws + 37748736;                    // 16,384
    float*          lv    = ws + 37765120;                    // 32,768
    float*          Sb    = ws + 37797888;                    // 16,384
    float*          Gb    = ws + 37814272;                    // 49,152
    unsigned short* Wb    = (unsigned short*)(ws + 37863424); // 32,768 f
    unsigned short* dWb   = (unsigned short*)(ws + 37896192); // 24,576 f
    unsigned short* uWb   = (unsigned short*)(ws + 37920768); // 24,576 f
    unsigned short* Wr1b  = (unsigned short*)(ws + 37945344); // 32,768 f
    size_t need_bytes = (size_t)37978112 * 4;
    if (ws_size < need_bytes) {
        fprintf(stderr, "kernel_launch: ws_size %zu < needed %zu\n", ws_size, need_bytes);
        return;
    }
    // aliases in logK8 region (dead after k_pi_mfma):
    float*          H    = ws + 14680064;                     // 4,194,304 f (dead after k_router2)
    float*          hall = ws + 18874368;                     // 3,145,728 f
    unsigned short* hcbb = (unsigned short*)(ws + 14680064);  // over H, written after router2

    k_prep_w<<<256, 256, 0, stream>>>(W_sh, Wb, 65536);
    k_prep_w<<<192, 256, 0, stream>>>(down_W, dWb, 49152);
    k_prep_w<<<192, 256, 0, stream>>>(up_W, uWb, 49152);
    k_prep_wr1<<<256, 256, 0, stream>>>(Wr1, Wr1b);
    k_lnproj_mfma<<<NRT / 64, 256, 0, stream>>>(text, ln_g, ln_b, Wb, b_sh, Tp, Tnb, nullptr, LT);
    k_lnproj_mfma<<<NRA / 64, 256, 0, stream>>>(audio, ln_g, ln_b, Wb, b_sh, nullptr, Anb, ApbT, LA);
    k_cost_mfma<<<dim3(LA / 128, LT / 128, NB), 256, 0, stream>>>(Tnb, Anb, logK8);
    k_zero<<<192, 256, 0, stream>>>(lu, 16384 + 32768);
    for (int it = 0; it < 10; it++) {
        k_rowlse<<<NRT, 256, 0, stream>>>(logK8, lv, lu);
        k_collse<<<dim3(LA / 128, NB), 256, 0, stream>>>(logK8, lu, lv);
    }
    k_pi_mfma<<<dim3(2, LT / 64, NB), 256, 0, stream>>>(logK8, ApbT, lu, lv, Apart);
    k_sresid<<<NRT, 256, 0, stream>>>(Tp, Apart, resid, residb, Sb);
    k_router1_mfma<<<NRT / 64, 256, 0, stream>>>(residb, Wr1b, Wr1, br1, Sb, H);
    k_router2<<<NRT, 256, 0, stream>>>(H, Wr2, br2, Gb);
    k_down_mfma<<<dim3(NRT / 64, 3), 256, 0, stream>>>(residb, dWb, down_b, hall);
    for (int e = 0; e < 3; e++) {
        const float* cw = (e == 0) ? cw1 : ((e == 1) ? cw3 : cw5);
        int ksz = (e == 0) ? 1 : ((e == 1) ? 3 : 5);
        k_conv<<<NRT / 64, 256, 0, stream>>>(hall + (long)e * NRT * RR_, cw, conv_b + e * 64,
                                             hcbb + (long)e * NRT * RR_, ksz);
    }
    for (int e = 0; e < 3; e++) {
        k_up_mfma<<<NRT / 64, 256, 0, stream>>>(hcbb + (long)e * NRT * RR_, uWb + (long)e * 16384,
                                                up_b + e * 256, resid, en_g + e * 256, en_b + e * 256,
                                                Gb + (long)e * NRT, (float*)d_out, e == 0 ? 1 : 0);
    }
}

// Round 7
// 652.126 us; speedup vs baseline: 4.0356x; 1.2741x over previous
//
#include <hip/hip_runtime.h>
#include <cstdio>

#define D_ 256
#define LT 1024
#define LA 2048
#define NB 16
#define RR_ 64
#define NRT (NB*LT)   // 16384 text rows
#define NRA (NB*LA)   // 32768 audio rows

// logK u8 quantization: q = rint((1-cos)*124), logK_hat = q * DECQ
#define DECQ (-0.080645161f)

typedef short bf16x8 __attribute__((ext_vector_type(8)));
typedef float f32x4 __attribute__((ext_vector_type(4)));

__device__ __forceinline__ float gelu_f(float x) {
    return 0.5f * x * (1.0f + erff(x * 0.70710678118654752f));
}
__device__ __forceinline__ unsigned short f2bf(float f) {   // RNE
    union { float f; unsigned int i; } c; c.f = f;
    unsigned int x = c.i;
    return (unsigned short)((x + 0x7fffu + ((x >> 16) & 1u)) >> 16);
}

// ---------------- prep: all weight fp32->bf16 conversions in ONE launch ----------------
__global__ __launch_bounds__(256) void k_prep_all(
    const float* __restrict__ W_sh, const float* __restrict__ down_W,
    const float* __restrict__ up_W, const float* __restrict__ Wr1,
    unsigned short* __restrict__ Wb, unsigned short* __restrict__ dWb,
    unsigned short* __restrict__ uWb, unsigned short* __restrict__ Wr1b)
{
    int i = blockIdx.x * 256 + threadIdx.x;          // 0 .. 229375
    if (i < 65536) Wb[i] = f2bf(W_sh[i]);
    else if (i < 114688) { int j = i - 65536; dWb[j] = f2bf(down_W[j]); }
    else if (i < 163840) { int j = i - 114688; uWb[j] = f2bf(up_W[j]); }
    else { int j = i - 163840; int n = j >> 8, k = j & 255; Wr1b[j] = f2bf(Wr1[(long)n * 257 + 1 + k]); }
}

// ---------------- K1: LayerNorm + shared projection (MFMA) ----------------
__global__ __launch_bounds__(256) void k_lnproj_mfma(
    const float* __restrict__ X, const float* __restrict__ g, const float* __restrict__ bln,
    const unsigned short* __restrict__ Wb, const float* __restrict__ bsh,
    float* __restrict__ Pf, unsigned short* __restrict__ Nb)
{
    __shared__ short xb[64][264];
    __shared__ short Bs[256][40];
    int tid = threadIdx.x;
    long row0 = (long)blockIdx.x * 64;
    {
        int lane = tid & 31, rg = tid >> 5;
        float4 ga = *(const float4*)(g + lane * 8);
        float4 gb2 = *(const float4*)(g + lane * 8 + 4);
        float4 ba = *(const float4*)(bln + lane * 8);
        float4 bb2 = *(const float4*)(bln + lane * 8 + 4);
        for (int it = 0; it < 8; it++) {
            int r = it * 8 + rg;
            const float4* xp4 = (const float4*)(X + (row0 + r) * D_);
            float4 a = xp4[lane * 2], b = xp4[lane * 2 + 1];
            float s = a.x + a.y + a.z + a.w + b.x + b.y + b.z + b.w;
#pragma unroll
            for (int off = 16; off >= 1; off >>= 1) s += __shfl_xor(s, off);
            float mean = s * (1.0f / 256.0f);
            float q = (a.x - mean) * (a.x - mean) + (a.y - mean) * (a.y - mean)
                    + (a.z - mean) * (a.z - mean) + (a.w - mean) * (a.w - mean)
                    + (b.x - mean) * (b.x - mean) + (b.y - mean) * (b.y - mean)
                    + (b.z - mean) * (b.z - mean) + (b.w - mean) * (b.w - mean);
#pragma unroll
            for (int off = 16; off >= 1; off >>= 1) q += __shfl_xor(q, off);
            float ivar = rsqrtf(q * (1.0f / 256.0f) + 1e-5f);
            unsigned int u0 = f2bf((a.x - mean) * ivar * ga.x + ba.x);
            unsigned int u1 = f2bf((a.y - mean) * ivar * ga.y + ba.y);
            unsigned int u2 = f2bf((a.z - mean) * ivar * ga.z + ba.z);
            unsigned int u3 = f2bf((a.w - mean) * ivar * ga.w + ba.w);
            unsigned int u4 = f2bf((b.x - mean) * ivar * gb2.x + bb2.x);
            unsigned int u5 = f2bf((b.y - mean) * ivar * gb2.y + bb2.y);
            unsigned int u6 = f2bf((b.z - mean) * ivar * gb2.z + bb2.z);
            unsigned int u7 = f2bf((b.w - mean) * ivar * gb2.w + bb2.w);
            int4 pv;
            pv.x = (int)(u0 | (u1 << 16)); pv.y = (int)(u2 | (u3 << 16));
            pv.z = (int)(u4 | (u5 << 16)); pv.w = (int)(u6 | (u7 << 16));
            *(int4*)&xb[r][lane * 8] = pv;
        }
    }
    __syncthreads();
    int wid = tid >> 6, lane = tid & 63;
    int l15 = lane & 15, kq = lane >> 4;
    int m_local = wid * 16;
    f32x4 acc[16];
#pragma unroll
    for (int j = 0; j < 16; j++) acc[j] = (f32x4){0.f, 0.f, 0.f, 0.f};
    for (int kt = 0; kt < 8; kt++) {
        int k0 = kt * 32;
#pragma unroll
        for (int h = 0; h < 4; h++) {
            int idx = tid + 256 * h;
            int n = idx >> 2, qc = idx & 3;
            *(int4*)&Bs[n][qc * 8] = *(const int4*)(Wb + (long)n * D_ + k0 + qc * 8);
        }
        __syncthreads();
        bf16x8 af = *(const bf16x8*)&xb[m_local + l15][k0 + kq * 8];
#pragma unroll
        for (int j = 0; j < 16; j++) {
            bf16x8 bf = *(const bf16x8*)&Bs[j * 16 + l15][kq * 8];
            acc[j] = __builtin_amdgcn_mfma_f32_16x16x32_bf16(af, bf, acc[j], 0, 0, 0);
        }
        __syncthreads();
    }
#pragma unroll
    for (int j = 0; j < 16; j++) {
        float bv = bsh[j * 16 + l15];
#pragma unroll
        for (int r = 0; r < 4; r++) acc[j][r] += bv;
    }
    float sq[4] = {0.f, 0.f, 0.f, 0.f};
#pragma unroll
    for (int j = 0; j < 16; j++)
#pragma unroll
        for (int r = 0; r < 4; r++) sq[r] += acc[j][r] * acc[j][r];
#pragma unroll
    for (int off = 8; off >= 1; off >>= 1) {
#pragma unroll
        for (int r = 0; r < 4; r++) sq[r] += __shfl_xor(sq[r], off);
    }
    float rinv[4];
#pragma unroll
    for (int r = 0; r < 4; r++) rinv[r] = 1.0f / fmaxf(sqrtf(sq[r]), 1e-12f);
#pragma unroll
    for (int j = 0; j < 16; j++) {
        int col = j * 16 + l15;
#pragma unroll
        for (int r = 0; r < 4; r++) {
            long m = row0 + m_local + kq * 4 + r;
            if (Pf) Pf[m * D_ + col] = acc[j][r];
            Nb[m * D_ + col] = f2bf(acc[j][r] * rinv[r]);
        }
    }
}

// ---------------- K1b: Anb [b][n][d] -> ApbT [b][d][n] (LDS-tiled transpose) ----------------
__global__ __launch_bounds__(256) void k_transpose_bf(
    const unsigned short* __restrict__ Anb, unsigned short* __restrict__ ApbT)
{
    __shared__ short t[64][68];
    int b = blockIdx.x;              // batch fastest -> XCD pinned
    int n0 = blockIdx.y * 64;
    int d0 = blockIdx.z * 64;
    int tid = threadIdx.x;
#pragma unroll
    for (int h = 0; h < 2; h++) {
        int c = tid + 256 * h;       // 512 chunks
        int nr = c >> 3, ch = c & 7;
        *(int4*)&t[nr][ch * 8] = *(const int4*)(Anb + ((long)b * LA + n0 + nr) * D_ + d0 + ch * 8);
    }
    __syncthreads();
#pragma unroll
    for (int h = 0; h < 2; h++) {
        int c = tid + 256 * h;
        int d = c >> 3, nch = c & 7;
        unsigned short v[8];
#pragma unroll
        for (int k = 0; k < 8; k++) v[k] = (unsigned short)t[nch * 8 + k][d];
        int4 ov;
        ov.x = (int)((unsigned int)v[0] | ((unsigned int)v[1] << 16));
        ov.y = (int)((unsigned int)v[2] | ((unsigned int)v[3] << 16));
        ov.z = (int)((unsigned int)v[4] | ((unsigned int)v[5] << 16));
        ov.w = (int)((unsigned int)v[6] | ((unsigned int)v[7] << 16));
        *(int4*)(ApbT + ((long)b * D_ + d0 + d) * LA + n0 + nch * 8) = ov;
    }
}

// ---------------- K2: cost GEMM (MFMA bf16) -> logK u8 (batch-fastest grid) ----------------
__global__ __launch_bounds__(256) void k_cost_mfma(
    const unsigned short* __restrict__ Tnb, const unsigned short* __restrict__ Anb,
    unsigned char* __restrict__ logK8)
{
    __shared__ short As[128][48];
    __shared__ short Bs[128][48];
    int b = blockIdx.x;
    int m_blk = blockIdx.y * 128, n_blk = blockIdx.z * 128;
    int tid = threadIdx.x;
    int wid = tid >> 6, lane = tid & 63;
    int l15 = lane & 15, kq = lane >> 4;
    int wm0 = (wid >> 1) * 64, wn0 = (wid & 1) * 64;
    const unsigned short* Ab = Tnb + ((long)b * LT + m_blk) * D_;
    const unsigned short* Bb = Anb + ((long)b * LA + n_blk) * D_;
    f32x4 acc[4][4];
#pragma unroll
    for (int i = 0; i < 4; i++)
#pragma unroll
        for (int j = 0; j < 4; j++) acc[i][j] = (f32x4){0.f, 0.f, 0.f, 0.f};
    for (int kt = 0; kt < 8; kt++) {
        int k0 = kt * 32;
#pragma unroll
        for (int h = 0; h < 2; h++) {
            int idx = tid + 256 * h;
            int row = idx >> 2, ch = idx & 3;
            *(int4*)&As[row][ch * 8] = *(const int4*)(Ab + (long)row * D_ + k0 + ch * 8);
            *(int4*)&Bs[row][ch * 8] = *(const int4*)(Bb + (long)row * D_ + k0 + ch * 8);
        }
        __syncthreads();
        bf16x8 af[4], bfv[4];
#pragma unroll
        for (int i = 0; i < 4; i++) af[i] = *(const bf16x8*)&As[wm0 + i * 16 + l15][kq * 8];
#pragma unroll
        for (int j = 0; j < 4; j++) bfv[j] = *(const bf16x8*)&Bs[wn0 + j * 16 + l15][kq * 8];
#pragma unroll
        for (int i = 0; i < 4; i++)
#pragma unroll
            for (int j = 0; j < 4; j++)
                acc[i][j] = __builtin_amdgcn_mfma_f32_16x16x32_bf16(af[i], bfv[j], acc[i][j], 0, 0, 0);
        __syncthreads();
    }
#pragma unroll
    for (int i = 0; i < 4; i++) {
#pragma unroll
        for (int r = 0; r < 4; r++) {
            int m = m_blk + wm0 + i * 16 + kq * 4 + r;
            long base = ((long)b * LT + m) * (long)LA + n_blk;
#pragma unroll
            for (int j = 0; j < 4; j++) {
                int n = wn0 + j * 16 + l15;
                float q = rintf((1.0f - acc[i][j][r]) * 124.0f);
                q = fminf(fmaxf(q, 0.0f), 255.0f);
                logK8[base + n] = (unsigned char)q;
            }
        }
    }
}

// ---------------- K3: row sum-exp -> lu (u8 logK, batch-fastest) ----------------
__global__ __launch_bounds__(256) void k_rowlse(
    const unsigned char* __restrict__ logK8, const float* __restrict__ lv,
    float* __restrict__ lu, int first)
{
    __shared__ float red[4];
    int b = blockIdx.x & 15;
    int m = blockIdx.x >> 4;
    long row = (long)b * LT + m;
    const unsigned char* p = logK8 + row * (long)LA;
    int tid = threadIdx.x;
    uint2 raw = *(const uint2*)(p + tid * 8);
    float lvv[8] = {0.f, 0.f, 0.f, 0.f, 0.f, 0.f, 0.f, 0.f};
    if (!first) {
        const float* lvp = lv + (long)b * LA;
        float4 l0 = *(const float4*)(lvp + tid * 8);
        float4 l1 = *(const float4*)(lvp + tid * 8 + 4);
        lvv[0] = l0.x; lvv[1] = l0.y; lvv[2] = l0.z; lvv[3] = l0.w;
        lvv[4] = l1.x; lvv[5] = l1.y; lvv[6] = l1.z; lvv[7] = l1.w;
    }
    unsigned int w0 = raw.x, w1 = raw.y;
    float s = 0.f;
    s += __expf((float)(w0 & 0xffu) * DECQ + lvv[0]);
    s += __expf((float)((w0 >> 8) & 0xffu) * DECQ + lvv[1]);
    s += __expf((float)((w0 >> 16) & 0xffu) * DECQ + lvv[2]);
    s += __expf((float)(w0 >> 24) * DECQ + lvv[3]);
    s += __expf((float)(w1 & 0xffu) * DECQ + lvv[4]);
    s += __expf((float)((w1 >> 8) & 0xffu) * DECQ + lvv[5]);
    s += __expf((float)((w1 >> 16) & 0xffu) * DECQ + lvv[6]);
    s += __expf((float)(w1 >> 24) * DECQ + lvv[7]);
#pragma unroll
    for (int off = 32; off >= 1; off >>= 1) s += __shfl_xor(s, off);
    if ((tid & 63) == 0) red[tid >> 6] = s;
    __syncthreads();
    if (tid == 0) lu[row] = -6.9314718055994531f - __logf(red[0] + red[1] + red[2] + red[3]);
}

// ---------------- K4: col sum-exp -> lv (u8 logK, batch-fastest) ----------------
__global__ __launch_bounds__(256) void k_collse(
    const unsigned char* __restrict__ logK8, const float* __restrict__ lu, float* __restrict__ lv)
{
    __shared__ float lus[1024];
    __shared__ float redS[4][128];
    int b = blockIdx.x;
    int n0 = blockIdx.y * 128;
    int tid = threadIdx.x;
    for (int i = tid; i < 1024; i += 256) lus[i] = lu[(long)b * LT + i];
    __syncthreads();
    int c2 = (tid & 63) * 2;
    int g = tid >> 6;
    const unsigned char* base = logK8 + (long)b * LT * LA + n0 + c2;
    float S0 = 0.f, S1 = 0.f;
#pragma unroll 4
    for (int m = g; m < 1024; m += 4) {
        unsigned short raw = *(const unsigned short*)(base + (long)m * LA);
        float lm = lus[m];
        S0 += __expf((float)(raw & 0xffu) * DECQ + lm);
        S1 += __expf((float)(raw >> 8) * DECQ + lm);
    }
    redS[g][c2] = S0; redS[g][c2 + 1] = S1;
    __syncthreads();
    if (tid < 128) {
        float s = redS[0][tid] + redS[1][tid] + redS[2][tid] + redS[3][tid];
        lv[(long)b * LA + n0 + tid] = -7.6246189861593985f - __logf(s);
    }
}

// ---------------- K5: A_al = pi @ Ap (MFMA; u8 logK, K-split x2, batch-fastest) ----------------
__global__ __launch_bounds__(256) void k_pi_mfma(
    const unsigned char* __restrict__ logK8, const unsigned short* __restrict__ ApbT,
    const float* __restrict__ lu, const float* __restrict__ lv, float* __restrict__ Apart)
{
    __shared__ short As[64][48];
    __shared__ short Bs[256][48];
    __shared__ float lv_s[1024];
    __shared__ float lu_s[64];
    int b = blockIdx.x;
    int kh = blockIdx.y;
    int m_blk = blockIdx.z * 64;
    int nbase = kh * 1024;
    int tid = threadIdx.x;
    for (int i = tid; i < 1024; i += 256) lv_s[i] = lv[(long)b * LA + nbase + i];
    if (tid < 64) lu_s[tid] = lu[(long)b * LT + m_blk + tid];
    __syncthreads();
    int wid = tid >> 6, lane = tid & 63;
    int l15 = lane & 15, kq = lane >> 4;
    int wm0 = (wid & 1) * 32, wd0 = (wid >> 1) * 128;
    f32x4 acc[2][8];
#pragma unroll
    for (int i = 0; i < 2; i++)
#pragma unroll
        for (int j = 0; j < 8; j++) acc[i][j] = (f32x4){0.f, 0.f, 0.f, 0.f};
    const unsigned char* Kbase = logK8 + ((long)b * LT + m_blk) * (long)LA + nbase;
    const unsigned short* Bbase = ApbT + (long)b * D_ * (long)LA + nbase;
    int arow = tid >> 2, ac8 = (tid & 3) * 8;
    for (int kt = 0; kt < 32; kt++) {
        int n0 = kt * 32;
        {
            uint2 raw = *(const uint2*)(Kbase + (long)arow * LA + n0 + ac8);
            float lum = lu_s[arow];
            const float* lvp = &lv_s[n0 + ac8];
            unsigned int w0 = raw.x, w1 = raw.y;
            unsigned int o0 = f2bf(__expf((float)(w0 & 0xffu) * DECQ + lum + lvp[0]));
            unsigned int o1 = f2bf(__expf((float)((w0 >> 8) & 0xffu) * DECQ + lum + lvp[1]));
            unsigned int o2 = f2bf(__expf((float)((w0 >> 16) & 0xffu) * DECQ + lum + lvp[2]));
            unsigned int o3 = f2bf(__expf((float)(w0 >> 24) * DECQ + lum + lvp[3]));
            unsigned int o4 = f2bf(__expf((float)(w1 & 0xffu) * DECQ + lum + lvp[4]));
            unsigned int o5 = f2bf(__expf((float)((w1 >> 8) & 0xffu) * DECQ + lum + lvp[5]));
            unsigned int o6 = f2bf(__expf((float)((w1 >> 16) & 0xffu) * DECQ + lum + lvp[6]));
            unsigned int o7 = f2bf(__expf((float)(w1 >> 24) * DECQ + lum + lvp[7]));
            int4 ov;
            ov.x = (int)(o0 | (o1 << 16)); ov.y = (int)(o2 | (o3 << 16));
            ov.z = (int)(o4 | (o5 << 16)); ov.w = (int)(o6 | (o7 << 16));
            *(int4*)&As[arow][ac8] = ov;
        }
#pragma unroll
        for (int h = 0; h < 4; h++) {
            int idx = tid + 256 * h;
            int row = idx >> 2, ch = idx & 3;
            *(int4*)&Bs[row][ch * 8] = *(const int4*)(Bbase + (long)row * LA + n0 + ch * 8);
        }
        __syncthreads();
        bf16x8 af[2], bfv[8];
        af[0] = *(const bf16x8*)&As[wm0 + l15][kq * 8];
        af[1] = *(const bf16x8*)&As[wm0 + 16 + l15][kq * 8];
#pragma unroll
        for (int j = 0; j < 8; j++) bfv[j] = *(const bf16x8*)&Bs[wd0 + j * 16 + l15][kq * 8];
#pragma unroll
        for (int i = 0; i < 2; i++)
#pragma unroll
            for (int j = 0; j < 8; j++)
                acc[i][j] = __builtin_amdgcn_mfma_f32_16x16x32_bf16(af[i], bfv[j], acc[i][j], 0, 0, 0);
        __syncthreads();
    }
    float* dst = Apart + (long)kh * (NB * (long)LT * D_);
#pragma unroll
    for (int i = 0; i < 2; i++) {
#pragma unroll
        for (int r = 0; r < 4; r++) {
            int m = m_blk + wm0 + i * 16 + kq * 4 + r;
            long obase = ((long)b * LT + m) * D_;
#pragma unroll
            for (int j = 0; j < 8; j++)
                dst[obase + wd0 + j * 16 + l15] = acc[i][j][r];
        }
    }
}

// ---------------- K6: combine K-halves, S, resid (batch-fastest) ----------------
__global__ __launch_bounds__(256) void k_sresid(
    const float* __restrict__ Tp, const float* __restrict__ Apart,
    float* __restrict__ resid, unsigned short* __restrict__ residb, float* __restrict__ S)
{
    __shared__ float red[4];
    int b = blockIdx.x & 15;
    int m = blockIdx.x >> 4;
    long row = (long)b * LT + m;
    int tid = threadIdx.x;
    long idx = row * D_ + tid;
    float t = Tp[idx];
    float a = Apart[idx] + Apart[idx + (long)NB * LT * D_];
    float rr = fabsf(t - a);
    resid[idx] = rr;
    residb[idx] = f2bf(rr);
    float p = t * a;
#pragma unroll
    for (int off = 32; off >= 1; off >>= 1) p += __shfl_xor(p, off);
    if ((tid & 63) == 0) red[tid >> 6] = p;
    __syncthreads();
    if (tid == 0) S[row] = red[0] + red[1] + red[2] + red[3];
}

// ---------------- K7: router fused: H (regs only) -> logits -> softmax -> G ----------------
__global__ __launch_bounds__(256) void k_router_fused(
    const unsigned short* __restrict__ residb, const unsigned short* __restrict__ Wr1b,
    const float* __restrict__ Wr1, const float* __restrict__ br1,
    const float* __restrict__ S, const float* __restrict__ Wr2,
    const float* __restrict__ br2, float* __restrict__ G)
{
    __shared__ short xb[64][264];
    __shared__ short Bs[256][40];
    int tid = threadIdx.x;
    long row0 = (long)blockIdx.x * 64;
#pragma unroll
    for (int h = 0; h < 8; h++) {
        int idx = tid + 256 * h;
        int row = idx >> 5, ch = idx & 31;
        *(int4*)&xb[row][ch * 8] = *(const int4*)(residb + (row0 + row) * D_ + ch * 8);
    }
    __syncthreads();
    int wid = tid >> 6, lane = tid & 63;
    int l15 = lane & 15, kq = lane >> 4;
    int m_local = wid * 16;
    f32x4 acc[16];
#pragma unroll
    for (int j = 0; j < 16; j++) acc[j] = (f32x4){0.f, 0.f, 0.f, 0.f};
    for (int kt = 0; kt < 8; kt++) {
        int k0 = kt * 32;
#pragma unroll
        for (int h = 0; h < 4; h++) {
            int idx = tid + 256 * h;
            int n = idx >> 2, qc = idx & 3;
            *(int4*)&Bs[n][qc * 8] = *(const int4*)(Wr1b + (long)n * D_ + k0 + qc * 8);
        }
        __syncthreads();
        bf16x8 af = *(const bf16x8*)&xb[m_local + l15][k0 + kq * 8];
#pragma unroll
        for (int j = 0; j < 16; j++) {
            bf16x8 bf = *(const bf16x8*)&Bs[j * 16 + l15][kq * 8];
            acc[j] = __builtin_amdgcn_mfma_f32_16x16x32_bf16(af, bf, acc[j], 0, 0, 0);
        }
        __syncthreads();
    }
    float sv[4];
#pragma unroll
    for (int r = 0; r < 4; r++) sv[r] = S[row0 + m_local + kq * 4 + r];
    float le[3][4] = {};
#pragma unroll
    for (int j = 0; j < 16; j++) {
        int col = j * 16 + l15;
        float w0 = Wr1[(long)col * 257];
        float bv = br1[col];
        float w2a = Wr2[col], w2b = Wr2[256 + col], w2c = Wr2[512 + col];
#pragma unroll
        for (int r = 0; r < 4; r++) {
            float hv = gelu_f(acc[j][r] + sv[r] * w0 + bv);
            le[0][r] += hv * w2a;
            le[1][r] += hv * w2b;
            le[2][r] += hv * w2c;
        }
    }
#pragma unroll
    for (int off = 8; off >= 1; off >>= 1)
#pragma unroll
        for (int e = 0; e < 3; e++)
#pragma unroll
            for (int r = 0; r < 4; r++) le[e][r] += __shfl_xor(le[e][r], off);
    if (l15 == 0) {
        float b0 = br2[0], b1 = br2[1], b2 = br2[2];
#pragma unroll
        for (int r = 0; r < 4; r++) {
            long m = row0 + m_local + kq * 4 + r;
            float L0 = le[0][r] + b0, L1 = le[1][r] + b1, L2 = le[2][r] + b2;
            float mx = fmaxf(L0, fmaxf(L1, L2));
            float e0 = __expf(L0 - mx), e1 = __expf(L1 - mx), e2 = __expf(L2 - mx);
            float inv = 1.0f / (e0 + e1 + e2);
            G[m] = e0 * inv; G[NRT + m] = e1 * inv; G[2 * NRT + m] = e2 * inv;
        }
    }
}

// ---------------- K8a: h[e] = gelu(residb @ down_W[e]^T + down_b[e]) ----------------
__global__ __launch_bounds__(256) void k_down_mfma(
    const unsigned short* __restrict__ residb, const unsigned short* __restrict__ dWb,
    const float* __restrict__ db, float* __restrict__ hall)
{
    __shared__ short xb[64][264];
    __shared__ short Bs[64][40];
    int tid = threadIdx.x;
    int e = blockIdx.y;
    int b = blockIdx.x & 15;
    int mseg = blockIdx.x >> 4;
    long row0 = (long)b * LT + mseg * 64;
    const unsigned short* dWe = dWb + (long)e * RR_ * D_;
    float* h = hall + (long)e * NRT * RR_;
#pragma unroll
    for (int hh = 0; hh < 8; hh++) {
        int idx = tid + 256 * hh;
        int row = idx >> 5, ch = idx & 31;
        *(int4*)&xb[row][ch * 8] = *(const int4*)(residb + (row0 + row) * D_ + ch * 8);
    }
    __syncthreads();
    int wid = tid >> 6, lane = tid & 63;
    int l15 = lane & 15, kq = lane >> 4;
    int m_local = wid * 16;
    f32x4 acc[4];
#pragma unroll
    for (int j = 0; j < 4; j++) acc[j] = (f32x4){0.f, 0.f, 0.f, 0.f};
    for (int kt = 0; kt < 8; kt++) {
        int k0 = kt * 32;
        {
            int n = tid >> 2, qc = tid & 3;
            *(int4*)&Bs[n][qc * 8] = *(const int4*)(dWe + (long)n * D_ + k0 + qc * 8);
        }
        __syncthreads();
        bf16x8 af = *(const bf16x8*)&xb[m_local + l15][k0 + kq * 8];
#pragma unroll
        for (int j = 0; j < 4; j++) {
            bf16x8 bf = *(const bf16x8*)&Bs[j * 16 + l15][kq * 8];
            acc[j] = __builtin_amdgcn_mfma_f32_16x16x32_bf16(af, bf, acc[j], 0, 0, 0);
        }
        __syncthreads();
    }
#pragma unroll
    for (int j = 0; j < 4; j++) {
        int col = j * 16 + l15;
        float bv = db[e * RR_ + col];
#pragma unroll
        for (int r = 0; r < 4; r++) {
            long m = row0 + m_local + kq * 4 + r;
            h[m * RR_ + col] = gelu_f(acc[j][r] + bv);
        }
    }
}

// ---------------- K8b: depth-conv, all 3 experts in one launch -> bf16 ----------------
__global__ __launch_bounds__(256) void k_conv_all(
    const float* __restrict__ hall, const float* __restrict__ cw1,
    const float* __restrict__ cw3, const float* __restrict__ cw5,
    const float* __restrict__ conv_b, unsigned short* __restrict__ hcbb)
{
    __shared__ float hs[68][68];
    __shared__ float wt[64][64];
    int e = blockIdx.y;
    const float* w = (e == 0) ? cw1 : ((e == 1) ? cw3 : cw5);
    int ksz = (e == 0) ? 1 : ((e == 1) ? 3 : 5);
    const float* h = hall + (long)e * NRT * RR_;
    unsigned short* hcb = hcbb + (long)e * NRT * RR_;
    const float* cb = conv_b + e * 64;
    int b = blockIdx.x & 15;
    int m0 = (blockIdx.x >> 4) * 64;
    int tid = threadIdx.x;
    int pad = (ksz - 1) >> 1;
    for (int idx = tid; idx < 68 * 16; idx += 256) {
        int mr = idx >> 4, i4 = idx & 15;
        int mm = m0 - 2 + mr;
        float4 vv = { 0.f, 0.f, 0.f, 0.f };
        if (mm >= 0 && mm < LT) vv = *(const float4*)(h + ((long)b * LT + mm) * RR_ + i4 * 4);
        *(float4*)&hs[mr][i4 * 4] = vv;
    }
    int tx = tid & 15, ty = tid >> 4;
    float acc[4][4] = {};
    for (int t = 0; t < ksz; t++) {
        __syncthreads();
        for (int idx = tid; idx < 4096; idx += 256) {
            int i = idx & 63, j = idx >> 6;
            wt[i][j] = w[(long)j * RR_ * ksz + i * ksz + t];
        }
        __syncthreads();
        int roff = ty * 4 + 2 + t - pad;
        for (int i4 = 0; i4 < 16; i4++) {
            float4 h0 = *(const float4*)&hs[roff + 0][i4 * 4];
            float4 h1 = *(const float4*)&hs[roff + 1][i4 * 4];
            float4 h2 = *(const float4*)&hs[roff + 2][i4 * 4];
            float4 h3 = *(const float4*)&hs[roff + 3][i4 * 4];
            float hh[4][4] = { { h0.x, h0.y, h0.z, h0.w }, { h1.x, h1.y, h1.z, h1.w },
                               { h2.x, h2.y, h2.z, h2.w }, { h3.x, h3.y, h3.z, h3.w } };
#pragma unroll
            for (int s = 0; s < 4; s++) {
                float4 wv = *(const float4*)&wt[i4 * 4 + s][tx * 4];
#pragma unroll
                for (int r = 0; r < 4; r++) {
                    acc[r][0] += hh[r][s] * wv.x;
                    acc[r][1] += hh[r][s] * wv.y;
                    acc[r][2] += hh[r][s] * wv.z;
                    acc[r][3] += hh[r][s] * wv.w;
                }
            }
        }
    }
    float4 bb = *(const float4*)(cb + tx * 4);
#pragma unroll
    for (int r = 0; r < 4; r++) {
        long m = (long)b * LT + m0 + ty * 4 + r;
        unsigned long long pv =
              (unsigned long long)f2bf(gelu_f(acc[r][0] + bb.x))
            | ((unsigned long long)f2bf(gelu_f(acc[r][1] + bb.y)) << 16)
            | ((unsigned long long)f2bf(gelu_f(acc[r][2] + bb.z)) << 32)
            | ((unsigned long long)f2bf(gelu_f(acc[r][3] + bb.w)) << 48);
        *(unsigned long long*)(hcb + m * RR_ + tx * 4) = pv;
    }
}

// ---------------- K8c: all 3 experts: up-proj + resid + LN + gated sum, ONE out write ----------------
__global__ __launch_bounds__(256) void k_up3(
    const unsigned short* __restrict__ hcbb, const unsigned short* __restrict__ uWb,
    const float* __restrict__ up_b, const float* __restrict__ resid,
    const float* __restrict__ en_g, const float* __restrict__ en_b,
    const float* __restrict__ G, float* __restrict__ out)
{
    __shared__ short hs[64][88];
    __shared__ short Bs[256][40];
    int tid = threadIdx.x;
    int b = blockIdx.x & 15;
    int mseg = blockIdx.x >> 4;
    long row0 = (long)b * LT + mseg * 64;
    int wid = tid >> 6, lane = tid & 63;
    int l15 = lane & 15, kq = lane >> 4;
    int m_local = wid * 16;
    long mrow[4];
#pragma unroll
    for (int r = 0; r < 4; r++) mrow[r] = row0 + m_local + kq * 4 + r;
    f32x4 outacc[16];
#pragma unroll
    for (int j = 0; j < 16; j++) outacc[j] = (f32x4){0.f, 0.f, 0.f, 0.f};
    for (int e = 0; e < 3; e++) {
        __syncthreads();   // prior expert's LDS readers done
        const unsigned short* hcb = hcbb + (long)e * NRT * RR_;
        const unsigned short* uWe = uWb + (long)e * 16384;
#pragma unroll
        for (int hh = 0; hh < 2; hh++) {
            int idx = tid + 256 * hh;
            int row = idx >> 3, ch = idx & 7;
            *(int4*)&hs[row][ch * 8] = *(const int4*)(hcb + (row0 + row) * RR_ + ch * 8);
        }
        f32x4 acc[16];
#pragma unroll
        for (int j = 0; j < 16; j++) acc[j] = (f32x4){0.f, 0.f, 0.f, 0.f};
        for (int kt = 0; kt < 2; kt++) {
            int k0 = kt * 32;
#pragma unroll
            for (int hh = 0; hh < 4; hh++) {
                int idx = tid + 256 * hh;
                int n = idx >> 2, qc = idx & 3;
                *(int4*)&Bs[n][qc * 8] = *(const int4*)(uWe + (long)n * RR_ + k0 + qc * 8);
            }
            __syncthreads();
            bf16x8 af = *(const bf16x8*)&hs[m_local + l15][k0 + kq * 8];
#pragma unroll
            for (int j = 0; j < 16; j++) {
                bf16x8 bf = *(const bf16x8*)&Bs[j * 16 + l15][kq * 8];
                acc[j] = __builtin_amdgcn_mfma_f32_16x16x32_bf16(af, bf, acc[j], 0, 0, 0);
            }
            __syncthreads();
        }
        const float* ub = up_b + e * 256;
#pragma unroll
        for (int j = 0; j < 16; j++) {
            int col = j * 16 + l15;
            float bv = ub[col];
#pragma unroll
            for (int r = 0; r < 4; r++)
                acc[j][r] += bv + resid[mrow[r] * D_ + col];
        }
        float s[4] = {0.f, 0.f, 0.f, 0.f};
#pragma unroll
        for (int j = 0; j < 16; j++)
#pragma unroll
            for (int r = 0; r < 4; r++) s[r] += acc[j][r];
#pragma unroll
        for (int off = 8; off >= 1; off >>= 1)
#pragma unroll
            for (int r = 0; r < 4; r++) s[r] += __shfl_xor(s[r], off);
        float mn[4];
#pragma unroll
        for (int r = 0; r < 4; r++) mn[r] = s[r] * (1.0f / 256.0f);
        float q[4] = {0.f, 0.f, 0.f, 0.f};
#pragma unroll
        for (int j = 0; j < 16; j++)
#pragma unroll
            for (int r = 0; r < 4; r++) { float d = acc[j][r] - mn[r]; q[r] += d * d; }
#pragma unroll
        for (int off = 8; off >= 1; off >>= 1)
#pragma unroll
            for (int r = 0; r < 4; r++) q[r] += __shfl_xor(q[r], off);
        float iv[4], gv[4];
#pragma unroll
        for (int r = 0; r < 4; r++) {
            iv[r] = rsqrtf(q[r] * (1.0f / 256.0f) + 1e-5f);
            gv[r] = G[(long)e * NRT + mrow[r]];
        }
        const float* eg = en_g + e * 256;
        const float* eb = en_b + e * 256;
#pragma unroll
        for (int j = 0; j < 16; j++) {
            int col = j * 16 + l15;
            float egc = eg[col], ebc = eb[col];
#pragma unroll
            for (int r = 0; r < 4; r++)
                outacc[j][r] += gv[r] * ((acc[j][r] - mn[r]) * iv[r] * egc + ebc);
        }
    }
#pragma unroll
    for (int j = 0; j < 16; j++) {
        int col = j * 16 + l15;
#pragma unroll
        for (int r = 0; r < 4; r++)
            out[mrow[r] * D_ + col] = outacc[j][r];
    }
}

extern "C" void kernel_launch(void* const* d_in, const int* in_sizes, int n_in,
                              void* d_out, int out_size, void* d_ws, size_t ws_size,
                              hipStream_t stream)
{
    const float* text   = (const float*)d_in[0];
    const float* audio  = (const float*)d_in[1];
    const float* ln_g   = (const float*)d_in[2];
    const float* ln_b   = (const float*)d_in[3];
    const float* W_sh   = (const float*)d_in[4];
    const float* b_sh   = (const float*)d_in[5];
    const float* Wr1    = (const float*)d_in[6];
    const float* br1    = (const float*)d_in[7];
    const float* Wr2    = (const float*)d_in[8];
    const float* br2    = (const float*)d_in[9];
    const float* down_W = (const float*)d_in[10];
    const float* down_b = (const float*)d_in[11];
    const float* cw1    = (const float*)d_in[12];
    const float* cw3    = (const float*)d_in[13];
    const float* cw5    = (const float*)d_in[14];
    const float* conv_b = (const float*)d_in[15];
    const float* up_W   = (const float*)d_in[16];
    const float* up_b   = (const float*)d_in[17];
    const float* en_g   = (const float*)d_in[18];
    const float* en_b   = (const float*)d_in[19];

    float* ws = (float*)d_ws;
    float*          Tp    = ws;                               // 4,194,304 f
    unsigned short* Tnb   = (unsigned short*)(ws + 4194304);  // 2,097,152 f
    unsigned short* Anb   = (unsigned short*)(ws + 6291456);  // 4,194,304 f
    unsigned short* ApbT  = (unsigned short*)(ws + 10485760); // 4,194,304 f
    unsigned char*  logK8 = (unsigned char*)(ws + 14680064);  // 8,388,608 f (33.5 MB u8)
    float*          Apart = ws + 23068672;                    // 2 x 4,194,304 f
    float*          resid = ws + 31457280;                    // 4,194,304 f
    unsigned short* residb= (unsigned short*)(ws + 35651584); // 2,097,152 f
    float*          lu    = ws + 37748736;                    // 16,384
    float*          lv    = ws + 37765120;                    // 32,768
    float*          Sb    = ws + 37797888;                    // 16,384
    float*          Gb    = ws + 37814272;                    // 49,152
    unsigned short* Wb    = (unsigned short*)(ws + 37863424); // 32,768 f
    unsigned short* dWb   = (unsigned short*)(ws + 37896192); // 24,576 f
    unsigned short* uWb   = (unsigned short*)(ws + 37920768); // 24,576 f
    unsigned short* Wr1b  = (unsigned short*)(ws + 37945344); // 32,768 f
    size_t need_bytes = (size_t)37978112 * 4;
    if (ws_size < need_bytes) {
        fprintf(stderr, "kernel_launch: ws_size %zu < needed %zu\n", ws_size, need_bytes);
        return;
    }
    // aliases in logK8 region (dead after k_pi_mfma):
    float*          hall = ws + 14680064;                     // 3,145,728 f
    unsigned short* hcbb = (unsigned short*)(ws + 17825792);  // 1,572,864 f

    k_prep_all<<<896, 256, 0, stream>>>(W_sh, down_W, up_W, Wr1, Wb, dWb, uWb, Wr1b);
    k_lnproj_mfma<<<NRT / 64, 256, 0, stream>>>(text, ln_g, ln_b, Wb, b_sh, Tp, Tnb);
    k_lnproj_mfma<<<NRA / 64, 256, 0, stream>>>(audio, ln_g, ln_b, Wb, b_sh, nullptr, Anb);
    k_transpose_bf<<<dim3(NB, LA / 64, D_ / 64), 256, 0, stream>>>(Anb, ApbT);
    k_cost_mfma<<<dim3(NB, LT / 128, LA / 128), 256, 0, stream>>>(Tnb, Anb, logK8);
    for (int it = 0; it < 10; it++) {
        k_rowlse<<<NRT, 256, 0, stream>>>(logK8, lv, lu, it == 0 ? 1 : 0);
        k_collse<<<dim3(NB, LA / 128), 256, 0, stream>>>(logK8, lu, lv);
    }
    k_pi_mfma<<<dim3(NB, 2, LT / 64), 256, 0, stream>>>(logK8, ApbT, lu, lv, Apart);
    k_sresid<<<NRT, 256, 0, stream>>>(Tp, Apart, resid, residb, Sb);
    k_router_fused<<<NRT / 64, 256, 0, stream>>>(residb, Wr1b, Wr1, br1, Sb, Wr2, br2, Gb);
    k_down_mfma<<<dim3(NRT / 64, 3), 256, 0, stream>>>(residb, dWb, down_b, hall);
    k_conv_all<<<dim3(NRT / 64, 3), 256, 0, stream>>>(hall, cw1, cw3, cw5, conv_b, hcbb);
    k_up3<<<NRT / 64, 256, 0, stream>>>(hcbb, uWb, up_b, resid, en_g, en_b, Gb, (float*)d_out);
}